// Round 4
// baseline (1056.098 us; speedup 1.0000x reference)
//
#include <hip/hip_runtime.h>
#include <math.h>

#define DD 128
#define LDSS 136   // u16 LDS row stride (128 + 8 pad)
#define LDSF 132   // f32 LDS row stride (128 + 4 pad)
#define WT 16384   // u16 elements per packed 128x128 weight matrix

typedef __attribute__((ext_vector_type(8))) short bf16x8;
typedef __attribute__((ext_vector_type(4))) float f32x4;
typedef unsigned short u16;
typedef unsigned int u32;

__device__ __forceinline__ u16 f2bf(float f) {
    u32 u = __builtin_bit_cast(u32, f);
    u += 0x7fffu + ((u >> 16) & 1u);   // RNE
    return (u16)(u >> 16);
}
__device__ __forceinline__ float bf2f(u16 h) {
    u32 u = ((u32)h) << 16;
    return __builtin_bit_cast(float, u);
}
__device__ __forceinline__ float mishf(float x) {
    float e = __expf(fminf(x, 15.0f));
    float n = e * (e + 2.0f);
    return x * n * __builtin_amdgcn_rcpf(n + 2.0f);
}
__device__ __forceinline__ void split8(const float* v, bf16x8& h, bf16x8& l) {
#pragma unroll
    for (int j = 0; j < 8; j++) {
        u16 hj = f2bf(v[j]);
        float r = v[j] - bf2f(hj);
        h[j] = (short)hj;
        l[j] = (short)f2bf(r);
    }
}

// NM=1: ah*bh ; NM=2: ah*(bh+bl) [A exact-bf16] ; NM=3: + al*bh [A fp32-split]
template<int NM>
__device__ __forceinline__ void gemm8(const bf16x8* ah, const bf16x8* al,
    const u16* __restrict__ Wh, const u16* __restrict__ Wl, int lane, f32x4* acc)
{
#pragma unroll
    for (int kb = 0; kb < 4; kb++)
#pragma unroll
        for (int nt = 0; nt < 8; nt++) {
            size_t boff = (((size_t)kb * 8 + nt) * 64 + lane) * 8;
            bf16x8 bh = *(const bf16x8*)(Wh + boff);
            acc[nt] = __builtin_amdgcn_mfma_f32_16x16x32_bf16(ah[kb], bh, acc[nt], 0, 0, 0);
            if (NM >= 2) {
                bf16x8 bl = *(const bf16x8*)(Wl + boff);
                acc[nt] = __builtin_amdgcn_mfma_f32_16x16x32_bf16(ah[kb], bl, acc[nt], 0, 0, 0);
            }
            if (NM == 3)
                acc[nt] = __builtin_amdgcn_mfma_f32_16x16x32_bf16(al[kb], bh, acc[nt], 0, 0, 0);
        }
}

__device__ __forceinline__ void zero_acc(f32x4* acc) {
#pragma unroll
    for (int nt = 0; nt < 8; nt++) { f32x4 z4 = {0.f, 0.f, 0.f, 0.f}; acc[nt] = z4; }
}

__device__ __forceinline__ void frag_from_lds(const float* ldsF, int wave, int lm, int quad,
                                              bf16x8* ah, bf16x8* al)
{
    const float* p = ldsF + (size_t)(wave * 16 + lm) * LDSF + quad * 8;
#pragma unroll
    for (int kb = 0; kb < 4; kb++) {
        float tmp[8];
        *(float4*)tmp       = *(const float4*)(p + kb * 32);
        *(float4*)(tmp + 4) = *(const float4*)(p + kb * 32 + 4);
        split8(tmp, ah[kb], al[kb]);
    }
}

// ============ weight prep ============
struct WSrc { const float* p[18]; };

__global__ __launch_bounds__(256) void prep_weights(WSrc ws, u16* __restrict__ Wh, u16* __restrict__ Wl)
{
    int mat = blockIdx.x >> 3, chunk = blockIdx.x & 7;
    int t = threadIdx.x;
    int tt = chunk * 4 + (t >> 6);
    int lane = t & 63;
    int kb = tt >> 3, nt = tt & 7;
    const float* __restrict__ src = ws.p[mat];
    size_t doff = (size_t)mat * WT + ((size_t)tt * 64 + lane) * 8;
    int srow = kb * 32 + ((lane >> 4) * 8);
    int scol = nt * 16 + (lane & 15);
    u16 th[8], tl[8];
#pragma unroll
    for (int j = 0; j < 8; j++) {
        float v = src[(srow + j) * DD + scol];
        u16 h = f2bf(v);
        th[j] = h;
        tl[j] = f2bf(v - bf2f(h));
    }
    *(bf16x8*)(Wh + doff) = *(bf16x8*)th;
    *(bf16x8*)(Wl + doff) = *(bf16x8*)tl;
}

// ============ front-end: x read once -> G(As,Bs,xb), xWs, At, Bt, Ct, e0 ============
__global__ __launch_bounds__(256) void frontend_kernel(
    const float* __restrict__ x, const u16* __restrict__ Wh, const u16* __restrict__ Wl,
    u16* __restrict__ G, u16* __restrict__ xWs,
    float* __restrict__ At, float* __restrict__ Bt, float* __restrict__ Ct,
    u16* __restrict__ e0, int M)
{
    __shared__ u16 sA[64 * LDSS], sB[64 * LDSS], sX[64 * LDSS];
    const int t = threadIdx.x, wave = t >> 6, lane = t & 63;
    const int lm = lane & 15, quad = lane >> 4;
    const int rowBase = blockIdx.x * 64;

    bf16x8 ah[4], al[4];
    {
        int row = rowBase + wave * 16 + lm; if (row >= M) row = M - 1;
        const float* p = x + (size_t)row * DD + quad * 8;
#pragma unroll
        for (int kb = 0; kb < 4; kb++) {
            float tmp[8];
            *(float4*)tmp       = *(const float4*)(p + kb * 32);
            *(float4*)(tmp + 4) = *(const float4*)(p + kb * 32 + 4);
            split8(tmp, ah[kb], al[kb]);
        }
    }
    // xb (== hi part of x) into sX, A-layout rows
    {
        int arow = wave * 16 + lm;
#pragma unroll
        for (int kb = 0; kb < 4; kb++)
            *(bf16x8*)&sX[arow * LDSS + kb * 32 + quad * 8] = ah[kb];
    }
    // As = x@W1 (hi), Bs = x@W3 (hi) -> LDS C-layout
    {
        f32x4 acc[8]; zero_acc(acc);
        gemm8<1>(ah, al, Wh + 1 * WT, Wh, lane, acc);
#pragma unroll
        for (int r = 0; r < 4; r++)
#pragma unroll
            for (int nt = 0; nt < 8; nt++)
                sA[(wave * 16 + quad * 4 + r) * LDSS + nt * 16 + lm] = f2bf(acc[nt][r]);
    }
    {
        f32x4 acc[8]; zero_acc(acc);
        gemm8<1>(ah, al, Wh + 3 * WT, Wh, lane, acc);
#pragma unroll
        for (int r = 0; r < 4; r++)
#pragma unroll
            for (int nt = 0; nt < 8; nt++)
                sB[(wave * 16 + quad * 4 + r) * LDSS + nt * 16 + lm] = f2bf(acc[nt][r]);
    }
    __syncthreads();
    // interleaved G write: per row 64 lanes x 12B contiguous
#pragma unroll
    for (int i = 0; i < 16; i++) {
        int r = (t >> 6) + i * 4;
        int grow = rowBase + r;
        u32 ga = *(const u32*)&sA[r * LDSS + lane * 2];
        u32 gb = *(const u32*)&sB[r * LDSS + lane * 2];
        u32 gx = *(const u32*)&sX[r * LDSS + lane * 2];
        if (grow < M) {
            u16* gp = G + (size_t)grow * 384 + lane * 6;
            *(u32*)gp       = ga;
            *(u32*)(gp + 2) = gb;
            *(u32*)(gp + 4) = gx;
        }
    }
    // xWs = x@W5 (hi) -> global bf16
    {
        f32x4 acc[8]; zero_acc(acc);
        gemm8<1>(ah, al, Wh + 5 * WT, Wh, lane, acc);
#pragma unroll
        for (int r = 0; r < 4; r++) {
            int grow = rowBase + wave * 16 + quad * 4 + r;
            if (grow >= M) continue;
#pragma unroll
            for (int nt = 0; nt < 8; nt++)
                xWs[(size_t)grow * DD + nt * 16 + lm] = f2bf(acc[nt][r]);
        }
    }
    // At, Bt, Ct (split, fp32 out)
    float* outs[3] = {At, Bt, Ct};
    const int mats[3] = {0, 2, 4};
#pragma unroll
    for (int wi = 0; wi < 3; wi++) {
        f32x4 acc[8]; zero_acc(acc);
        gemm8<3>(ah, al, Wh + (size_t)mats[wi] * WT, Wl + (size_t)mats[wi] * WT, lane, acc);
        float* out = outs[wi];
#pragma unroll
        for (int r = 0; r < 4; r++) {
            int grow = rowBase + wave * 16 + quad * 4 + r;
            if (grow >= M) continue;
#pragma unroll
            for (int nt = 0; nt < 8; nt++)
                out[(size_t)grow * DD + nt * 16 + lm] = acc[nt][r];
        }
    }
    // lin2 = mish2(x@W6) -> sA (reuse), then e0 = lin2@W7
    __syncthreads();
    {
        f32x4 acc[8]; zero_acc(acc);
        gemm8<1>(ah, al, Wh + 6 * WT, Wh, lane, acc);
#pragma unroll
        for (int r = 0; r < 4; r++)
#pragma unroll
            for (int nt = 0; nt < 8; nt++)
                sA[(wave * 16 + quad * 4 + r) * LDSS + nt * 16 + lm] = f2bf(mishf(mishf(acc[nt][r])));
    }
    {   // same-wave LDS order guarantees writes precede these reads
        bf16x8 lh[4];
        const u16* p = &sA[(wave * 16 + lm) * LDSS + quad * 8];
#pragma unroll
        for (int kb = 0; kb < 4; kb++) lh[kb] = *(const bf16x8*)(p + kb * 32);
        f32x4 acc[8]; zero_acc(acc);
        gemm8<1>(lh, lh, Wh + 7 * WT, Wh, lane, acc);
#pragma unroll
        for (int r = 0; r < 4; r++) {
            int grow = rowBase + wave * 16 + quad * 4 + r;
            if (grow >= M) continue;
#pragma unroll
            for (int nt = 0; nt < 8; nt++)
                e0[(size_t)grow * DD + nt * 16 + lm] = f2bf(acc[nt][r]);
        }
    }
}

// ============ CSR build ============
__global__ __launch_bounds__(256) void hist_kernel(const int* __restrict__ ei, int* __restrict__ deg, int E)
{
    int e = blockIdx.x * 256 + threadIdx.x;
    if (e < E) atomicAdd(&deg[ei[E + e]], 1);
}

__global__ __launch_bounds__(1024) void scan_kernel(const int* __restrict__ deg,
                                                    int* __restrict__ rowptr,
                                                    int* __restrict__ cursor, int N)
{
    __shared__ int sums[1024];
    int t = threadIdx.x;
    int CH = (N + 1023) / 1024;
    int base = t * CH;
    int local = 0;
    for (int i = 0; i < CH; i++) {
        int idx = base + i;
        if (idx < N) local += deg[idx];
    }
    sums[t] = local;
    __syncthreads();
    for (int off = 1; off < 1024; off <<= 1) {
        int v = sums[t];
        int u = (t >= off) ? sums[t - off] : 0;
        __syncthreads();
        sums[t] = v + u;
        __syncthreads();
    }
    int run = (t == 0) ? 0 : sums[t - 1];
    for (int i = 0; i < CH; i++) {
        int idx = base + i;
        if (idx < N) {
            rowptr[idx] = run;
            cursor[idx] = run;
            run += deg[idx];
        }
    }
    if (t == 1023) rowptr[N] = sums[1023];
}

__global__ __launch_bounds__(256) void scatter_kernel(
    const int* __restrict__ ei, const int* __restrict__ bond,
    const float* __restrict__ coords, int* __restrict__ cursor,
    int2* __restrict__ csr, int E)
{
    int e = blockIdx.x * 256 + threadIdx.x;
    if (e >= E) return;
    int src = ei[e], dst = ei[E + e];
    int pos = atomicAdd(&cursor[dst], 1);
    float dx = coords[src * 3 + 0] - coords[dst * 3 + 0];
    float dy = coords[src * 3 + 1] - coords[dst * 3 + 1];
    float dz = coords[src * 3 + 2] - coords[dst * 3 + 2];
    float d2 = dx * dx + dy * dy + dz * dz;
    csr[pos] = make_int2(src | (bond[e] << 20), __float_as_int(d2));
}

// ============ per-node edge aggregation (interleaved gather) ============
__global__ __launch_bounds__(256) void edge_agg(
    const float* __restrict__ At, const float* __restrict__ Bt,
    const u16* __restrict__ G,
    const int* __restrict__ rowptr, const int2* __restrict__ csr,
    const float* __restrict__ conv_w, const float* __restrict__ conv_b,
    const float* __restrict__ b_nb, const float* __restrict__ b_el,
    u16* __restrict__ Pn, u16* __restrict__ Pe, float* __restrict__ z,
    float* __restrict__ s_arr, int N)
{
    int wave = threadIdx.x >> 6;
    int lane = threadIdx.x & 63;
    int node = blockIdx.x * 4 + wave;
    if (node >= N) return;
    int c0 = lane * 2;
    float2 at = *(const float2*)(At + (size_t)node * DD + c0);
    float2 bt = *(const float2*)(Bt + (size_t)node * DD + c0);
    float cb = conv_b[0];
    float cw0 = conv_w[0] + cb, cw1 = conv_w[1] + cb, cw2 = conv_w[2] + cb, cw3 = conv_w[3] + cb;
    float bn0 = b_nb[c0], bn1 = b_nb[c0 + 1];
    float be0 = b_el[c0], be1 = b_el[c0 + 1];
    float accn0 = 0.f, accn1 = 0.f, acce0 = 0.f, acce1 = 0.f, accz0 = 0.f, accz1 = 0.f, ssum = 0.f;
    int beg = rowptr[node], end = rowptr[node + 1];
    for (int k = beg; k < end; k++) {
        int2 pd = csr[k];
        int src = pd.x & 0xFFFFF;
        int bond = (pd.x >> 20) & 3;
        float w = (bond == 0) ? cw0 : (bond == 1) ? cw1 : (bond == 2) ? cw2 : cw3;
        float d2 = __int_as_float(pd.y);
        const u16* gp = G + (size_t)src * 384 + lane * 6;
        u32 ga = *(const u32*)gp;
        u32 gb = *(const u32*)(gp + 2);
        u32 gx = *(const u32*)(gp + 4);
        float a0 = __builtin_bit_cast(float, ga << 16), a1 = __builtin_bit_cast(float, ga & 0xffff0000u);
        float b0 = __builtin_bit_cast(float, gb << 16), b1 = __builtin_bit_cast(float, gb & 0xffff0000u);
        float x0 = __builtin_bit_cast(float, gx << 16), x1 = __builtin_bit_cast(float, gx & 0xffff0000u);
        accn0 += mishf(at.x + a0 + bn0);
        accn1 += mishf(at.y + a1 + bn1);
        acce0 += mishf(w * (bt.x + b0) + be0);
        acce1 += mishf(w * (bt.y + b1) + be1);
        accz0 += d2 * x0;
        accz1 += d2 * x1;
        ssum += d2;
    }
    *(u32*)(Pn + (size_t)node * DD + c0) = (u32)f2bf(accn0) | ((u32)f2bf(accn1) << 16);
    *(u32*)(Pe + (size_t)node * DD + c0) = (u32)f2bf(acce0) | ((u32)f2bf(acce1) << 16);
    *(float2*)(z + (size_t)node * DD + c0) = make_float2(accz0, accz1);
    if (lane == 0) s_arr[node] = ssum;
}

// ============ fused back end: all chains + softmax + @W_agg ============
__global__ __launch_bounds__(256) void paths_kernel(
    const u16* __restrict__ Pn, const u16* __restrict__ Pe, const float* __restrict__ z,
    const float* __restrict__ Ct, const u16* __restrict__ xWs, const u16* __restrict__ e0,
    const float* __restrict__ s_arr, const int* __restrict__ deg,
    const float* __restrict__ b_nout, const float* __restrict__ b_eout,
    const float* __restrict__ b_coord, const float* __restrict__ b_pair,
    const float* __restrict__ b_sout,
    const u16* __restrict__ Wh, const u16* __restrict__ Wl,
    float* __restrict__ hout, int M)
{
    __shared__ u16 smem[2 * 64 * LDSS];
    float* ldsF = (float*)smem;
    const int t = threadIdx.x, wave = t >> 6, lane = t & 63;
    const int lm = lane & 15, quad = lane >> 4;
    const int rowBase = blockIdx.x * 64;
    const int row0 = rowBase + wave * 16;

    // preload e0 (C-layout, packed bf16)
    u32 e0pk[16];
#pragma unroll
    for (int j = 0; j < 32; j++) {
        int r = j >> 3, nt = j & 7;
        int row = row0 + quad * 4 + r; if (row >= M) row = M - 1;
        u32 v = e0[(size_t)row * DD + nt * 16 + lm];
        if (j & 1) e0pk[j >> 1] |= v << 16; else e0pk[j >> 1] = v;
    }

    float e1v[32], e2v[32];
    u32 f1pk[16], f2pk[16], f3pk[16];

    // ---------- node path ----------
    {
        bf16x8 ah[4];
        int row = row0 + lm; if (row >= M) row = M - 1;
        const u16* p = Pn + (size_t)row * DD + quad * 8;
#pragma unroll
        for (int kb = 0; kb < 4; kb++) ah[kb] = *(const bf16x8*)(p + kb * 32);
        f32x4 acc[8]; zero_acc(acc);
        gemm8<2>(ah, ah, Wh + 11 * WT, Wl + 11 * WT, lane, acc);
#pragma unroll
        for (int r = 0; r < 4; r++)
#pragma unroll
            for (int nt = 0; nt < 8; nt++) {
                int col = nt * 16 + lm;
                float v = mishf(acc[nt][r] + b_nout[col]);
                ldsF[(wave * 16 + quad * 4 + r) * LDSF + col] = v;
                int j = r * 8 + nt;
                if (j & 1) f1pk[j >> 1] |= ((u32)f2bf(v)) << 16; else f1pk[j >> 1] = f2bf(v);
            }
    }
    {
        bf16x8 ah[4], al[4];
        frag_from_lds(ldsF, wave, lm, quad, ah, al);
        f32x4 acc[8]; zero_acc(acc);
        gemm8<3>(ah, al, Wh + 13 * WT, Wl + 13 * WT, lane, acc);
#pragma unroll
        for (int r = 0; r < 4; r++)
#pragma unroll
            for (int nt = 0; nt < 8; nt++)
                ldsF[(wave * 16 + quad * 4 + r) * LDSF + nt * 16 + lm] = mishf(mishf(acc[nt][r]));
    }
    {
        bf16x8 ah[4], al[4];
        frag_from_lds(ldsF, wave, lm, quad, ah, al);
        f32x4 acc[8]; zero_acc(acc);
        gemm8<3>(ah, al, Wh + 16 * WT, Wl + 16 * WT, lane, acc);
#pragma unroll
        for (int j = 0; j < 32; j++) {
            int r = j >> 3, nt = j & 7;
            u32 u = e0pk[j >> 1];
            u16 ev = (j & 1) ? (u16)(u >> 16) : (u16)(u & 0xffff);
            e1v[j] = acc[nt][r] + bf2f(ev);
        }
    }
    // ---------- edge path ----------
    {
        bf16x8 ah[4];
        int row = row0 + lm; if (row >= M) row = M - 1;
        const u16* p = Pe + (size_t)row * DD + quad * 8;
#pragma unroll
        for (int kb = 0; kb < 4; kb++) ah[kb] = *(const bf16x8*)(p + kb * 32);
        f32x4 acc[8]; zero_acc(acc);
        gemm8<2>(ah, ah, Wh + 12 * WT, Wl + 12 * WT, lane, acc);
#pragma unroll
        for (int r = 0; r < 4; r++)
#pragma unroll
            for (int nt = 0; nt < 8; nt++) {
                int col = nt * 16 + lm;
                float v = mishf(acc[nt][r] + b_eout[col]);
                ldsF[(wave * 16 + quad * 4 + r) * LDSF + col] = v;
                int j = r * 8 + nt;
                if (j & 1) f2pk[j >> 1] |= ((u32)f2bf(v)) << 16; else f2pk[j >> 1] = f2bf(v);
            }
    }
    {
        bf16x8 ah[4], al[4];
        frag_from_lds(ldsF, wave, lm, quad, ah, al);
        f32x4 acc[8]; zero_acc(acc);
        gemm8<3>(ah, al, Wh + 14 * WT, Wl + 14 * WT, lane, acc);
#pragma unroll
        for (int r = 0; r < 4; r++)
#pragma unroll
            for (int nt = 0; nt < 8; nt++)
                ldsF[(wave * 16 + quad * 4 + r) * LDSF + nt * 16 + lm] = mishf(mishf(acc[nt][r]));
    }
    {
        bf16x8 ah[4], al[4];
        frag_from_lds(ldsF, wave, lm, quad, ah, al);
        f32x4 acc[8]; zero_acc(acc);
        gemm8<3>(ah, al, Wh + 16 * WT, Wl + 16 * WT, lane, acc);
#pragma unroll
        for (int j = 0; j < 32; j++) {
            int r = j >> 3, nt = j & 7;
            u32 u = e0pk[j >> 1];
            u16 ev = (j & 1) ? (u16)(u >> 16) : (u16)(u & 0xffff);
            e2v[j] = acc[nt][r] + bf2f(ev);
        }
    }
    // ---------- struct path ----------
    {   // Qagg = z@Wc_s + s*Ct + deg*b_coord
        bf16x8 ah[4], al[4];
        int row = row0 + lm; if (row >= M) row = M - 1;
        const float* p = z + (size_t)row * DD + quad * 8;
#pragma unroll
        for (int kb = 0; kb < 4; kb++) {
            float tmp[8];
            *(float4*)tmp       = *(const float4*)(p + kb * 32);
            *(float4*)(tmp + 4) = *(const float4*)(p + kb * 32 + 4);
            split8(tmp, ah[kb], al[kb]);
        }
        f32x4 acc[8]; zero_acc(acc);
        gemm8<3>(ah, al, Wh + 8 * WT, Wl + 8 * WT, lane, acc);
#pragma unroll
        for (int r = 0; r < 4; r++) {
            int crow = row0 + quad * 4 + r; if (crow >= M) crow = M - 1;
            float sv = s_arr[crow];
            float dv = (float)deg[crow];
#pragma unroll
            for (int nt = 0; nt < 8; nt++) {
                int col = nt * 16 + lm;
                float v = acc[nt][r] + sv * Ct[(size_t)crow * DD + col] + dv * b_coord[col];
                ldsF[(wave * 16 + quad * 4 + r) * LDSF + col] = v;
            }
        }
    }
    {   // Q = mish(Qagg@W_pair + b_pair)
        bf16x8 ah[4], al[4];
        frag_from_lds(ldsF, wave, lm, quad, ah, al);
        f32x4 acc[8]; zero_acc(acc);
        gemm8<3>(ah, al, Wh + 9 * WT, Wl + 9 * WT, lane, acc);
#pragma unroll
        for (int r = 0; r < 4; r++)
#pragma unroll
            for (int nt = 0; nt < 8; nt++) {
                int col = nt * 16 + lm;
                ldsF[(wave * 16 + quad * 4 + r) * LDSF + col] = mishf(acc[nt][r] + b_pair[col]);
            }
    }
    {   // f_struct = mish(Q@Ws_b + xWs + b_sout)
        bf16x8 ah[4], al[4];
        frag_from_lds(ldsF, wave, lm, quad, ah, al);
        f32x4 acc[8]; zero_acc(acc);
        gemm8<3>(ah, al, Wh + 10 * WT, Wl + 10 * WT, lane, acc);
#pragma unroll
        for (int r = 0; r < 4; r++) {
            int crow = row0 + quad * 4 + r; if (crow >= M) crow = M - 1;
#pragma unroll
            for (int nt = 0; nt < 8; nt++) {
                int col = nt * 16 + lm;
                float v = mishf(acc[nt][r] + bf2f(xWs[(size_t)crow * DD + col]) + b_sout[col]);
                ldsF[(wave * 16 + quad * 4 + r) * LDSF + col] = v;
                int j = r * 8 + nt;
                if (j & 1) f3pk[j >> 1] |= ((u32)f2bf(v)) << 16; else f3pk[j >> 1] = f2bf(v);
            }
        }
    }
    {   // l2 = mish2(f_struct@FL2)
        bf16x8 ah[4], al[4];
        frag_from_lds(ldsF, wave, lm, quad, ah, al);
        f32x4 acc[8]; zero_acc(acc);
        gemm8<3>(ah, al, Wh + 15 * WT, Wl + 15 * WT, lane, acc);
#pragma unroll
        for (int r = 0; r < 4; r++)
#pragma unroll
            for (int nt = 0; nt < 8; nt++)
                ldsF[(wave * 16 + quad * 4 + r) * LDSF + nt * 16 + lm] = mishf(mishf(acc[nt][r]));
    }
    // ---------- e3 + softmax combine -> att hi/lo into LDS ----------
    u16* ldsH = smem;
    u16* ldsL = smem + 64 * LDSS;
    {
        bf16x8 ah[4], al[4];
        frag_from_lds(ldsF, wave, lm, quad, ah, al);
        f32x4 acc[8]; zero_acc(acc);
        gemm8<3>(ah, al, Wh + 16 * WT, Wl + 16 * WT, lane, acc);
        __syncthreads();   // all waves done reading ldsF before H/L overwrite
#pragma unroll
        for (int j = 0; j < 32; j++) {
            int r = j >> 3, nt = j & 7;
            int col = nt * 16 + lm;
            u32 u0 = e0pk[j >> 1];
            u16 e0u = (j & 1) ? (u16)(u0 >> 16) : (u16)(u0 & 0xffff);
            float x3 = acc[nt][r] + bf2f(e0u);
            float x1 = e1v[j], x2 = e2v[j];
            float m = fmaxf(fmaxf(x1, x2), x3);
            float p1 = __expf(x1 - m), p2 = __expf(x2 - m), p3 = __expf(x3 - m);
            u32 uf1 = f1pk[j >> 1], uf2 = f2pk[j >> 1], uf3 = f3pk[j >> 1];
            float fv1 = bf2f((j & 1) ? (u16)(uf1 >> 16) : (u16)(uf1 & 0xffff));
            float fv2 = bf2f((j & 1) ? (u16)(uf2 >> 16) : (u16)(uf2 & 0xffff));
            float fv3 = bf2f((j & 1) ? (u16)(uf3 >> 16) : (u16)(uf3 & 0xffff));
            float att = (p1 * fv1 + p2 * fv2 + p3 * fv3) * __builtin_amdgcn_rcpf(p1 + p2 + p3);
            u16 hi = f2bf(att);
            int lidx = (wave * 16 + quad * 4 + r) * LDSS + col;
            ldsH[lidx] = hi;
            ldsL[lidx] = f2bf(att - bf2f(hi));
        }
    }
    // ---------- h_agg = att@W_agg ----------
    {
        bf16x8 ah[4], al[4];
        const u16* ph = ldsH + (wave * 16 + lm) * LDSS + quad * 8;
        const u16* pl = ldsL + (wave * 16 + lm) * LDSS + quad * 8;
#pragma unroll
        for (int kb = 0; kb < 4; kb++) {
            ah[kb] = *(const bf16x8*)(ph + kb * 32);
            al[kb] = *(const bf16x8*)(pl + kb * 32);
        }
        f32x4 acc[8]; zero_acc(acc);
        gemm8<3>(ah, al, Wh + 17 * WT, Wl + 17 * WT, lane, acc);
#pragma unroll
        for (int r = 0; r < 4; r++) {
            int grow = row0 + quad * 4 + r;
            if (grow >= M) continue;
#pragma unroll
            for (int nt = 0; nt < 8; nt++)
                hout[(size_t)grow * DD + nt * 16 + lm] = acc[nt][r];
        }
    }
}

// ============ batchnorm ============
__global__ __launch_bounds__(256) void bn_stats(const float* __restrict__ h, float* __restrict__ sums, int N)
{
    int t = threadIdx.x;
    int col = t & 127;
    float s = 0.f, sq = 0.f;
    for (int r = blockIdx.x * 2 + (t >> 7); r < N; r += gridDim.x * 2) {
        float v = h[(size_t)r * DD + col];
        s += v; sq += v * v;
    }
    __shared__ float sh[256];
    sh[t] = s; __syncthreads();
    float s2 = (t < 128) ? (sh[t] + sh[t + 128]) : 0.f;
    __syncthreads();
    sh[t] = sq; __syncthreads();
    if (t < 128) {
        float q2 = sh[t] + sh[t + 128];
        atomicAdd(&sums[t], s2);
        atomicAdd(&sums[128 + t], q2);
    }
}

__global__ void bn_finalize(const float* __restrict__ sums, const float* __restrict__ gamma,
                            const float* __restrict__ beta, float* __restrict__ scale,
                            float* __restrict__ shift, float n_inv)
{
    int c = threadIdx.x;
    float mean = sums[c] * n_inv;
    float var = sums[128 + c] * n_inv - mean * mean;
    float inv = rsqrtf(var + 1e-5f);
    float sc = gamma[c] * inv;
    scale[c] = sc;
    shift[c] = beta[c] - mean * sc;
}

__global__ __launch_bounds__(256) void bn_apply(float* __restrict__ h, const float* __restrict__ scale,
                                                const float* __restrict__ shift, size_t total4)
{
    size_t idx = (size_t)blockIdx.x * 256 + threadIdx.x;
    if (idx >= total4) return;
    size_t off = idx * 4;
    int c = (int)(off & 127);
    float4 v = *(const float4*)(h + off);
    float4 sc = *(const float4*)(scale + c);
    float4 sh = *(const float4*)(shift + c);
    v.x = mishf(v.x * sc.x + sh.x);
    v.y = mishf(v.y * sc.y + sh.y);
    v.z = mishf(v.z * sc.z + sh.z);
    v.w = mishf(v.w * sc.w + sh.w);
    *(float4*)(h + off) = v;
}

// ============ host ============
extern "C" void kernel_launch(void* const* d_in, const int* in_sizes, int n_in,
                              void* d_out, int out_size, void* d_ws, size_t ws_size,
                              hipStream_t stream)
{
    (void)n_in; (void)out_size; (void)ws_size;
    const float* x       = (const float*)d_in[0];
    const float* coords  = (const float*)d_in[1];
    const int*   ei      = (const int*)d_in[2];
    const int*   bond    = (const int*)d_in[3];
    const float* W_nb    = (const float*)d_in[4];
    const float* b_nb    = (const float*)d_in[5];
    const float* W_nout  = (const float*)d_in[6];
    const float* b_nout  = (const float*)d_in[7];
    const float* conv_w  = (const float*)d_in[8];
    const float* conv_b  = (const float*)d_in[9];
    const float* W_el    = (const float*)d_in[10];
    const float* b_el    = (const float*)d_in[11];
    const float* W_eout  = (const float*)d_in[12];
    const float* b_eout  = (const float*)d_in[13];
    const float* W_coord = (const float*)d_in[14];
    const float* b_coord = (const float*)d_in[15];
    const float* W_pair  = (const float*)d_in[16];
    const float* b_pair  = (const float*)d_in[17];
    const float* W_sout  = (const float*)d_in[18];
    const float* b_sout  = (const float*)d_in[19];
    const float* W_init  = (const float*)d_in[20];
    const float* feat_lin= (const float*)d_in[21];
    const float* W_att   = (const float*)d_in[22];
    const float* W_agg   = (const float*)d_in[23];
    const float* gamma   = (const float*)d_in[24];
    const float* beta    = (const float*)d_in[25];

    const int N = in_sizes[0] / DD;     // 50000
    const int E = in_sizes[3];          // 800000
    const size_t ND = (size_t)N * DD;
    const int SUB = DD * DD;
    const int NBS = (N + 63) / 64;

    char* base = (char*)d_ws;
    size_t off = 0;
    auto alloc = [&](size_t bytes) -> char* {
        char* p = base + off;
        off = (off + bytes + 63) & ~(size_t)63;
        return p;
    };
    u16*   G    = (u16*)alloc((size_t)N * 384 * 2);
    u16*   xWs  = (u16*)alloc(ND * 2);
    float* At   = (float*)alloc(ND * 4);
    float* Bt   = (float*)alloc(ND * 4);
    float* Ct   = (float*)alloc(ND * 4);
    u16*   e0   = (u16*)alloc(ND * 2);
    u16*   Pn   = (u16*)alloc(ND * 2);
    u16*   Pe   = (u16*)alloc(ND * 2);
    float* z    = (float*)alloc(ND * 4);
    u16*   Wh   = (u16*)alloc((size_t)18 * WT * 2);
    u16*   Wl   = (u16*)alloc((size_t)18 * WT * 2);
    int2*  csr  = (int2*)alloc((size_t)E * 8);
    int*   deg    = (int*)alloc((size_t)N * 4);
    int*   rowptr = (int*)alloc((size_t)(N + 1) * 4);
    int*   cursor = (int*)alloc((size_t)N * 4);
    float* s_arr  = (float*)alloc((size_t)N * 4);
    float* bnsums  = (float*)alloc(256 * 4);
    float* bnscale = (float*)alloc(128 * 4);
    float* bnshift = (float*)alloc(128 * 4);

    float* hout = (float*)d_out;

    WSrc wsrc;
    wsrc.p[0] = W_nb;            wsrc.p[1] = W_nb + SUB;
    wsrc.p[2] = W_el;            wsrc.p[3] = W_el + SUB;
    wsrc.p[4] = W_coord;         wsrc.p[5] = W_sout;
    wsrc.p[6] = W_init;          wsrc.p[7] = W_att;
    wsrc.p[8] = W_coord + SUB;   wsrc.p[9] = W_pair;
    wsrc.p[10] = W_sout + SUB;   wsrc.p[11] = W_nout;
    wsrc.p[12] = W_eout;         wsrc.p[13] = feat_lin;
    wsrc.p[14] = feat_lin + SUB; wsrc.p[15] = feat_lin + 2 * SUB;
    wsrc.p[16] = W_att + SUB;    wsrc.p[17] = W_agg;

    const dim3 blk(256);
    const dim3 gE((E + 255) / 256);
    const size_t total4 = ND / 4;
    const dim3 gElem((unsigned)((total4 + 255) / 256));

    prep_weights<<<dim3(18 * 8), blk, 0, stream>>>(wsrc, Wh, Wl);
    frontend_kernel<<<NBS, blk, 0, stream>>>(x, Wh, Wl, G, xWs, At, Bt, Ct, e0, N);

    hipMemsetAsync(deg, 0, (size_t)N * 4, stream);
    hist_kernel<<<gE, blk, 0, stream>>>(ei, deg, E);
    scan_kernel<<<1, 1024, 0, stream>>>(deg, rowptr, cursor, N);
    scatter_kernel<<<gE, blk, 0, stream>>>(ei, bond, coords, cursor, csr, E);

    edge_agg<<<(N + 3) / 4, blk, 0, stream>>>(At, Bt, G, rowptr, csr, conv_w, conv_b,
                                              b_nb, b_el, Pn, Pe, z, s_arr, N);

    paths_kernel<<<NBS, blk, 0, stream>>>(Pn, Pe, z, Ct, xWs, e0, s_arr, deg,
                                          b_nout, b_eout, b_coord, b_pair, b_sout,
                                          Wh, Wl, hout, N);

    hipMemsetAsync(bnsums, 0, 256 * 4, stream);
    bn_stats<<<512, blk, 0, stream>>>(hout, bnsums, N);
    bn_finalize<<<1, 128, 0, stream>>>(bnsums, gamma, beta, bnscale, bnshift, 1.0f / (float)N);
    bn_apply<<<gElem, blk, 0, stream>>>(hout, bnscale, bnshift, total4);
}

// Round 5
// 860.655 us; speedup vs baseline: 1.2271x; 1.2271x over previous
//
#include <hip/hip_runtime.h>
#include <math.h>

#define DD 128
#define LDSS 136   // u16 LDS row stride (128 + 8 pad)
#define WT 16384   // u16 elements per packed 128x128 weight matrix

typedef __attribute__((ext_vector_type(8))) short bf16x8;
typedef __attribute__((ext_vector_type(4))) float f32x4;
typedef unsigned short u16;
typedef unsigned int u32;

__device__ __forceinline__ u16 f2bf(float f) {          // RNE (for stored tensors)
    u32 u = __builtin_bit_cast(u32, f);
    u += 0x7fffu + ((u >> 16) & 1u);
    return (u16)(u >> 16);
}
__device__ __forceinline__ float bf2f(u16 h) {
    u32 u = ((u32)h) << 16;
    return __builtin_bit_cast(float, u);
}
__device__ __forceinline__ float mishf(float x) {
    float e = __expf(fminf(x, 15.0f));
    float n = e * (e + 2.0f);
    return x * n * __builtin_amdgcn_rcpf(n + 2.0f);
}
// cheap truncating hi/lo split: err(hi)<=2^-8, reconstruction err ~2^-16 — 3 VALU ops
__device__ __forceinline__ void splitv(float v, u16& h, u16& l) {
    u32 u = __builtin_bit_cast(u32, v);
    h = (u16)(u >> 16);
    float r = v - __builtin_bit_cast(float, u & 0xffff0000u);
    l = (u16)(__builtin_bit_cast(u32, r) >> 16);
}

// NM=1: ah*bh ; NM=2: ah*(bh+bl) [A exact-bf16] ; NM=3: + al*bh [A split]
template<int NM>
__device__ __forceinline__ void gemm8(const bf16x8* ah, const bf16x8* al,
    const u16* __restrict__ Wh, const u16* __restrict__ Wl, int lane, f32x4* acc)
{
#pragma unroll
    for (int kb = 0; kb < 4; kb++)
#pragma unroll
        for (int nt = 0; nt < 8; nt++) {
            size_t boff = (((size_t)kb * 8 + nt) * 64 + lane) * 8;
            bf16x8 bh = *(const bf16x8*)(Wh + boff);
            acc[nt] = __builtin_amdgcn_mfma_f32_16x16x32_bf16(ah[kb], bh, acc[nt], 0, 0, 0);
            if (NM >= 2) {
                bf16x8 bl = *(const bf16x8*)(Wl + boff);
                acc[nt] = __builtin_amdgcn_mfma_f32_16x16x32_bf16(ah[kb], bl, acc[nt], 0, 0, 0);
            }
            if (NM == 3)
                acc[nt] = __builtin_amdgcn_mfma_f32_16x16x32_bf16(al[kb], bh, acc[nt], 0, 0, 0);
        }
}

__device__ __forceinline__ void zero_acc(f32x4* acc) {
#pragma unroll
    for (int nt = 0; nt < 8; nt++) { f32x4 z4 = {0.f, 0.f, 0.f, 0.f}; acc[nt] = z4; }
}

// A-fragment (hi only) from a global bf16 [M,128] matrix
__device__ __forceinline__ void frag_hi_global(const u16* __restrict__ src, int row0,
                                               int lm, int quad, int M, bf16x8* ah)
{
    int row = row0 + lm; if (row >= M) row = M - 1;
    const u16* p = src + (size_t)row * DD + quad * 8;
#pragma unroll
    for (int kb = 0; kb < 4; kb++) ah[kb] = *(const bf16x8*)(p + kb * 32);
}
// split A-fragments from a global fp32 [M,128] matrix
__device__ __forceinline__ void frag_split_global(const float* __restrict__ src, int row0,
                                                  int lm, int quad, int M, bf16x8* ah, bf16x8* al)
{
    int row = row0 + lm; if (row >= M) row = M - 1;
    const float* p = src + (size_t)row * DD + quad * 8;
#pragma unroll
    for (int kb = 0; kb < 4; kb++) {
        float tmp[8];
        *(float4*)tmp       = *(const float4*)(p + kb * 32);
        *(float4*)(tmp + 4) = *(const float4*)(p + kb * 32 + 4);
#pragma unroll
        for (int j = 0; j < 8; j++) { u16 h, l; splitv(tmp[j], h, l); ah[kb][j] = (short)h; al[kb][j] = (short)l; }
    }
}
// split A-fragments from the wave-private LDS hi/lo planes
__device__ __forceinline__ void frag_planes(const u16* pH, const u16* pL, int wave,
                                            int lm, int quad, bf16x8* ah, bf16x8* al)
{
    const u16* ph = pH + (size_t)(wave * 16 + lm) * LDSS + quad * 8;
    const u16* pl = pL + (size_t)(wave * 16 + lm) * LDSS + quad * 8;
#pragma unroll
    for (int kb = 0; kb < 4; kb++) {
        ah[kb] = *(const bf16x8*)(ph + kb * 32);
        al[kb] = *(const bf16x8*)(pl + kb * 32);
    }
}

// ============ weight prep ============
struct WSrc { const float* p[18]; };

__global__ __launch_bounds__(256) void prep_weights(WSrc ws, u16* __restrict__ Wh, u16* __restrict__ Wl)
{
    int mat = blockIdx.x >> 3, chunk = blockIdx.x & 7;
    int t = threadIdx.x;
    int tt = chunk * 4 + (t >> 6);
    int lane = t & 63;
    int kb = tt >> 3, nt = tt & 7;
    const float* __restrict__ src = ws.p[mat];
    size_t doff = (size_t)mat * WT + ((size_t)tt * 64 + lane) * 8;
    int srow = kb * 32 + ((lane >> 4) * 8);
    int scol = nt * 16 + (lane & 15);
    u16 th[8], tl[8];
#pragma unroll
    for (int j = 0; j < 8; j++) {
        float v = src[(srow + j) * DD + scol];
        u16 h = f2bf(v);
        th[j] = h;
        tl[j] = f2bf(v - bf2f(h));
    }
    *(bf16x8*)(Wh + doff) = *(bf16x8*)th;
    *(bf16x8*)(Wl + doff) = *(bf16x8*)tl;
}

// ============ front1: G(As,Bs,xb) + xWs (hi-only GEMMs) ============
__global__ __launch_bounds__(256, 3) void front1_kernel(
    const float* __restrict__ x, const u16* __restrict__ Wh,
    u16* __restrict__ G, u16* __restrict__ xWs, int M)
{
    __shared__ u16 sA[64 * LDSS], sB[64 * LDSS], sX[64 * LDSS];
    const int t = threadIdx.x, wave = t >> 6, lane = t & 63;
    const int lm = lane & 15, quad = lane >> 4;
    const int rowBase = blockIdx.x * 64;
    const int row0 = rowBase + wave * 16;

    bf16x8 ah[4];
    {
        int row = row0 + lm; if (row >= M) row = M - 1;
        const float* p = x + (size_t)row * DD + quad * 8;
        int arow = wave * 16 + lm;
#pragma unroll
        for (int kb = 0; kb < 4; kb++) {
            float tmp[8];
            *(float4*)tmp       = *(const float4*)(p + kb * 32);
            *(float4*)(tmp + 4) = *(const float4*)(p + kb * 32 + 4);
#pragma unroll
            for (int j = 0; j < 8; j++) {
                ah[kb][j] = (short)(u16)(__builtin_bit_cast(u32, tmp[j]) >> 16); // trunc for GEMM A
                sX[arow * LDSS + kb * 32 + quad * 8 + j] = f2bf(tmp[j]);          // RNE xb plane
            }
        }
    }
    {   // As = x@W1 -> sA
        f32x4 acc[8]; zero_acc(acc);
        gemm8<1>(ah, ah, Wh + 1 * WT, Wh, lane, acc);
#pragma unroll
        for (int r = 0; r < 4; r++)
#pragma unroll
            for (int nt = 0; nt < 8; nt++)
                sA[(wave * 16 + quad * 4 + r) * LDSS + nt * 16 + lm] = f2bf(acc[nt][r]);
    }
    {   // Bs = x@W3 -> sB
        f32x4 acc[8]; zero_acc(acc);
        gemm8<1>(ah, ah, Wh + 3 * WT, Wh, lane, acc);
#pragma unroll
        for (int r = 0; r < 4; r++)
#pragma unroll
            for (int nt = 0; nt < 8; nt++)
                sB[(wave * 16 + quad * 4 + r) * LDSS + nt * 16 + lm] = f2bf(acc[nt][r]);
    }
    __syncthreads();
#pragma unroll
    for (int i = 0; i < 16; i++) {      // interleave G: 12B per lane per row
        int r = wave + i * 4;
        int grow = rowBase + r;
        u32 ga = *(const u32*)&sA[r * LDSS + lane * 2];
        u32 gb = *(const u32*)&sB[r * LDSS + lane * 2];
        u32 gx = *(const u32*)&sX[r * LDSS + lane * 2];
        if (grow < M) {
            u16* gp = G + (size_t)grow * 384 + lane * 6;
            *(u32*)gp       = ga;
            *(u32*)(gp + 2) = gb;
            *(u32*)(gp + 4) = gx;
        }
    }
    {   // xWs = x@W5 -> global bf16
        f32x4 acc[8]; zero_acc(acc);
        gemm8<1>(ah, ah, Wh + 5 * WT, Wh, lane, acc);
#pragma unroll
        for (int r = 0; r < 4; r++) {
            int grow = row0 + quad * 4 + r;
            if (grow >= M) continue;
#pragma unroll
            for (int nt = 0; nt < 8; nt++)
                xWs[(size_t)grow * DD + nt * 16 + lm] = f2bf(acc[nt][r]);
        }
    }
}

// ============ front2: At, Bt, Ct (split fp32) + e0 ============
__global__ __launch_bounds__(256, 3) void front2_kernel(
    const float* __restrict__ x, const u16* __restrict__ Wh, const u16* __restrict__ Wl,
    float* __restrict__ At, float* __restrict__ Bt, float* __restrict__ Ct,
    u16* __restrict__ e0, int M)
{
    __shared__ u16 sH[64 * LDSS];
    const int t = threadIdx.x, wave = t >> 6, lane = t & 63;
    const int lm = lane & 15, quad = lane >> 4;
    const int row0 = blockIdx.x * 64 + wave * 16;

    bf16x8 ah[4], al[4];
    frag_split_global(x, row0, lm, quad, M, ah, al);

    float* outs[3] = {At, Bt, Ct};
    const int mats[3] = {0, 2, 4};
#pragma unroll
    for (int wi = 0; wi < 3; wi++) {
        f32x4 acc[8]; zero_acc(acc);
        gemm8<3>(ah, al, Wh + (size_t)mats[wi] * WT, Wl + (size_t)mats[wi] * WT, lane, acc);
        float* out = outs[wi];
#pragma unroll
        for (int r = 0; r < 4; r++) {
            int grow = row0 + quad * 4 + r;
            if (grow >= M) continue;
#pragma unroll
            for (int nt = 0; nt < 8; nt++)
                out[(size_t)grow * DD + nt * 16 + lm] = acc[nt][r];
        }
    }
    {   // lin2 = mish2(x@W6) -> sH (wave-private band)
        f32x4 acc[8]; zero_acc(acc);
        gemm8<1>(ah, ah, Wh + 6 * WT, Wh, lane, acc);
#pragma unroll
        for (int r = 0; r < 4; r++)
#pragma unroll
            for (int nt = 0; nt < 8; nt++)
                sH[(wave * 16 + quad * 4 + r) * LDSS + nt * 16 + lm] = f2bf(mishf(mishf(acc[nt][r])));
    }
    {   // e0 = lin2@W7 -> global bf16
        bf16x8 lh[4];
        const u16* p = &sH[(size_t)(wave * 16 + lm) * LDSS + quad * 8];
#pragma unroll
        for (int kb = 0; kb < 4; kb++) lh[kb] = *(const bf16x8*)(p + kb * 32);
        f32x4 acc[8]; zero_acc(acc);
        gemm8<1>(lh, lh, Wh + 7 * WT, Wh, lane, acc);
#pragma unroll
        for (int r = 0; r < 4; r++) {
            int grow = row0 + quad * 4 + r;
            if (grow >= M) continue;
#pragma unroll
            for (int nt = 0; nt < 8; nt++)
                e0[(size_t)grow * DD + nt * 16 + lm] = f2bf(acc[nt][r]);
        }
    }
}

// ============ CSR build ============
__global__ __launch_bounds__(256) void hist_kernel(const int* __restrict__ ei, int* __restrict__ deg, int E)
{
    int e = blockIdx.x * 256 + threadIdx.x;
    if (e < E) atomicAdd(&deg[ei[E + e]], 1);
}

__global__ __launch_bounds__(1024) void scan_kernel(const int* __restrict__ deg,
                                                    int* __restrict__ rowptr,
                                                    int* __restrict__ cursor, int N)
{
    __shared__ int sums[1024];
    int t = threadIdx.x;
    int CH = (N + 1023) / 1024;
    int base = t * CH;
    int local = 0;
    for (int i = 0; i < CH; i++) {
        int idx = base + i;
        if (idx < N) local += deg[idx];
    }
    sums[t] = local;
    __syncthreads();
    for (int off = 1; off < 1024; off <<= 1) {
        int v = sums[t];
        int u = (t >= off) ? sums[t - off] : 0;
        __syncthreads();
        sums[t] = v + u;
        __syncthreads();
    }
    int run = (t == 0) ? 0 : sums[t - 1];
    for (int i = 0; i < CH; i++) {
        int idx = base + i;
        if (idx < N) {
            rowptr[idx] = run;
            cursor[idx] = run;
            run += deg[idx];
        }
    }
    if (t == 1023) rowptr[N] = sums[1023];
}

__global__ __launch_bounds__(256) void scatter_kernel(
    const int* __restrict__ ei, const int* __restrict__ bond,
    const float* __restrict__ coords, int* __restrict__ cursor,
    int2* __restrict__ csr, int E)
{
    int e = blockIdx.x * 256 + threadIdx.x;
    if (e >= E) return;
    int src = ei[e], dst = ei[E + e];
    int pos = atomicAdd(&cursor[dst], 1);
    float dx = coords[src * 3 + 0] - coords[dst * 3 + 0];
    float dy = coords[src * 3 + 1] - coords[dst * 3 + 1];
    float dz = coords[src * 3 + 2] - coords[dst * 3 + 2];
    float d2 = dx * dx + dy * dy + dz * dz;
    csr[pos] = make_int2(src | (bond[e] << 20), __float_as_int(d2));
}

// ============ per-node edge aggregation (interleaved gather) ============
__global__ __launch_bounds__(256) void edge_agg(
    const float* __restrict__ At, const float* __restrict__ Bt,
    const u16* __restrict__ G,
    const int* __restrict__ rowptr, const int2* __restrict__ csr,
    const float* __restrict__ conv_w, const float* __restrict__ conv_b,
    const float* __restrict__ b_nb, const float* __restrict__ b_el,
    u16* __restrict__ Pn, u16* __restrict__ Pe, float* __restrict__ z,
    float* __restrict__ s_arr, int N)
{
    int wave = threadIdx.x >> 6;
    int lane = threadIdx.x & 63;
    int node = blockIdx.x * 4 + wave;
    if (node >= N) return;
    int c0 = lane * 2;
    float2 at = *(const float2*)(At + (size_t)node * DD + c0);
    float2 bt = *(const float2*)(Bt + (size_t)node * DD + c0);
    float cb = conv_b[0];
    float cw0 = conv_w[0] + cb, cw1 = conv_w[1] + cb, cw2 = conv_w[2] + cb, cw3 = conv_w[3] + cb;
    float bn0 = b_nb[c0], bn1 = b_nb[c0 + 1];
    float be0 = b_el[c0], be1 = b_el[c0 + 1];
    float accn0 = 0.f, accn1 = 0.f, acce0 = 0.f, acce1 = 0.f, accz0 = 0.f, accz1 = 0.f, ssum = 0.f;
    int beg = rowptr[node], end = rowptr[node + 1];
    for (int k = beg; k < end; k++) {
        int2 pd = csr[k];
        int src = pd.x & 0xFFFFF;
        int bond = (pd.x >> 20) & 3;
        float w = (bond == 0) ? cw0 : (bond == 1) ? cw1 : (bond == 2) ? cw2 : cw3;
        float d2 = __int_as_float(pd.y);
        const u16* gp = G + (size_t)src * 384 + lane * 6;
        u32 ga = *(const u32*)gp;
        u32 gb = *(const u32*)(gp + 2);
        u32 gx = *(const u32*)(gp + 4);
        float a0 = __builtin_bit_cast(float, ga << 16), a1 = __builtin_bit_cast(float, ga & 0xffff0000u);
        float b0 = __builtin_bit_cast(float, gb << 16), b1 = __builtin_bit_cast(float, gb & 0xffff0000u);
        float x0 = __builtin_bit_cast(float, gx << 16), x1 = __builtin_bit_cast(float, gx & 0xffff0000u);
        accn0 += mishf(at.x + a0 + bn0);
        accn1 += mishf(at.y + a1 + bn1);
        acce0 += mishf(w * (bt.x + b0) + be0);
        acce1 += mishf(w * (bt.y + b1) + be1);
        accz0 += d2 * x0;
        accz1 += d2 * x1;
        ssum += d2;
    }
    *(u32*)(Pn + (size_t)node * DD + c0) = (u32)f2bf(accn0) | ((u32)f2bf(accn1) << 16);
    *(u32*)(Pe + (size_t)node * DD + c0) = (u32)f2bf(acce0) | ((u32)f2bf(acce1) << 16);
    *(float2*)(z + (size_t)node * DD + c0) = make_float2(accz0, accz1);
    if (lane == 0) s_arr[node] = ssum;
}

// ============ backend: 3 path-chains in parallel (blockIdx.y = path) ============
__global__ __launch_bounds__(256, 3) void backend_kernel(
    const u16* __restrict__ Pn, const u16* __restrict__ Pe, const float* __restrict__ z,
    const float* __restrict__ Ct, const u16* __restrict__ xWs, const u16* __restrict__ e0,
    const float* __restrict__ s_arr, const int* __restrict__ deg,
    const float* __restrict__ b_nout, const float* __restrict__ b_eout,
    const float* __restrict__ b_coord, const float* __restrict__ b_pair,
    const float* __restrict__ b_sout,
    const u16* __restrict__ Wh, const u16* __restrict__ Wl,
    u16* __restrict__ f1, u16* __restrict__ f2, u16* __restrict__ f3,
    float* __restrict__ e1, float* __restrict__ e2, float* __restrict__ e3, int M)
{
    __shared__ u16 pH[64 * LDSS], pL[64 * LDSS];    // hi/lo planes, wave-private bands
    const int t = threadIdx.x, wave = t >> 6, lane = t & 63;
    const int lm = lane & 15, quad = lane >> 4;
    const int row0 = blockIdx.x * 64 + wave * 16;
    const int path = blockIdx.y;

    bf16x8 ah[4], al[4];
    f32x4 acc[8];

    if (path < 2) {
        const u16* P = (path == 0) ? Pn : Pe;
        const float* bo = (path == 0) ? b_nout : b_eout;
        u16* fO = (path == 0) ? f1 : f2;
        float* eO = (path == 0) ? e1 : e2;
        const int mO = 11 + path, mF = 13 + path;
        // stage 1: f = mish(P@W_out + b_out)
        frag_hi_global(P, row0, lm, quad, M, ah);
        zero_acc(acc);
        gemm8<2>(ah, ah, Wh + (size_t)mO * WT, Wl + (size_t)mO * WT, lane, acc);
#pragma unroll
        for (int r = 0; r < 4; r++) {
            int grow = row0 + quad * 4 + r;
            bool inb = grow < M;
#pragma unroll
            for (int nt = 0; nt < 8; nt++) {
                int col = nt * 16 + lm;
                float v = mishf(acc[nt][r] + bo[col]);
                if (inb) fO[(size_t)grow * DD + col] = f2bf(v);
                int lidx = (wave * 16 + quad * 4 + r) * LDSS + col;
                u16 h, l; splitv(v, h, l); pH[lidx] = h; pL[lidx] = l;
            }
        }
        // stage 2: l = mish2(f@FL)
        frag_planes(pH, pL, wave, lm, quad, ah, al);
        zero_acc(acc);
        gemm8<3>(ah, al, Wh + (size_t)mF * WT, Wl + (size_t)mF * WT, lane, acc);
#pragma unroll
        for (int r = 0; r < 4; r++)
#pragma unroll
            for (int nt = 0; nt < 8; nt++) {
                int lidx = (wave * 16 + quad * 4 + r) * LDSS + nt * 16 + lm;
                u16 h, l; splitv(mishf(mishf(acc[nt][r])), h, l); pH[lidx] = h; pL[lidx] = l;
            }
        // stage 3: e = l@Wa_b + e0
        frag_planes(pH, pL, wave, lm, quad, ah, al);
        zero_acc(acc);
        gemm8<3>(ah, al, Wh + 16 * WT, Wl + 16 * WT, lane, acc);
#pragma unroll
        for (int r = 0; r < 4; r++) {
            int grow = row0 + quad * 4 + r;
            if (grow >= M) continue;
#pragma unroll
            for (int nt = 0; nt < 8; nt++) {
                int col = nt * 16 + lm;
                eO[(size_t)grow * DD + col] = acc[nt][r] + bf2f(e0[(size_t)grow * DD + col]);
            }
        }
    } else {
        // stage 1: Qagg = z@Wc_s + s*Ct + deg*b_coord
        frag_split_global(z, row0, lm, quad, M, ah, al);
        zero_acc(acc);
        gemm8<3>(ah, al, Wh + 8 * WT, Wl + 8 * WT, lane, acc);
#pragma unroll
        for (int r = 0; r < 4; r++) {
            int crow = row0 + quad * 4 + r; if (crow >= M) crow = M - 1;
            float sv = s_arr[crow];
            float dv = (float)deg[crow];
#pragma unroll
            for (int nt = 0; nt < 8; nt++) {
                int col = nt * 16 + lm;
                float v = acc[nt][r] + sv * Ct[(size_t)crow * DD + col] + dv * b_coord[col];
                int lidx = (wave * 16 + quad * 4 + r) * LDSS + col;
                u16 h, l; splitv(v, h, l); pH[lidx] = h; pL[lidx] = l;
            }
        }
        // stage 2: Q = mish(Qagg@W_pair + b_pair)
        frag_planes(pH, pL, wave, lm, quad, ah, al);
        zero_acc(acc);
        gemm8<3>(ah, al, Wh + 9 * WT, Wl + 9 * WT, lane, acc);
#pragma unroll
        for (int r = 0; r < 4; r++)
#pragma unroll
            for (int nt = 0; nt < 8; nt++) {
                int col = nt * 16 + lm;
                int lidx = (wave * 16 + quad * 4 + r) * LDSS + col;
                u16 h, l; splitv(mishf(acc[nt][r] + b_pair[col]), h, l); pH[lidx] = h; pL[lidx] = l;
            }
        // stage 3: f_struct = mish(Q@Ws_b + xWs + b_sout)
        frag_planes(pH, pL, wave, lm, quad, ah, al);
        zero_acc(acc);
        gemm8<3>(ah, al, Wh + 10 * WT, Wl + 10 * WT, lane, acc);
#pragma unroll
        for (int r = 0; r < 4; r++) {
            int crow = row0 + quad * 4 + r; if (crow >= M) crow = M - 1;
            bool inb = (row0 + quad * 4 + r) < M;
#pragma unroll
            for (int nt = 0; nt < 8; nt++) {
                int col = nt * 16 + lm;
                float v = mishf(acc[nt][r] + bf2f(xWs[(size_t)crow * DD + col]) + b_sout[col]);
                if (inb) f3[(size_t)crow * DD + col] = f2bf(v);
                int lidx = (wave * 16 + quad * 4 + r) * LDSS + col;
                u16 h, l; splitv(v, h, l); pH[lidx] = h; pL[lidx] = l;
            }
        }
        // stage 4: l2 = mish2(f_struct@FL2)
        frag_planes(pH, pL, wave, lm, quad, ah, al);
        zero_acc(acc);
        gemm8<3>(ah, al, Wh + 15 * WT, Wl + 15 * WT, lane, acc);
#pragma unroll
        for (int r = 0; r < 4; r++)
#pragma unroll
            for (int nt = 0; nt < 8; nt++) {
                int lidx = (wave * 16 + quad * 4 + r) * LDSS + nt * 16 + lm;
                u16 h, l; splitv(mishf(mishf(acc[nt][r])), h, l); pH[lidx] = h; pL[lidx] = l;
            }
        // stage 5: e3 = l2@Wa_b + e0
        frag_planes(pH, pL, wave, lm, quad, ah, al);
        zero_acc(acc);
        gemm8<3>(ah, al, Wh + 16 * WT, Wl + 16 * WT, lane, acc);
#pragma unroll
        for (int r = 0; r < 4; r++) {
            int grow = row0 + quad * 4 + r;
            if (grow >= M) continue;
#pragma unroll
            for (int nt = 0; nt < 8; nt++) {
                int col = nt * 16 + lm;
                e3[(size_t)grow * DD + col] = acc[nt][r] + bf2f(e0[(size_t)grow * DD + col]);
            }
        }
    }
}

// ============ softmax combine + @W_agg ============
__global__ __launch_bounds__(256, 3) void attagg_kernel(
    const float* __restrict__ e1, const float* __restrict__ e2, const float* __restrict__ e3,
    const u16* __restrict__ f1, const u16* __restrict__ f2, const u16* __restrict__ f3,
    const u16* __restrict__ Wh, const u16* __restrict__ Wl, float* __restrict__ hout, int M)
{
    __shared__ u16 pH[64 * LDSS], pL[64 * LDSS];
    const int t = threadIdx.x, wave = t >> 6, lane = t & 63;
    const int lm = lane & 15, quad = lane >> 4;
    const int row0 = blockIdx.x * 64 + wave * 16;

#pragma unroll
    for (int r = 0; r < 4; r++) {
        int crow = row0 + quad * 4 + r; if (crow >= M) crow = M - 1;
#pragma unroll
        for (int nt = 0; nt < 8; nt++) {
            int col = nt * 16 + lm;
            size_t idx = (size_t)crow * DD + col;
            float x1 = e1[idx], x2 = e2[idx], x3 = e3[idx];
            float m = fmaxf(fmaxf(x1, x2), x3);
            float p1 = __expf(x1 - m), p2 = __expf(x2 - m), p3 = __expf(x3 - m);
            float att = (p1 * bf2f(f1[idx]) + p2 * bf2f(f2[idx]) + p3 * bf2f(f3[idx]))
                        * __builtin_amdgcn_rcpf(p1 + p2 + p3);
            int lidx = (wave * 16 + quad * 4 + r) * LDSS + col;
            u16 h, l; splitv(att, h, l); pH[lidx] = h; pL[lidx] = l;
        }
    }
    bf16x8 ah[4], al[4];
    frag_planes(pH, pL, wave, lm, quad, ah, al);
    f32x4 acc[8]; zero_acc(acc);
    gemm8<3>(ah, al, Wh + 17 * WT, Wl + 17 * WT, lane, acc);
#pragma unroll
    for (int r = 0; r < 4; r++) {
        int grow = row0 + quad * 4 + r;
        if (grow >= M) continue;
#pragma unroll
        for (int nt = 0; nt < 8; nt++)
            hout[(size_t)grow * DD + nt * 16 + lm] = acc[nt][r];
    }
}

// ============ batchnorm ============
__global__ __launch_bounds__(256) void bn_stats(const float* __restrict__ h, float* __restrict__ sums, int N)
{
    int t = threadIdx.x;
    int col = t & 127;
    float s = 0.f, sq = 0.f;
    for (int r = blockIdx.x * 2 + (t >> 7); r < N; r += gridDim.x * 2) {
        float v = h[(size_t)r * DD + col];
        s += v; sq += v * v;
    }
    __shared__ float sh[256];
    sh[t] = s; __syncthreads();
    float s2 = (t < 128) ? (sh[t] + sh[t + 128]) : 0.f;
    __syncthreads();
    sh[t] = sq; __syncthreads();
    if (t < 128) {
        float q2 = sh[t] + sh[t + 128];
        atomicAdd(&sums[t], s2);
        atomicAdd(&sums[128 + t], q2);
    }
}

__global__ void bn_finalize(const float* __restrict__ sums, const float* __restrict__ gamma,
                            const float* __restrict__ beta, float* __restrict__ scale,
                            float* __restrict__ shift, float n_inv)
{
    int c = threadIdx.x;
    float mean = sums[c] * n_inv;
    float var = sums[128 + c] * n_inv - mean * mean;
    float inv = rsqrtf(var + 1e-5f);
    float sc = gamma[c] * inv;
    scale[c] = sc;
    shift[c] = beta[c] - mean * sc;
}

__global__ __launch_bounds__(256) void bn_apply(float* __restrict__ h, const float* __restrict__ scale,
                                                const float* __restrict__ shift, size_t total4)
{
    size_t idx = (size_t)blockIdx.x * 256 + threadIdx.x;
    if (idx >= total4) return;
    size_t off = idx * 4;
    int c = (int)(off & 127);
    float4 v = *(const float4*)(h + off);
    float4 sc = *(const float4*)(scale + c);
    float4 sh = *(const float4*)(shift + c);
    v.x = mishf(v.x * sc.x + sh.x);
    v.y = mishf(v.y * sc.y + sh.y);
    v.z = mishf(v.z * sc.z + sh.z);
    v.w = mishf(v.w * sc.w + sh.w);
    *(float4*)(h + off) = v;
}

// ============ host ============
extern "C" void kernel_launch(void* const* d_in, const int* in_sizes, int n_in,
                              void* d_out, int out_size, void* d_ws, size_t ws_size,
                              hipStream_t stream)
{
    (void)n_in; (void)out_size; (void)ws_size;
    const float* x       = (const float*)d_in[0];
    const float* coords  = (const float*)d_in[1];
    const int*   ei      = (const int*)d_in[2];
    const int*   bond    = (const int*)d_in[3];
    const float* W_nb    = (const float*)d_in[4];
    const float* b_nb    = (const float*)d_in[5];
    const float* W_nout  = (const float*)d_in[6];
    const float* b_nout  = (const float*)d_in[7];
    const float* conv_w  = (const float*)d_in[8];
    const float* conv_b  = (const float*)d_in[9];
    const float* W_el    = (const float*)d_in[10];
    const float* b_el    = (const float*)d_in[11];
    const float* W_eout  = (const float*)d_in[12];
    const float* b_eout  = (const float*)d_in[13];
    const float* W_coord = (const float*)d_in[14];
    const float* b_coord = (const float*)d_in[15];
    const float* W_pair  = (const float*)d_in[16];
    const float* b_pair  = (const float*)d_in[17];
    const float* W_sout  = (const float*)d_in[18];
    const float* b_sout  = (const float*)d_in[19];
    const float* W_init  = (const float*)d_in[20];
    const float* feat_lin= (const float*)d_in[21];
    const float* W_att   = (const float*)d_in[22];
    const float* W_agg   = (const float*)d_in[23];
    const float* gamma   = (const float*)d_in[24];
    const float* beta    = (const float*)d_in[25];

    const int N = in_sizes[0] / DD;     // 50000
    const int E = in_sizes[3];          // 800000
    const size_t ND = (size_t)N * DD;
    const int SUB = DD * DD;
    const int NBS = (N + 63) / 64;

    char* base = (char*)d_ws;
    size_t off = 0;
    auto alloc = [&](size_t bytes) -> char* {
        char* p = base + off;
        off = (off + bytes + 63) & ~(size_t)63;
        return p;
    };
    u16*   G    = (u16*)alloc((size_t)N * 384 * 2);
    u16*   xWs  = (u16*)alloc(ND * 2);
    float* At   = (float*)alloc(ND * 4);   // dead after edge_agg -> aliased as e1
    float* Bt   = (float*)alloc(ND * 4);   // dead after edge_agg -> aliased as e2
    float* Ct   = (float*)alloc(ND * 4);
    u16*   e0   = (u16*)alloc(ND * 2);
    u16*   Pn   = (u16*)alloc(ND * 2);
    u16*   Pe   = (u16*)alloc(ND * 2);
    float* z    = (float*)alloc(ND * 4);   // consumed in backend stage1 -> aliased as e3
    u16*   f1   = (u16*)alloc(ND * 2);
    u16*   f2   = (u16*)alloc(ND * 2);
    u16*   f3   = (u16*)alloc(ND * 2);
    u16*   Wh   = (u16*)alloc((size_t)18 * WT * 2);
    u16*   Wl   = (u16*)alloc((size_t)18 * WT * 2);
    int2*  csr  = (int2*)alloc((size_t)E * 8);
    int*   deg    = (int*)alloc((size_t)N * 4);
    int*   rowptr = (int*)alloc((size_t)(N + 1) * 4);
    int*   cursor = (int*)alloc((size_t)N * 4);
    float* s_arr  = (float*)alloc((size_t)N * 4);
    float* bnsums  = (float*)alloc(256 * 4);
    float* bnscale = (float*)alloc(128 * 4);
    float* bnshift = (float*)alloc(128 * 4);

    float* hout = (float*)d_out;
    float* e1 = At;   // safe: At/Bt dead after edge_agg completes (stream order)
    float* e2 = Bt;
    float* e3 = z;    // safe: same block reads z (stage1) before writing e3 (stage5), same rows

    WSrc wsrc;
    wsrc.p[0] = W_nb;            wsrc.p[1] = W_nb + SUB;
    wsrc.p[2] = W_el;            wsrc.p[3] = W_el + SUB;
    wsrc.p[4] = W_coord;         wsrc.p[5] = W_sout;
    wsrc.p[6] = W_init;          wsrc.p[7] = W_att;
    wsrc.p[8] = W_coord + SUB;   wsrc.p[9] = W_pair;
    wsrc.p[10] = W_sout + SUB;   wsrc.p[11] = W_nout;
    wsrc.p[12] = W_eout;         wsrc.p[13] = feat_lin;
    wsrc.p[14] = feat_lin + SUB; wsrc.p[15] = feat_lin + 2 * SUB;
    wsrc.p[16] = W_att + SUB;    wsrc.p[17] = W_agg;

    const dim3 blk(256);
    const dim3 gE((E + 255) / 256);
    const size_t total4 = ND / 4;
    const dim3 gElem((unsigned)((total4 + 255) / 256));

    prep_weights<<<dim3(18 * 8), blk, 0, stream>>>(wsrc, Wh, Wl);
    front1_kernel<<<NBS, blk, 0, stream>>>(x, Wh, G, xWs, N);
    front2_kernel<<<NBS, blk, 0, stream>>>(x, Wh, Wl, At, Bt, Ct, e0, N);

    hipMemsetAsync(deg, 0, (size_t)N * 4, stream);
    hist_kernel<<<gE, blk, 0, stream>>>(ei, deg, E);
    scan_kernel<<<1, 1024, 0, stream>>>(deg, rowptr, cursor, N);
    scatter_kernel<<<gE, blk, 0, stream>>>(ei, bond, coords, cursor, csr, E);

    edge_agg<<<(N + 3) / 4, blk, 0, stream>>>(At, Bt, G, rowptr, csr, conv_w, conv_b,
                                              b_nb, b_el, Pn, Pe, z, s_arr, N);

    backend_kernel<<<dim3(NBS, 3), blk, 0, stream>>>(Pn, Pe, z, Ct, xWs, e0, s_arr, deg,
                                                     b_nout, b_eout, b_coord, b_pair, b_sout,
                                                     Wh, Wl, f1, f2, f3, e1, e2, e3, N);

    attagg_kernel<<<NBS, blk, 0, stream>>>(e1, e2, e3, f1, f2, f3,
                                           Wh, Wl, hout, N);

    hipMemsetAsync(bnsums, 0, 256 * 4, stream);
    bn_stats<<<512, blk, 0, stream>>>(hout, bnsums, N);
    bn_finalize<<<1, 128, 0, stream>>>(bnsums, gamma, beta, bnscale, bnshift, 1.0f / (float)N);
    bn_apply<<<gElem, blk, 0, stream>>>(hout, bnscale, bnshift, total4);
}

// Round 6
// 769.350 us; speedup vs baseline: 1.3727x; 1.1187x over previous
//
#include <hip/hip_runtime.h>
#include <math.h>

#define DD 128
#define LDSS 136   // u16 LDS row stride (128 + 8 pad)
#define WT 16384   // u16 elements per packed 128x128 weight matrix

typedef __attribute__((ext_vector_type(8))) short bf16x8;
typedef __attribute__((ext_vector_type(4))) float f32x4;
typedef unsigned short u16;
typedef unsigned int u32;

__device__ __forceinline__ u16 f2bf(float f) {          // RNE (stored tensors)
    u32 u = __builtin_bit_cast(u32, f);
    u += 0x7fffu + ((u >> 16) & 1u);
    return (u16)(u >> 16);
}
__device__ __forceinline__ float bf2f(u16 h) {
    u32 u = ((u32)h) << 16;
    return __builtin_bit_cast(float, u);
}
__device__ __forceinline__ float mishf(float x) {
    float e = __expf(fminf(x, 15.0f));
    float n = e * (e + 2.0f);
    return x * n * __builtin_amdgcn_rcpf(n + 2.0f);
}
// truncating hi/lo split (cheap, reconstruction err ~2^-16)
__device__ __forceinline__ void splitv(float v, u16& h, u16& l) {
    u32 u = __builtin_bit_cast(u32, v);
    h = (u16)(u >> 16);
    float r = v - __builtin_bit_cast(float, u & 0xffff0000u);
    l = (u16)(__builtin_bit_cast(u32, r) >> 16);
}

// NM=1: ah*bh ; NM=2: ah*(bh+bl) ; NM=3: + al*bh
template<int NM>
__device__ __forceinline__ void gemm8(const bf16x8* ah, const bf16x8* al,
    const u16* __restrict__ Wh, const u16* __restrict__ Wl, int lane, f32x4* acc)
{
#pragma unroll
    for (int kb = 0; kb < 4; kb++)
#pragma unroll
        for (int nt = 0; nt < 8; nt++) {
            size_t boff = (((size_t)kb * 8 + nt) * 64 + lane) * 8;
            bf16x8 bh = *(const bf16x8*)(Wh + boff);
            acc[nt] = __builtin_amdgcn_mfma_f32_16x16x32_bf16(ah[kb], bh, acc[nt], 0, 0, 0);
            if (NM >= 2) {
                bf16x8 bl = *(const bf16x8*)(Wl + boff);
                acc[nt] = __builtin_amdgcn_mfma_f32_16x16x32_bf16(ah[kb], bl, acc[nt], 0, 0, 0);
            }
            if (NM == 3)
                acc[nt] = __builtin_amdgcn_mfma_f32_16x16x32_bf16(al[kb], bh, acc[nt], 0, 0, 0);
        }
}

__device__ __forceinline__ void zero_acc(f32x4* acc) {
#pragma unroll
    for (int nt = 0; nt < 8; nt++) { f32x4 z4 = {0.f, 0.f, 0.f, 0.f}; acc[nt] = z4; }
}

__device__ __forceinline__ void frag_hi_global(const u16* __restrict__ src, int row0,
                                               int lm, int quad, int M, bf16x8* ah)
{
    int row = row0 + lm; if (row >= M) row = M - 1;
    const u16* p = src + (size_t)row * DD + quad * 8;
#pragma unroll
    for (int kb = 0; kb < 4; kb++) ah[kb] = *(const bf16x8*)(p + kb * 32);
}
__device__ __forceinline__ void frag_split_global(const float* __restrict__ src, int row0,
                                                  int lm, int quad, int M, bf16x8* ah, bf16x8* al)
{
    int row = row0 + lm; if (row >= M) row = M - 1;
    const float* p = src + (size_t)row * DD + quad * 8;
#pragma unroll
    for (int kb = 0; kb < 4; kb++) {
        float tmp[8];
        *(float4*)tmp       = *(const float4*)(p + kb * 32);
        *(float4*)(tmp + 4) = *(const float4*)(p + kb * 32 + 4);
#pragma unroll
        for (int j = 0; j < 8; j++) { u16 h, l; splitv(tmp[j], h, l); ah[kb][j] = (short)h; al[kb][j] = (short)l; }
    }
}
// hi-only frag from plane (wave-private 16-row band)
__device__ __forceinline__ void frag_hi_plane(const u16* pH, int wave, int lm, int quad, bf16x8* ah)
{
    const u16* ph = pH + (size_t)(wave * 16 + lm) * LDSS + quad * 8;
#pragma unroll
    for (int kb = 0; kb < 4; kb++) ah[kb] = *(const bf16x8*)(ph + kb * 32);
}
__device__ __forceinline__ void frag_planes(const u16* pH, const u16* pL, int wave,
                                            int lm, int quad, bf16x8* ah, bf16x8* al)
{
    const u16* ph = pH + (size_t)(wave * 16 + lm) * LDSS + quad * 8;
    const u16* pl = pL + (size_t)(wave * 16 + lm) * LDSS + quad * 8;
#pragma unroll
    for (int kb = 0; kb < 4; kb++) {
        ah[kb] = *(const bf16x8*)(ph + kb * 32);
        al[kb] = *(const bf16x8*)(pl + kb * 32);
    }
}

// ============ weight prep ============
struct WSrc { const float* p[18]; };

__global__ __launch_bounds__(256) void prep_weights(WSrc ws, u16* __restrict__ Wh, u16* __restrict__ Wl)
{
    int mat = blockIdx.x >> 3, chunk = blockIdx.x & 7;
    int t = threadIdx.x;
    int tt = chunk * 4 + (t >> 6);
    int lane = t & 63;
    int kb = tt >> 3, nt = tt & 7;
    const float* __restrict__ src = ws.p[mat];
    size_t doff = (size_t)mat * WT + ((size_t)tt * 64 + lane) * 8;
    int srow = kb * 32 + ((lane >> 4) * 8);
    int scol = nt * 16 + (lane & 15);
    u16 th[8], tl[8];
#pragma unroll
    for (int j = 0; j < 8; j++) {
        float v = src[(srow + j) * DD + scol];
        u16 h = f2bf(v);
        th[j] = h;
        tl[j] = f2bf(v - bf2f(h));
    }
    *(bf16x8*)(Wh + doff) = *(bf16x8*)th;
    *(bf16x8*)(Wl + doff) = *(bf16x8*)tl;
}

// ============ front: x read once -> G=[As|Bs|xb], xWs, At, Bt, Ct, e0 ============
__global__ __launch_bounds__(128, 4) void front_kernel(
    const float* __restrict__ x, const u16* __restrict__ Wh, const u16* __restrict__ Wl,
    u16* __restrict__ G, u16* __restrict__ xWs,
    float* __restrict__ At, float* __restrict__ Bt, float* __restrict__ Ct,
    u16* __restrict__ e0, int M)
{
    __shared__ u16 sP[32 * LDSS];
    const int t = threadIdx.x, wave = t >> 6, lane = t & 63;
    const int lm = lane & 15, quad = lane >> 4;
    const int rowBase = blockIdx.x * 32;
    const int row0 = rowBase + wave * 16;

    bf16x8 ah[4], al[4];
    {   // load x, write RNE xb into plane, build trunc-split frags
        int row = row0 + lm; if (row >= M) row = M - 1;
        const float* p = x + (size_t)row * DD + quad * 8;
        int arow = wave * 16 + lm;
#pragma unroll
        for (int kb = 0; kb < 4; kb++) {
            float tmp[8];
            *(float4*)tmp       = *(const float4*)(p + kb * 32);
            *(float4*)(tmp + 4) = *(const float4*)(p + kb * 32 + 4);
#pragma unroll
            for (int j = 0; j < 8; j++) {
                u16 h, l; splitv(tmp[j], h, l);
                ah[kb][j] = (short)h; al[kb][j] = (short)l;
                sP[arow * LDSS + kb * 32 + quad * 8 + j] = f2bf(tmp[j]);
            }
        }
    }
    __syncthreads();
#pragma unroll
    for (int i = 0; i < 16; i++) {      // drain xb -> G seg2
        int r = wave + i * 2;
        int grow = rowBase + r;
        u32 v = *(const u32*)&sP[r * LDSS + lane * 2];
        if (grow < M) *(u32*)(G + (size_t)grow * 384 + 256 + lane * 2) = v;
    }
    __syncthreads();
    {   // As = x@W1 -> plane -> G seg0
        f32x4 acc[8]; zero_acc(acc);
        gemm8<1>(ah, ah, Wh + 1 * WT, Wh, lane, acc);
#pragma unroll
        for (int r = 0; r < 4; r++)
#pragma unroll
            for (int nt = 0; nt < 8; nt++)
                sP[(wave * 16 + quad * 4 + r) * LDSS + nt * 16 + lm] = f2bf(acc[nt][r]);
        __syncthreads();
#pragma unroll
        for (int i = 0; i < 16; i++) {
            int r = wave + i * 2;
            int grow = rowBase + r;
            u32 v = *(const u32*)&sP[r * LDSS + lane * 2];
            if (grow < M) *(u32*)(G + (size_t)grow * 384 + lane * 2) = v;
        }
        __syncthreads();
    }
    {   // Bs = x@W3 -> plane -> G seg1
        f32x4 acc[8]; zero_acc(acc);
        gemm8<1>(ah, ah, Wh + 3 * WT, Wh, lane, acc);
#pragma unroll
        for (int r = 0; r < 4; r++)
#pragma unroll
            for (int nt = 0; nt < 8; nt++)
                sP[(wave * 16 + quad * 4 + r) * LDSS + nt * 16 + lm] = f2bf(acc[nt][r]);
        __syncthreads();
#pragma unroll
        for (int i = 0; i < 16; i++) {
            int r = wave + i * 2;
            int grow = rowBase + r;
            u32 v = *(const u32*)&sP[r * LDSS + lane * 2];
            if (grow < M) *(u32*)(G + (size_t)grow * 384 + 128 + lane * 2) = v;
        }
        __syncthreads();
    }
    {   // xWs = x@W5 -> global bf16
        f32x4 acc[8]; zero_acc(acc);
        gemm8<1>(ah, ah, Wh + 5 * WT, Wh, lane, acc);
#pragma unroll
        for (int r = 0; r < 4; r++) {
            int grow = row0 + quad * 4 + r;
            if (grow >= M) continue;
#pragma unroll
            for (int nt = 0; nt < 8; nt++)
                xWs[(size_t)grow * DD + nt * 16 + lm] = f2bf(acc[nt][r]);
        }
    }
    {   // At, Bt, Ct (split, fp32 out)
        float* outs[3] = {At, Bt, Ct};
        const int mats[3] = {0, 2, 4};
#pragma unroll
        for (int wi = 0; wi < 3; wi++) {
            f32x4 acc[8]; zero_acc(acc);
            gemm8<3>(ah, al, Wh + (size_t)mats[wi] * WT, Wl + (size_t)mats[wi] * WT, lane, acc);
            float* out = outs[wi];
#pragma unroll
            for (int r = 0; r < 4; r++) {
                int grow = row0 + quad * 4 + r;
                if (grow >= M) continue;
#pragma unroll
                for (int nt = 0; nt < 8; nt++)
                    out[(size_t)grow * DD + nt * 16 + lm] = acc[nt][r];
            }
        }
    }
    {   // lin2 = mish2(x@W6) -> plane (wave-private band, no sync needed after)
        f32x4 acc[8]; zero_acc(acc);
        gemm8<1>(ah, ah, Wh + 6 * WT, Wh, lane, acc);
#pragma unroll
        for (int r = 0; r < 4; r++)
#pragma unroll
            for (int nt = 0; nt < 8; nt++)
                sP[(wave * 16 + quad * 4 + r) * LDSS + nt * 16 + lm] = f2bf(mishf(mishf(acc[nt][r])));
    }
    {   // e0 = lin2@W7 -> global bf16
        bf16x8 lh[4];
        frag_hi_plane(sP, wave, lm, quad, lh);
        f32x4 acc[8]; zero_acc(acc);
        gemm8<1>(lh, lh, Wh + 7 * WT, Wh, lane, acc);
#pragma unroll
        for (int r = 0; r < 4; r++) {
            int grow = row0 + quad * 4 + r;
            if (grow >= M) continue;
#pragma unroll
            for (int nt = 0; nt < 8; nt++)
                e0[(size_t)grow * DD + nt * 16 + lm] = f2bf(acc[nt][r]);
        }
    }
}

// ============ CSR build ============
__global__ __launch_bounds__(256) void hist_kernel(const int* __restrict__ ei, int* __restrict__ deg, int E)
{
    int e = blockIdx.x * 256 + threadIdx.x;
    if (e < E) atomicAdd(&deg[ei[E + e]], 1);
}

__global__ __launch_bounds__(1024) void scan_kernel(const int* __restrict__ deg,
                                                    int* __restrict__ rowptr,
                                                    int* __restrict__ cursor, int N)
{
    __shared__ int sums[1024];
    const int CH = 52;                      // 52*1024 >= 50000; 52*4B = 208B = 13x16B aligned
    int t = threadIdx.x;
    int base = t * CH;
    int local = 0;
#pragma unroll
    for (int i = 0; i < 13; i++) {
        int idx = base + i * 4;
        if (idx + 3 < N) {
            int4 v = *(const int4*)(deg + idx);
            local += v.x + v.y + v.z + v.w;
        } else {
            for (int k = 0; k < 4; k++) if (idx + k < N) local += deg[idx + k];
        }
    }
    sums[t] = local;
    __syncthreads();
    for (int off = 1; off < 1024; off <<= 1) {
        int v = sums[t];
        int u = (t >= off) ? sums[t - off] : 0;
        __syncthreads();
        sums[t] = v + u;
        __syncthreads();
    }
    int run = (t == 0) ? 0 : sums[t - 1];
    for (int i = 0; i < CH; i++) {
        int idx = base + i;
        if (idx < N) {
            rowptr[idx] = run;
            cursor[idx] = run;
            run += deg[idx];
        }
    }
    if (t == 1023) rowptr[N] = sums[1023];
}

__global__ __launch_bounds__(256) void scatter_kernel(
    const int* __restrict__ ei, const int* __restrict__ bond,
    const float* __restrict__ coords, int* __restrict__ cursor,
    int2* __restrict__ csr, int E)
{
    int e = blockIdx.x * 256 + threadIdx.x;
    if (e >= E) return;
    int src = ei[e], dst = ei[E + e];
    int pos = atomicAdd(&cursor[dst], 1);
    float dx = coords[src * 3 + 0] - coords[dst * 3 + 0];
    float dy = coords[src * 3 + 1] - coords[dst * 3 + 1];
    float dz = coords[src * 3 + 2] - coords[dst * 3 + 2];
    float d2 = dx * dx + dy * dy + dz * dz;
    csr[pos] = make_int2(src | (bond[e] << 20), __float_as_int(d2));
}

// ============ per-node edge aggregation ============
__global__ __launch_bounds__(256) void edge_agg(
    const float* __restrict__ At, const float* __restrict__ Bt,
    const u16* __restrict__ G,
    const int* __restrict__ rowptr, const int2* __restrict__ csr,
    const float* __restrict__ conv_w, const float* __restrict__ conv_b,
    const float* __restrict__ b_nb, const float* __restrict__ b_el,
    u16* __restrict__ Pn, u16* __restrict__ Pe, float* __restrict__ z,
    float* __restrict__ s_arr, int N)
{
    int wave = threadIdx.x >> 6;
    int lane = threadIdx.x & 63;
    int node = blockIdx.x * 4 + wave;
    if (node >= N) return;
    int c0 = lane * 2;
    float2 at = *(const float2*)(At + (size_t)node * DD + c0);
    float2 bt = *(const float2*)(Bt + (size_t)node * DD + c0);
    float cb = conv_b[0];
    float cw0 = conv_w[0] + cb, cw1 = conv_w[1] + cb, cw2 = conv_w[2] + cb, cw3 = conv_w[3] + cb;
    float bn0 = b_nb[c0], bn1 = b_nb[c0 + 1];
    float be0 = b_el[c0], be1 = b_el[c0 + 1];
    float accn0 = 0.f, accn1 = 0.f, acce0 = 0.f, acce1 = 0.f, accz0 = 0.f, accz1 = 0.f, ssum = 0.f;
    int beg = rowptr[node], end = rowptr[node + 1];
#pragma unroll 2
    for (int k = beg; k < end; k++) {
        int2 pd = csr[k];
        int src = pd.x & 0xFFFFF;
        int bond = (pd.x >> 20) & 3;
        float w = (bond == 0) ? cw0 : (bond == 1) ? cw1 : (bond == 2) ? cw2 : cw3;
        float d2 = __int_as_float(pd.y);
        const u16* gp = G + (size_t)src * 384;
        u32 ga = *(const u32*)(gp + c0);
        u32 gb = *(const u32*)(gp + 128 + c0);
        u32 gx = *(const u32*)(gp + 256 + c0);
        float a0 = __builtin_bit_cast(float, ga << 16), a1 = __builtin_bit_cast(float, ga & 0xffff0000u);
        float b0 = __builtin_bit_cast(float, gb << 16), b1 = __builtin_bit_cast(float, gb & 0xffff0000u);
        float x0 = __builtin_bit_cast(float, gx << 16), x1 = __builtin_bit_cast(float, gx & 0xffff0000u);
        accn0 += mishf(at.x + a0 + bn0);
        accn1 += mishf(at.y + a1 + bn1);
        acce0 += mishf(w * (bt.x + b0) + be0);
        acce1 += mishf(w * (bt.y + b1) + be1);
        accz0 += d2 * x0;
        accz1 += d2 * x1;
        ssum += d2;
    }
    *(u32*)(Pn + (size_t)node * DD + c0) = (u32)f2bf(accn0) | ((u32)f2bf(accn1) << 16);
    *(u32*)(Pe + (size_t)node * DD + c0) = (u32)f2bf(acce0) | ((u32)f2bf(acce1) << 16);
    *(float2*)(z + (size_t)node * DD + c0) = make_float2(accz0, accz1);
    if (lane == 0) s_arr[node] = ssum;
}

// ============ backend NE: node/edge chains, hi-only planes (blockIdx.y = path) ============
__global__ __launch_bounds__(128, 4) void backendNE_kernel(
    const u16* __restrict__ Pn, const u16* __restrict__ Pe, const u16* __restrict__ e0,
    const float* __restrict__ b_nout, const float* __restrict__ b_eout,
    const u16* __restrict__ Wh, const u16* __restrict__ Wl,
    u16* __restrict__ f1, u16* __restrict__ f2,
    float* __restrict__ e1, float* __restrict__ e2, int M)
{
    __shared__ u16 pH[32 * LDSS];
    const int t = threadIdx.x, wave = t >> 6, lane = t & 63;
    const int lm = lane & 15, quad = lane >> 4;
    const int row0 = blockIdx.x * 32 + wave * 16;
    const int path = blockIdx.y;

    const u16* P = (path == 0) ? Pn : Pe;
    const float* bo = (path == 0) ? b_nout : b_eout;
    u16* fO = (path == 0) ? f1 : f2;
    float* eO = (path == 0) ? e1 : e2;
    const int mO = 11 + path, mF = 13 + path;

    bf16x8 ah[4];
    f32x4 acc[8];
    // stage 1: f = mish(P@W_out + b_out) -> global bf16 + plane
    frag_hi_global(P, row0, lm, quad, M, ah);
    zero_acc(acc);
    gemm8<2>(ah, ah, Wh + (size_t)mO * WT, Wl + (size_t)mO * WT, lane, acc);
#pragma unroll
    for (int r = 0; r < 4; r++) {
        int grow = row0 + quad * 4 + r;
        bool inb = grow < M;
#pragma unroll
        for (int nt = 0; nt < 8; nt++) {
            int col = nt * 16 + lm;
            float v = mishf(acc[nt][r] + bo[col]);
            u16 hv = f2bf(v);
            if (inb) fO[(size_t)grow * DD + col] = hv;
            pH[(wave * 16 + quad * 4 + r) * LDSS + col] = hv;
        }
    }
    // stage 2: l = mish2(f@FL) -> plane
    frag_hi_plane(pH, wave, lm, quad, ah);
    zero_acc(acc);
    gemm8<2>(ah, ah, Wh + (size_t)mF * WT, Wl + (size_t)mF * WT, lane, acc);
#pragma unroll
    for (int r = 0; r < 4; r++)
#pragma unroll
        for (int nt = 0; nt < 8; nt++)
            pH[(wave * 16 + quad * 4 + r) * LDSS + nt * 16 + lm] = f2bf(mishf(mishf(acc[nt][r])));
    // stage 3: e = l@Wa_b + e0 -> fp32 global
    frag_hi_plane(pH, wave, lm, quad, ah);
    zero_acc(acc);
    gemm8<2>(ah, ah, Wh + 16 * WT, Wl + 16 * WT, lane, acc);
#pragma unroll
    for (int r = 0; r < 4; r++) {
        int grow = row0 + quad * 4 + r;
        if (grow >= M) continue;
#pragma unroll
        for (int nt = 0; nt < 8; nt++) {
            int col = nt * 16 + lm;
            eO[(size_t)grow * DD + col] = acc[nt][r] + bf2f(e0[(size_t)grow * DD + col]);
        }
    }
}

// ============ backend S: struct chain, split hi/lo planes ============
__global__ __launch_bounds__(128, 4) void backendS_kernel(
    const float* __restrict__ z, const float* __restrict__ Ct,
    const u16* __restrict__ xWs, const u16* __restrict__ e0,
    const float* __restrict__ s_arr, const int* __restrict__ deg,
    const float* __restrict__ b_coord, const float* __restrict__ b_pair,
    const float* __restrict__ b_sout,
    const u16* __restrict__ Wh, const u16* __restrict__ Wl,
    u16* __restrict__ f3, float* __restrict__ e3, int M)
{
    __shared__ u16 pH[32 * LDSS], pL[32 * LDSS];
    const int t = threadIdx.x, wave = t >> 6, lane = t & 63;
    const int lm = lane & 15, quad = lane >> 4;
    const int row0 = blockIdx.x * 32 + wave * 16;

    bf16x8 ah[4], al[4];
    f32x4 acc[8];
    // stage 1: Qagg = z@Wc_s + s*Ct + deg*b_coord -> planes
    frag_split_global(z, row0, lm, quad, M, ah, al);
    zero_acc(acc);
    gemm8<3>(ah, al, Wh + 8 * WT, Wl + 8 * WT, lane, acc);
#pragma unroll
    for (int r = 0; r < 4; r++) {
        int crow = row0 + quad * 4 + r; if (crow >= M) crow = M - 1;
        float sv = s_arr[crow];
        float dv = (float)deg[crow];
#pragma unroll
        for (int nt = 0; nt < 8; nt++) {
            int col = nt * 16 + lm;
            float v = acc[nt][r] + sv * Ct[(size_t)crow * DD + col] + dv * b_coord[col];
            int lidx = (wave * 16 + quad * 4 + r) * LDSS + col;
            u16 h, l; splitv(v, h, l); pH[lidx] = h; pL[lidx] = l;
        }
    }
    // stage 2: Q = mish(Qagg@W_pair + b_pair)
    frag_planes(pH, pL, wave, lm, quad, ah, al);
    zero_acc(acc);
    gemm8<3>(ah, al, Wh + 9 * WT, Wl + 9 * WT, lane, acc);
#pragma unroll
    for (int r = 0; r < 4; r++)
#pragma unroll
        for (int nt = 0; nt < 8; nt++) {
            int col = nt * 16 + lm;
            int lidx = (wave * 16 + quad * 4 + r) * LDSS + col;
            u16 h, l; splitv(mishf(acc[nt][r] + b_pair[col]), h, l); pH[lidx] = h; pL[lidx] = l;
        }
    // stage 3: f_struct = mish(Q@Ws_b + xWs + b_sout) -> global bf16 + planes
    frag_planes(pH, pL, wave, lm, quad, ah, al);
    zero_acc(acc);
    gemm8<3>(ah, al, Wh + 10 * WT, Wl + 10 * WT, lane, acc);
#pragma unroll
    for (int r = 0; r < 4; r++) {
        int crow = row0 + quad * 4 + r; if (crow >= M) crow = M - 1;
        bool inb = (row0 + quad * 4 + r) < M;
#pragma unroll
        for (int nt = 0; nt < 8; nt++) {
            int col = nt * 16 + lm;
            float v = mishf(acc[nt][r] + bf2f(xWs[(size_t)crow * DD + col]) + b_sout[col]);
            if (inb) f3[(size_t)crow * DD + col] = f2bf(v);
            int lidx = (wave * 16 + quad * 4 + r) * LDSS + col;
            u16 h, l; splitv(v, h, l); pH[lidx] = h; pL[lidx] = l;
        }
    }
    // stage 4: l2 = mish2(f_struct@FL2)
    frag_planes(pH, pL, wave, lm, quad, ah, al);
    zero_acc(acc);
    gemm8<3>(ah, al, Wh + 15 * WT, Wl + 15 * WT, lane, acc);
#pragma unroll
    for (int r = 0; r < 4; r++)
#pragma unroll
        for (int nt = 0; nt < 8; nt++) {
            int lidx = (wave * 16 + quad * 4 + r) * LDSS + nt * 16 + lm;
            u16 h, l; splitv(mishf(mishf(acc[nt][r])), h, l); pH[lidx] = h; pL[lidx] = l;
        }
    // stage 5: e3 = l2@Wa_b + e0 -> fp32 global
    frag_planes(pH, pL, wave, lm, quad, ah, al);
    zero_acc(acc);
    gemm8<3>(ah, al, Wh + 16 * WT, Wl + 16 * WT, lane, acc);
#pragma unroll
    for (int r = 0; r < 4; r++) {
        int grow = row0 + quad * 4 + r;
        if (grow >= M) continue;
#pragma unroll
        for (int nt = 0; nt < 8; nt++) {
            int col = nt * 16 + lm;
            e3[(size_t)grow * DD + col] = acc[nt][r] + bf2f(e0[(size_t)grow * DD + col]);
        }
    }
}

// ============ softmax combine + @W_agg ============
__global__ __launch_bounds__(128, 4) void attagg_kernel(
    const float* __restrict__ e1, const float* __restrict__ e2, const float* __restrict__ e3,
    const u16* __restrict__ f1, const u16* __restrict__ f2, const u16* __restrict__ f3,
    const u16* __restrict__ Wh, const u16* __restrict__ Wl, float* __restrict__ hout, int M)
{
    __shared__ u16 pH[32 * LDSS], pL[32 * LDSS];
    const int t = threadIdx.x, wave = t >> 6, lane = t & 63;
    const int lm = lane & 15, quad = lane >> 4;
    const int row0 = blockIdx.x * 32 + wave * 16;

#pragma unroll
    for (int r = 0; r < 4; r++) {
        int crow = row0 + quad * 4 + r; if (crow >= M) crow = M - 1;
#pragma unroll
        for (int nt = 0; nt < 8; nt++) {
            int col = nt * 16 + lm;
            size_t idx = (size_t)crow * DD + col;
            float x1 = e1[idx], x2 = e2[idx], x3 = e3[idx];
            float m = fmaxf(fmaxf(x1, x2), x3);
            float p1 = __expf(x1 - m), p2 = __expf(x2 - m), p3 = __expf(x3 - m);
            float att = (p1 * bf2f(f1[idx]) + p2 * bf2f(f2[idx]) + p3 * bf2f(f3[idx]))
                        * __builtin_amdgcn_rcpf(p1 + p2 + p3);
            int lidx = (wave * 16 + quad * 4 + r) * LDSS + col;
            u16 h, l; splitv(att, h, l); pH[lidx] = h; pL[lidx] = l;
        }
    }
    bf16x8 ah[4], al[4];
    frag_planes(pH, pL, wave, lm, quad, ah, al);
    f32x4 acc[8]; zero_acc(acc);
    gemm8<3>(ah, al, Wh + 17 * WT, Wl + 17 * WT, lane, acc);
#pragma unroll
    for (int r = 0; r < 4; r++) {
        int grow = row0 + quad * 4 + r;
        if (grow >= M) continue;
#pragma unroll
        for (int nt = 0; nt < 8; nt++)
            hout[(size_t)grow * DD + nt * 16 + lm] = acc[nt][r];
    }
}

// ============ batchnorm ============
__global__ __launch_bounds__(256) void bn_stats(const float* __restrict__ h, float* __restrict__ sums, int N)
{
    int t = threadIdx.x;
    int col = t & 127;
    float s = 0.f, sq = 0.f;
    for (int r = blockIdx.x * 2 + (t >> 7); r < N; r += gridDim.x * 2) {
        float v = h[(size_t)r * DD + col];
        s += v; sq += v * v;
    }
    __shared__ float sh[256];
    sh[t] = s; __syncthreads();
    float s2 = (t < 128) ? (sh[t] + sh[t + 128]) : 0.f;
    __syncthreads();
    sh[t] = sq; __syncthreads();
    if (t < 128) {
        float q2 = sh[t] + sh[t + 128];
        atomicAdd(&sums[t], s2);
        atomicAdd(&sums[128 + t], q2);
    }
}

__global__ void bn_finalize(const float* __restrict__ sums, const float* __restrict__ gamma,
                            const float* __restrict__ beta, float* __restrict__ scale,
                            float* __restrict__ shift, float n_inv)
{
    int c = threadIdx.x;
    float mean = sums[c] * n_inv;
    float var = sums[128 + c] * n_inv - mean * mean;
    float inv = rsqrtf(var + 1e-5f);
    float sc = gamma[c] * inv;
    scale[c] = sc;
    shift[c] = beta[c] - mean * sc;
}

__global__ __launch_bounds__(256) void bn_apply(float* __restrict__ h, const float* __restrict__ scale,
                                                const float* __restrict__ shift, size_t total4)
{
    size_t idx = (size_t)blockIdx.x * 256 + threadIdx.x;
    if (idx >= total4) return;
    size_t off = idx * 4;
    int c = (int)(off & 127);
    float4 v = *(const float4*)(h + off);
    float4 sc = *(const float4*)(scale + c);
    float4 sh = *(const float4*)(shift + c);
    v.x = mishf(v.x * sc.x + sh.x);
    v.y = mishf(v.y * sc.y + sh.y);
    v.z = mishf(v.z * sc.z + sh.z);
    v.w = mishf(v.w * sc.w + sh.w);
    *(float4*)(h + off) = v;
}

// ============ host ============
extern "C" void kernel_launch(void* const* d_in, const int* in_sizes, int n_in,
                              void* d_out, int out_size, void* d_ws, size_t ws_size,
                              hipStream_t stream)
{
    (void)n_in; (void)out_size; (void)ws_size;
    const float* x       = (const float*)d_in[0];
    const float* coords  = (const float*)d_in[1];
    const int*   ei      = (const int*)d_in[2];
    const int*   bond    = (const int*)d_in[3];
    const float* W_nb    = (const float*)d_in[4];
    const float* b_nb    = (const float*)d_in[5];
    const float* W_nout  = (const float*)d_in[6];
    const float* b_nout  = (const float*)d_in[7];
    const float* conv_w  = (const float*)d_in[8];
    const float* conv_b  = (const float*)d_in[9];
    const float* W_el    = (const float*)d_in[10];
    const float* b_el    = (const float*)d_in[11];
    const float* W_eout  = (const float*)d_in[12];
    const float* b_eout  = (const float*)d_in[13];
    const float* W_coord = (const float*)d_in[14];
    const float* b_coord = (const float*)d_in[15];
    const float* W_pair  = (const float*)d_in[16];
    const float* b_pair  = (const float*)d_in[17];
    const float* W_sout  = (const float*)d_in[18];
    const float* b_sout  = (const float*)d_in[19];
    const float* W_init  = (const float*)d_in[20];
    const float* feat_lin= (const float*)d_in[21];
    const float* W_att   = (const float*)d_in[22];
    const float* W_agg   = (const float*)d_in[23];
    const float* gamma   = (const float*)d_in[24];
    const float* beta    = (const float*)d_in[25];

    const int N = in_sizes[0] / DD;     // 50000
    const int E = in_sizes[3];          // 800000
    const size_t ND = (size_t)N * DD;
    const int SUB = DD * DD;
    const int NB32 = (N + 31) / 32;

    char* base = (char*)d_ws;
    size_t off = 0;
    auto alloc = [&](size_t bytes) -> char* {
        char* p = base + off;
        off = (off + bytes + 63) & ~(size_t)63;
        return p;
    };
    u16*   G    = (u16*)alloc((size_t)N * 384 * 2);
    u16*   xWs  = (u16*)alloc(ND * 2);
    float* At   = (float*)alloc(ND * 4);   // dead after edge_agg -> aliased as e1
    float* Bt   = (float*)alloc(ND * 4);   // dead after edge_agg -> aliased as e2
    float* Ct   = (float*)alloc(ND * 4);
    u16*   e0   = (u16*)alloc(ND * 2);
    u16*   Pn   = (u16*)alloc(ND * 2);
    u16*   Pe   = (u16*)alloc(ND * 2);
    float* z    = (float*)alloc(ND * 4);   // consumed in backendS stage1 -> aliased as e3
    u16*   f1   = (u16*)alloc(ND * 2);
    u16*   f2   = (u16*)alloc(ND * 2);
    u16*   f3   = (u16*)alloc(ND * 2);
    u16*   Wh   = (u16*)alloc((size_t)18 * WT * 2);
    u16*   Wl   = (u16*)alloc((size_t)18 * WT * 2);
    int2*  csr  = (int2*)alloc((size_t)E * 8);
    int*   deg    = (int*)alloc((size_t)(N + 64) * 4);
    int*   rowptr = (int*)alloc((size_t)(N + 1) * 4);
    int*   cursor = (int*)alloc((size_t)N * 4);
    float* s_arr  = (float*)alloc((size_t)N * 4);
    float* bnsums  = (float*)alloc(256 * 4);
    float* bnscale = (float*)alloc(128 * 4);
    float* bnshift = (float*)alloc(128 * 4);

    float* hout = (float*)d_out;
    float* e1 = At;   // safe: At/Bt dead after edge_agg completes (stream order)
    float* e2 = Bt;
    float* e3 = z;    // safe: backendS wave reads its own z rows before writing same rows

    WSrc wsrc;
    wsrc.p[0] = W_nb;            wsrc.p[1] = W_nb + SUB;
    wsrc.p[2] = W_el;            wsrc.p[3] = W_el + SUB;
    wsrc.p[4] = W_coord;         wsrc.p[5] = W_sout;
    wsrc.p[6] = W_init;          wsrc.p[7] = W_att;
    wsrc.p[8] = W_coord + SUB;   wsrc.p[9] = W_pair;
    wsrc.p[10] = W_sout + SUB;   wsrc.p[11] = W_nout;
    wsrc.p[12] = W_eout;         wsrc.p[13] = feat_lin;
    wsrc.p[14] = feat_lin + SUB; wsrc.p[15] = feat_lin + 2 * SUB;
    wsrc.p[16] = W_att + SUB;    wsrc.p[17] = W_agg;

    const dim3 blk256(256), blk128(128);
    const dim3 gE((E + 255) / 256);
    const size_t total4 = ND / 4;
    const dim3 gElem((unsigned)((total4 + 255) / 256));

    prep_weights<<<dim3(18 * 8), blk256, 0, stream>>>(wsrc, Wh, Wl);
    front_kernel<<<NB32, blk128, 0, stream>>>(x, Wh, Wl, G, xWs, At, Bt, Ct, e0, N);

    hipMemsetAsync(deg, 0, (size_t)N * 4, stream);
    hist_kernel<<<gE, blk256, 0, stream>>>(ei, deg, E);
    scan_kernel<<<1, 1024, 0, stream>>>(deg, rowptr, cursor, N);
    scatter_kernel<<<gE, blk256, 0, stream>>>(ei, bond, coords, cursor, csr, E);

    edge_agg<<<(N + 3) / 4, blk256, 0, stream>>>(At, Bt, G, rowptr, csr, conv_w, conv_b,
                                                 b_nb, b_el, Pn, Pe, z, s_arr, N);

    backendNE_kernel<<<dim3(NB32, 2), blk128, 0, stream>>>(Pn, Pe, e0, b_nout, b_eout,
                                                           Wh, Wl, f1, f2, e1, e2, N);
    backendS_kernel<<<NB32, blk128, 0, stream>>>(z, Ct, xWs, e0, s_arr, deg,
                                                 b_coord, b_pair, b_sout, Wh, Wl, f3, e3, N);

    attagg_kernel<<<NB32, blk128, 0, stream>>>(e1, e2, e3, f1, f2, f3, Wh, Wl, hout, N);

    hipMemsetAsync(bnsums, 0, 256 * 4, stream);
    bn_stats<<<512, blk256, 0, stream>>>(hout, bnsums, N);
    bn_finalize<<<1, 128, 0, stream>>>(bnsums, gamma, beta, bnscale, bnshift, 1.0f / (float)N);
    bn_apply<<<gElem, blk256, 0, stream>>>(hout, bnscale, bnshift, total4);
}

// Round 7
// 651.915 us; speedup vs baseline: 1.6200x; 1.1801x over previous
//
#include <hip/hip_runtime.h>
#include <math.h>

#define DD 128
#define LDSS 136            // u16 LDS row stride (128 + 8 pad)
#define PLANE (16 * LDSS)   // u16 elements per 16-row plane
#define WT 16384            // u16 elements per packed 128x128 weight matrix

typedef __attribute__((ext_vector_type(8))) short bf16x8;
typedef __attribute__((ext_vector_type(4))) float f32x4;
typedef unsigned short u16;
typedef unsigned int u32;

__device__ __forceinline__ u16 f2bf(float f) {          // RNE (stored tensors)
    u32 u = __builtin_bit_cast(u32, f);
    u += 0x7fffu + ((u >> 16) & 1u);
    return (u16)(u >> 16);
}
__device__ __forceinline__ float bf2f(u16 h) {
    u32 u = ((u32)h) << 16;
    return __builtin_bit_cast(float, u);
}
__device__ __forceinline__ float mishf(float x) {
    float e = __expf(fminf(x, 15.0f));
    float n = e * (e + 2.0f);
    return x * n * __builtin_amdgcn_rcpf(n + 2.0f);
}
// truncating hi/lo split (3 VALU ops, reconstruction err ~2^-16)
__device__ __forceinline__ void splitv(float v, u16& h, u16& l) {
    u32 u = __builtin_bit_cast(u32, v);
    h = (u16)(u >> 16);
    float r = v - __builtin_bit_cast(float, u & 0xffff0000u);
    l = (u16)(__builtin_bit_cast(u32, r) >> 16);
}

// 2-nt-tile GEMM slice. NM=1: ah*bh ; NM=2: ah*(bh+bl) ; NM=3: + al*bh
template<int NM>
__device__ __forceinline__ void gemm2(const bf16x8* ah, const bf16x8* al,
    const u16* __restrict__ Wh, const u16* __restrict__ Wl, int lane, int ntB, f32x4* acc)
{
#pragma unroll
    for (int kb = 0; kb < 4; kb++)
#pragma unroll
        for (int j = 0; j < 2; j++) {
            size_t boff = (((size_t)kb * 8 + ntB + j) * 64 + lane) * 8;
            bf16x8 bh = *(const bf16x8*)(Wh + boff);
            acc[j] = __builtin_amdgcn_mfma_f32_16x16x32_bf16(ah[kb], bh, acc[j], 0, 0, 0);
            if (NM >= 2) {
                bf16x8 bl = *(const bf16x8*)(Wl + boff);
                acc[j] = __builtin_amdgcn_mfma_f32_16x16x32_bf16(ah[kb], bl, acc[j], 0, 0, 0);
            }
            if (NM == 3)
                acc[j] = __builtin_amdgcn_mfma_f32_16x16x32_bf16(al[kb], bh, acc[j], 0, 0, 0);
        }
}

__device__ __forceinline__ void zero2(f32x4* acc) {
    f32x4 z4 = {0.f, 0.f, 0.f, 0.f};
    acc[0] = z4; acc[1] = z4;
}

// A-frags (16-row band shared by all waves of the block)
__device__ __forceinline__ void frag_hi_global16(const u16* __restrict__ src, int row0,
                                                 int lm, int quad, int M, bf16x8* ah)
{
    int row = row0 + lm; if (row >= M) row = M - 1;
    const u16* p = src + (size_t)row * DD + quad * 8;
#pragma unroll
    for (int kb = 0; kb < 4; kb++) ah[kb] = *(const bf16x8*)(p + kb * 32);
}
__device__ __forceinline__ void frag_split_global16(const float* __restrict__ src, int row0,
                                                    int lm, int quad, int M, bf16x8* ah, bf16x8* al)
{
    int row = row0 + lm; if (row >= M) row = M - 1;
    const float* p = src + (size_t)row * DD + quad * 8;
#pragma unroll
    for (int kb = 0; kb < 4; kb++) {
        float tmp[8];
        *(float4*)tmp       = *(const float4*)(p + kb * 32);
        *(float4*)(tmp + 4) = *(const float4*)(p + kb * 32 + 4);
#pragma unroll
        for (int j = 0; j < 8; j++) { u16 h, l; splitv(tmp[j], h, l); ah[kb][j] = (short)h; al[kb][j] = (short)l; }
    }
}
__device__ __forceinline__ void frag_hi_plane16(const u16* P, int lm, int quad, bf16x8* ah)
{
    const u16* p = P + (size_t)lm * LDSS + quad * 8;
#pragma unroll
    for (int kb = 0; kb < 4; kb++) ah[kb] = *(const bf16x8*)(p + kb * 32);
}
__device__ __forceinline__ void frag_planes16(const u16* PH, const u16* PL, int lm, int quad,
                                              bf16x8* ah, bf16x8* al)
{
    const u16* ph = PH + (size_t)lm * LDSS + quad * 8;
    const u16* pl = PL + (size_t)lm * LDSS + quad * 8;
#pragma unroll
    for (int kb = 0; kb < 4; kb++) {
        ah[kb] = *(const bf16x8*)(ph + kb * 32);
        al[kb] = *(const bf16x8*)(pl + kb * 32);
    }
}

// ============ weight prep ============
struct WSrc { const float* p[18]; };

__global__ __launch_bounds__(256) void prep_weights(WSrc ws, u16* __restrict__ Wh, u16* __restrict__ Wl)
{
    int mat = blockIdx.x >> 3, chunk = blockIdx.x & 7;
    int t = threadIdx.x;
    int tt = chunk * 4 + (t >> 6);
    int lane = t & 63;
    int kb = tt >> 3, nt = tt & 7;
    const float* __restrict__ src = ws.p[mat];
    size_t doff = (size_t)mat * WT + ((size_t)tt * 64 + lane) * 8;
    int srow = kb * 32 + ((lane >> 4) * 8);
    int scol = nt * 16 + (lane & 15);
    u16 th[8], tl[8];
#pragma unroll
    for (int j = 0; j < 8; j++) {
        float v = src[(srow + j) * DD + scol];
        u16 h = f2bf(v);
        th[j] = h;
        tl[j] = f2bf(v - bf2f(h));
    }
    *(bf16x8*)(Wh + doff) = *(bf16x8*)th;
    *(bf16x8*)(Wl + doff) = *(bf16x8*)tl;
}

// drain a 16-row bf16 plane into G segment (seg*128 cols), 4 rows per wave
__device__ __forceinline__ void drainG(const u16* P, u16* __restrict__ G, int seg,
                                       int row0, int wave, int lane, int M)
{
#pragma unroll
    for (int i = 0; i < 4; i++) {
        int r = wave * 4 + i;
        int grow = row0 + r;
        u32 v = *(const u32*)&P[r * LDSS + lane * 2];
        if (grow < M) *(u32*)(G + (size_t)grow * 384 + seg * 128 + lane * 2) = v;
    }
}

// ============ front: x read once -> G=[As|Bs|xb], xWs, At, Bt, Ct, e0 ============
__global__ __launch_bounds__(256, 4) void front_kernel(
    const float* __restrict__ x, const u16* __restrict__ Wh, const u16* __restrict__ Wl,
    u16* __restrict__ G, u16* __restrict__ xWs,
    float* __restrict__ At, float* __restrict__ Bt, float* __restrict__ Ct,
    u16* __restrict__ e0, int M)
{
    __shared__ u16 sP[2 * PLANE];
    u16* P0 = sP; u16* P1 = sP + PLANE;
    const int t = threadIdx.x, wave = t >> 6, lane = t & 63;
    const int lm = lane & 15, quad = lane >> 4;
    const int ntB = wave * 2;
    const int row0 = blockIdx.x * 16;

    bf16x8 ah[4], al[4];
    {   // every wave loads the same 16 rows (L1 hits); wave 0 writes the xb plane
        int row = row0 + lm; if (row >= M) row = M - 1;
        const float* p = x + (size_t)row * DD + quad * 8;
#pragma unroll
        for (int kb = 0; kb < 4; kb++) {
            float tmp[8];
            *(float4*)tmp       = *(const float4*)(p + kb * 32);
            *(float4*)(tmp + 4) = *(const float4*)(p + kb * 32 + 4);
#pragma unroll
            for (int j = 0; j < 8; j++) {
                u16 h, l; splitv(tmp[j], h, l);
                ah[kb][j] = (short)h; al[kb][j] = (short)l;
                if (wave == 0) P0[lm * LDSS + kb * 32 + quad * 8 + j] = f2bf(tmp[j]);
            }
        }
    }
    __syncthreads();
    drainG(P0, G, 2, row0, wave, lane, M);   // xb
    __syncthreads();
    {   // As = x@W1 -> P1 -> G seg0
        f32x4 acc[2]; zero2(acc);
        gemm2<1>(ah, ah, Wh + 1 * WT, Wh, lane, ntB, acc);
#pragma unroll
        for (int r = 0; r < 4; r++)
#pragma unroll
            for (int j = 0; j < 2; j++)
                P1[(quad * 4 + r) * LDSS + (ntB + j) * 16 + lm] = f2bf(acc[j][r]);
        __syncthreads();
        drainG(P1, G, 0, row0, wave, lane, M);
        __syncthreads();
    }
    {   // Bs = x@W3 -> P0 -> G seg1
        f32x4 acc[2]; zero2(acc);
        gemm2<1>(ah, ah, Wh + 3 * WT, Wh, lane, ntB, acc);
#pragma unroll
        for (int r = 0; r < 4; r++)
#pragma unroll
            for (int j = 0; j < 2; j++)
                P0[(quad * 4 + r) * LDSS + (ntB + j) * 16 + lm] = f2bf(acc[j][r]);
        __syncthreads();
        drainG(P0, G, 1, row0, wave, lane, M);
        __syncthreads();
    }
    {   // xWs = x@W5 -> global bf16
        f32x4 acc[2]; zero2(acc);
        gemm2<1>(ah, ah, Wh + 5 * WT, Wh, lane, ntB, acc);
#pragma unroll
        for (int r = 0; r < 4; r++) {
            int grow = row0 + quad * 4 + r;
            if (grow >= M) continue;
#pragma unroll
            for (int j = 0; j < 2; j++)
                xWs[(size_t)grow * DD + (ntB + j) * 16 + lm] = f2bf(acc[j][r]);
        }
    }
    {   // At, Bt, Ct (split, fp32 out)
        float* outs[3] = {At, Bt, Ct};
        const int mats[3] = {0, 2, 4};
#pragma unroll
        for (int wi = 0; wi < 3; wi++) {
            f32x4 acc[2]; zero2(acc);
            gemm2<3>(ah, al, Wh + (size_t)mats[wi] * WT, Wl + (size_t)mats[wi] * WT, lane, ntB, acc);
            float* out = outs[wi];
#pragma unroll
            for (int r = 0; r < 4; r++) {
                int grow = row0 + quad * 4 + r;
                if (grow >= M) continue;
#pragma unroll
                for (int j = 0; j < 2; j++)
                    out[(size_t)grow * DD + (ntB + j) * 16 + lm] = acc[j][r];
            }
        }
    }
    {   // lin2 = mish2(x@W6) -> P1
        f32x4 acc[2]; zero2(acc);
        gemm2<1>(ah, ah, Wh + 6 * WT, Wh, lane, ntB, acc);
#pragma unroll
        for (int r = 0; r < 4; r++)
#pragma unroll
            for (int j = 0; j < 2; j++)
                P1[(quad * 4 + r) * LDSS + (ntB + j) * 16 + lm] = f2bf(mishf(mishf(acc[j][r])));
    }
    __syncthreads();
    {   // e0 = lin2@W7 -> global bf16
        bf16x8 lh[4];
        frag_hi_plane16(P1, lm, quad, lh);
        f32x4 acc[2]; zero2(acc);
        gemm2<1>(lh, lh, Wh + 7 * WT, Wh, lane, ntB, acc);
#pragma unroll
        for (int r = 0; r < 4; r++) {
            int grow = row0 + quad * 4 + r;
            if (grow >= M) continue;
#pragma unroll
            for (int j = 0; j < 2; j++)
                e0[(size_t)grow * DD + (ntB + j) * 16 + lm] = f2bf(acc[j][r]);
        }
    }
}

// ============ CSR build ============
__global__ __launch_bounds__(256) void hist_kernel(const int* __restrict__ ei, int* __restrict__ deg, int E)
{
    int e = blockIdx.x * 256 + threadIdx.x;
    if (e < E) atomicAdd(&deg[ei[E + e]], 1);
}

__global__ __launch_bounds__(1024) void scan_kernel(const int* __restrict__ deg,
                                                    int* __restrict__ rowptr,
                                                    int* __restrict__ cursor, int N)
{
    __shared__ int sums[1024];
    const int CH = 52;
    int t = threadIdx.x;
    int base = t * CH;
    int local = 0;
#pragma unroll
    for (int i = 0; i < 13; i++) {
        int idx = base + i * 4;
        if (idx + 3 < N) {
            int4 v = *(const int4*)(deg + idx);
            local += v.x + v.y + v.z + v.w;
        } else {
            for (int k = 0; k < 4; k++) if (idx + k < N) local += deg[idx + k];
        }
    }
    sums[t] = local;
    __syncthreads();
    for (int off = 1; off < 1024; off <<= 1) {
        int v = sums[t];
        int u = (t >= off) ? sums[t - off] : 0;
        __syncthreads();
        sums[t] = v + u;
        __syncthreads();
    }
    int run = (t == 0) ? 0 : sums[t - 1];
    for (int i = 0; i < CH; i++) {
        int idx = base + i;
        if (idx < N) {
            rowptr[idx] = run;
            cursor[idx] = run;
            run += deg[idx];
        }
    }
    if (t == 1023) rowptr[N] = sums[1023];
}

__global__ __launch_bounds__(256) void scatter_kernel(
    const int* __restrict__ ei, const int* __restrict__ bond,
    const float* __restrict__ coords, int* __restrict__ cursor,
    int2* __restrict__ csr, int E)
{
    int e = blockIdx.x * 256 + threadIdx.x;
    if (e >= E) return;
    int src = ei[e], dst = ei[E + e];
    int pos = atomicAdd(&cursor[dst], 1);
    float dx = coords[src * 3 + 0] - coords[dst * 3 + 0];
    float dy = coords[src * 3 + 1] - coords[dst * 3 + 1];
    float dz = coords[src * 3 + 2] - coords[dst * 3 + 2];
    float d2 = dx * dx + dy * dy + dz * dz;
    csr[pos] = make_int2(src | (bond[e] << 20), __float_as_int(d2));
}

// ============ per-node edge aggregation ============
__global__ __launch_bounds__(256) void edge_agg(
    const float* __restrict__ At, const float* __restrict__ Bt,
    const u16* __restrict__ G,
    const int* __restrict__ rowptr, const int2* __restrict__ csr,
    const float* __restrict__ conv_w, const float* __restrict__ conv_b,
    const float* __restrict__ b_nb, const float* __restrict__ b_el,
    u16* __restrict__ Pn, u16* __restrict__ Pe, float* __restrict__ z,
    float* __restrict__ s_arr, int N)
{
    int wave = threadIdx.x >> 6;
    int lane = threadIdx.x & 63;
    int node = blockIdx.x * 4 + wave;
    if (node >= N) return;
    int c0 = lane * 2;
    float2 at = *(const float2*)(At + (size_t)node * DD + c0);
    float2 bt = *(const float2*)(Bt + (size_t)node * DD + c0);
    float cb = conv_b[0];
    float cw0 = conv_w[0] + cb, cw1 = conv_w[1] + cb, cw2 = conv_w[2] + cb, cw3 = conv_w[3] + cb;
    float bn0 = b_nb[c0], bn1 = b_nb[c0 + 1];
    float be0 = b_el[c0], be1 = b_el[c0 + 1];
    float accn0 = 0.f, accn1 = 0.f, acce0 = 0.f, acce1 = 0.f, accz0 = 0.f, accz1 = 0.f, ssum = 0.f;
    int beg = rowptr[node], end = rowptr[node + 1];
#pragma unroll 2
    for (int k = beg; k < end; k++) {
        int2 pd = csr[k];
        int src = pd.x & 0xFFFFF;
        int bond = (pd.x >> 20) & 3;
        float w = (bond == 0) ? cw0 : (bond == 1) ? cw1 : (bond == 2) ? cw2 : cw3;
        float d2 = __int_as_float(pd.y);
        const u16* gp = G + (size_t)src * 384;
        u32 ga = *(const u32*)(gp + c0);
        u32 gb = *(const u32*)(gp + 128 + c0);
        u32 gx = *(const u32*)(gp + 256 + c0);
        float a0 = __builtin_bit_cast(float, ga << 16), a1 = __builtin_bit_cast(float, ga & 0xffff0000u);
        float b0 = __builtin_bit_cast(float, gb << 16), b1 = __builtin_bit_cast(float, gb & 0xffff0000u);
        float x0 = __builtin_bit_cast(float, gx << 16), x1 = __builtin_bit_cast(float, gx & 0xffff0000u);
        accn0 += mishf(at.x + a0 + bn0);
        accn1 += mishf(at.y + a1 + bn1);
        acce0 += mishf(w * (bt.x + b0) + be0);
        acce1 += mishf(w * (bt.y + b1) + be1);
        accz0 += d2 * x0;
        accz1 += d2 * x1;
        ssum += d2;
    }
    *(u32*)(Pn + (size_t)node * DD + c0) = (u32)f2bf(accn0) | ((u32)f2bf(accn1) << 16);
    *(u32*)(Pe + (size_t)node * DD + c0) = (u32)f2bf(acce0) | ((u32)f2bf(acce1) << 16);
    *(float2*)(z + (size_t)node * DD + c0) = make_float2(accz0, accz1);
    if (lane == 0) s_arr[node] = ssum;
}

// ============ backend: all 3 chains pooled (blockIdx.y = path), nt-split 4 waves ============
__global__ __launch_bounds__(256, 4) void backend_kernel(
    const u16* __restrict__ Pn, const u16* __restrict__ Pe, const float* __restrict__ z,
    const float* __restrict__ Ct, const u16* __restrict__ xWs, const u16* __restrict__ e0,
    const float* __restrict__ s_arr, const int* __restrict__ deg,
    const float* __restrict__ b_nout, const float* __restrict__ b_eout,
    const float* __restrict__ b_coord, const float* __restrict__ b_pair,
    const float* __restrict__ b_sout,
    const u16* __restrict__ Wh, const u16* __restrict__ Wl,
    u16* __restrict__ f1, u16* __restrict__ f2, u16* __restrict__ f3,
    float* __restrict__ e1, float* __restrict__ e2, float* __restrict__ e3, int M)
{
    __shared__ u16 sP[4 * PLANE];
    u16 *PH0 = sP, *PL0 = sP + PLANE, *PH1 = sP + 2 * PLANE, *PL1 = sP + 3 * PLANE;
    const int t = threadIdx.x, wave = t >> 6, lane = t & 63;
    const int lm = lane & 15, quad = lane >> 4;
    const int ntB = wave * 2;
    const int row0 = blockIdx.x * 16;
    const int path = blockIdx.y;

    bf16x8 ah[4], al[4];
    f32x4 acc[2];

    if (path < 2) {
        const u16* P = (path == 0) ? Pn : Pe;
        const float* bo = (path == 0) ? b_nout : b_eout;
        u16* fO = (path == 0) ? f1 : f2;
        float* eO = (path == 0) ? e1 : e2;
        const int mO = 11 + path, mF = 13 + path;
        // stage 1: f = mish(P@W_out + b_out) -> global bf16 + PH0
        frag_hi_global16(P, row0, lm, quad, M, ah);
        zero2(acc);
        gemm2<2>(ah, ah, Wh + (size_t)mO * WT, Wl + (size_t)mO * WT, lane, ntB, acc);
#pragma unroll
        for (int r = 0; r < 4; r++) {
            int grow = row0 + quad * 4 + r;
            bool inb = grow < M;
#pragma unroll
            for (int j = 0; j < 2; j++) {
                int col = (ntB + j) * 16 + lm;
                float v = mishf(acc[j][r] + bo[col]);
                u16 hv = f2bf(v);
                if (inb) fO[(size_t)grow * DD + col] = hv;
                PH0[(quad * 4 + r) * LDSS + col] = hv;
            }
        }
        __syncthreads();
        // stage 2: l = mish2(f@FL) -> PH1
        frag_hi_plane16(PH0, lm, quad, ah);
        zero2(acc);
        gemm2<2>(ah, ah, Wh + (size_t)mF * WT, Wl + (size_t)mF * WT, lane, ntB, acc);
#pragma unroll
        for (int r = 0; r < 4; r++)
#pragma unroll
            for (int j = 0; j < 2; j++)
                PH1[(quad * 4 + r) * LDSS + (ntB + j) * 16 + lm] = f2bf(mishf(mishf(acc[j][r])));
        __syncthreads();
        // stage 3: e = l@Wa_b + e0 -> fp32 global
        frag_hi_plane16(PH1, lm, quad, ah);
        zero2(acc);
        gemm2<2>(ah, ah, Wh + 16 * WT, Wl + 16 * WT, lane, ntB, acc);
#pragma unroll
        for (int r = 0; r < 4; r++) {
            int grow = row0 + quad * 4 + r;
            if (grow >= M) continue;
#pragma unroll
            for (int j = 0; j < 2; j++) {
                int col = (ntB + j) * 16 + lm;
                eO[(size_t)grow * DD + col] = acc[j][r] + bf2f(e0[(size_t)grow * DD + col]);
            }
        }
    } else {
        // stage 1: Qagg = z@Wc_s + s*Ct + deg*b_coord -> PH0/PL0
        frag_split_global16(z, row0, lm, quad, M, ah, al);
        zero2(acc);
        gemm2<3>(ah, al, Wh + 8 * WT, Wl + 8 * WT, lane, ntB, acc);
#pragma unroll
        for (int r = 0; r < 4; r++) {
            int crow = row0 + quad * 4 + r; if (crow >= M) crow = M - 1;
            float sv = s_arr[crow];
            float dv = (float)deg[crow];
#pragma unroll
            for (int j = 0; j < 2; j++) {
                int col = (ntB + j) * 16 + lm;
                float v = acc[j][r] + sv * Ct[(size_t)crow * DD + col] + dv * b_coord[col];
                int lidx = (quad * 4 + r) * LDSS + col;
                u16 h, l; splitv(v, h, l); PH0[lidx] = h; PL0[lidx] = l;
            }
        }
        __syncthreads();
        // stage 2: Q = mish(Qagg@W_pair + b_pair) -> PH1/PL1
        frag_planes16(PH0, PL0, lm, quad, ah, al);
        zero2(acc);
        gemm2<3>(ah, al, Wh + 9 * WT, Wl + 9 * WT, lane, ntB, acc);
#pragma unroll
        for (int r = 0; r < 4; r++)
#pragma unroll
            for (int j = 0; j < 2; j++) {
                int col = (ntB + j) * 16 + lm;
                int lidx = (quad * 4 + r) * LDSS + col;
                u16 h, l; splitv(mishf(acc[j][r] + b_pair[col]), h, l); PH1[lidx] = h; PL1[lidx] = l;
            }
        __syncthreads();
        // stage 3: f_struct = mish(Q@Ws_b + xWs + b_sout) -> global bf16 + PH0/PL0
        frag_planes16(PH1, PL1, lm, quad, ah, al);
        zero2(acc);
        gemm2<3>(ah, al, Wh + 10 * WT, Wl + 10 * WT, lane, ntB, acc);
#pragma unroll
        for (int r = 0; r < 4; r++) {
            int crow = row0 + quad * 4 + r; if (crow >= M) crow = M - 1;
            bool inb = (row0 + quad * 4 + r) < M;
#pragma unroll
            for (int j = 0; j < 2; j++) {
                int col = (ntB + j) * 16 + lm;
                float v = mishf(acc[j][r] + bf2f(xWs[(size_t)crow * DD + col]) + b_sout[col]);
                if (inb) f3[(size_t)crow * DD + col] = f2bf(v);
                int lidx = (quad * 4 + r) * LDSS + col;
                u16 h, l; splitv(v, h, l); PH0[lidx] = h; PL0[lidx] = l;
            }
        }
        __syncthreads();
        // stage 4: l2 = mish2(f_struct@FL2) -> PH1/PL1
        frag_planes16(PH0, PL0, lm, quad, ah, al);
        zero2(acc);
        gemm2<3>(ah, al, Wh + 15 * WT, Wl + 15 * WT, lane, ntB, acc);
#pragma unroll
        for (int r = 0; r < 4; r++)
#pragma unroll
            for (int j = 0; j < 2; j++) {
                int lidx = (quad * 4 + r) * LDSS + (ntB + j) * 16 + lm;
                u16 h, l; splitv(mishf(mishf(acc[j][r])), h, l); PH1[lidx] = h; PL1[lidx] = l;
            }
        __syncthreads();
        // stage 5: e3 = l2@Wa_b + e0 -> fp32 global
        frag_planes16(PH1, PL1, lm, quad, ah, al);
        zero2(acc);
        gemm2<3>(ah, al, Wh + 16 * WT, Wl + 16 * WT, lane, ntB, acc);
#pragma unroll
        for (int r = 0; r < 4; r++) {
            int grow = row0 + quad * 4 + r;
            if (grow >= M) continue;
#pragma unroll
            for (int j = 0; j < 2; j++) {
                int col = (ntB + j) * 16 + lm;
                e3[(size_t)grow * DD + col] = acc[j][r] + bf2f(e0[(size_t)grow * DD + col]);
            }
        }
    }
}

// ============ softmax combine + @W_agg (nt-split 4 waves) ============
__global__ __launch_bounds__(256, 4) void attagg_kernel(
    const float* __restrict__ e1, const float* __restrict__ e2, const float* __restrict__ e3,
    const u16* __restrict__ f1, const u16* __restrict__ f2, const u16* __restrict__ f3,
    const u16* __restrict__ Wh, const u16* __restrict__ Wl, float* __restrict__ hout, int M)
{
    __shared__ u16 sP[2 * PLANE];
    u16* PH = sP; u16* PL = sP + PLANE;
    const int t = threadIdx.x, wave = t >> 6, lane = t & 63;
    const int lm = lane & 15, quad = lane >> 4;
    const int ntB = wave * 2;
    const int row0 = blockIdx.x * 16;

#pragma unroll
    for (int r = 0; r < 4; r++) {
        int crow = row0 + quad * 4 + r; if (crow >= M) crow = M - 1;
#pragma unroll
        for (int j = 0; j < 2; j++) {
            int col = (ntB + j) * 16 + lm;
            size_t idx = (size_t)crow * DD + col;
            float x1 = e1[idx], x2 = e2[idx], x3 = e3[idx];
            float m = fmaxf(fmaxf(x1, x2), x3);
            float p1 = __expf(x1 - m), p2 = __expf(x2 - m), p3 = __expf(x3 - m);
            float att = (p1 * bf2f(f1[idx]) + p2 * bf2f(f2[idx]) + p3 * bf2f(f3[idx]))
                        * __builtin_amdgcn_rcpf(p1 + p2 + p3);
            int lidx = (quad * 4 + r) * LDSS + col;
            u16 h, l; splitv(att, h, l); PH[lidx] = h; PL[lidx] = l;
        }
    }
    __syncthreads();
    bf16x8 ah[4], al[4];
    frag_planes16(PH, PL, lm, quad, ah, al);
    f32x4 acc[2]; zero2(acc);
    gemm2<3>(ah, al, Wh + 17 * WT, Wl + 17 * WT, lane, ntB, acc);
#pragma unroll
    for (int r = 0; r < 4; r++) {
        int grow = row0 + quad * 4 + r;
        if (grow >= M) continue;
#pragma unroll
        for (int j = 0; j < 2; j++)
            hout[(size_t)grow * DD + (ntB + j) * 16 + lm] = acc[j][r];
    }
}

// ============ batchnorm ============
__global__ __launch_bounds__(256) void bn_stats(const float* __restrict__ h, float* __restrict__ sums, int N)
{
    int t = threadIdx.x;
    int col = t & 127;
    float s = 0.f, sq = 0.f;
    for (int r = blockIdx.x * 2 + (t >> 7); r < N; r += gridDim.x * 2) {
        float v = h[(size_t)r * DD + col];
        s += v; sq += v * v;
    }
    __shared__ float sh[256];
    sh[t] = s; __syncthreads();
    float s2 = (t < 128) ? (sh[t] + sh[t + 128]) : 0.f;
    __syncthreads();
    sh[t] = sq; __syncthreads();
    if (t < 128) {
        float q2 = sh[t] + sh[t + 128];
        atomicAdd(&sums[t], s2);
        atomicAdd(&sums[128 + t], q2);
    }
}

__global__ void bn_finalize(const float* __restrict__ sums, const float* __restrict__ gamma,
                            const float* __restrict__ beta, float* __restrict__ scale,
                            float* __restrict__ shift, float n_inv)
{
    int c = threadIdx.x;
    float mean = sums[c] * n_inv;
    float var = sums[128 + c] * n_inv - mean * mean;
    float inv = rsqrtf(var + 1e-5f);
    float sc = gamma[c] * inv;
    scale[c] = sc;
    shift[c] = beta[c] - mean * sc;
}

__global__ __launch_bounds__(256) void bn_apply(float* __restrict__ h, const float* __restrict__ scale,
                                                const float* __restrict__ shift, size_t total4)
{
    size_t idx = (size_t)blockIdx.x * 256 + threadIdx.x;
    if (idx >= total4) return;
    size_t off = idx * 4;
    int c = (int)(off & 127);
    float4 v = *(const float4*)(h + off);
    float4 sc = *(const float4*)(scale + c);
    float4 sh = *(const float4*)(shift + c);
    v.x = mishf(v.x * sc.x + sh.x);
    v.y = mishf(v.y * sc.y + sh.y);
    v.z = mishf(v.z * sc.z + sh.z);
    v.w = mishf(v.w * sc.w + sh.w);
    *(float4*)(h + off) = v;
}

// ============ host ============
extern "C" void kernel_launch(void* const* d_in, const int* in_sizes, int n_in,
                              void* d_out, int out_size, void* d_ws, size_t ws_size,
                              hipStream_t stream)
{
    (void)n_in; (void)out_size; (void)ws_size;
    const float* x       = (const float*)d_in[0];
    const float* coords  = (const float*)d_in[1];
    const int*   ei      = (const int*)d_in[2];
    const int*   bond    = (const int*)d_in[3];
    const float* W_nb    = (const float*)d_in[4];
    const float* b_nb    = (const float*)d_in[5];
    const float* W_nout  = (const float*)d_in[6];
    const float* b_nout  = (const float*)d_in[7];
    const float* conv_w  = (const float*)d_in[8];
    const float* conv_b  = (const float*)d_in[9];
    const float* W_el    = (const float*)d_in[10];
    const float* b_el    = (const float*)d_in[11];
    const float* W_eout  = (const float*)d_in[12];
    const float* b_eout  = (const float*)d_in[13];
    const float* W_coord = (const float*)d_in[14];
    const float* b_coord = (const float*)d_in[15];
    const float* W_pair  = (const float*)d_in[16];
    const float* b_pair  = (const float*)d_in[17];
    const float* W_sout  = (const float*)d_in[18];
    const float* b_sout  = (const float*)d_in[19];
    const float* W_init  = (const float*)d_in[20];
    const float* feat_lin= (const float*)d_in[21];
    const float* W_att   = (const float*)d_in[22];
    const float* W_agg   = (const float*)d_in[23];
    const float* gamma   = (const float*)d_in[24];
    const float* beta    = (const float*)d_in[25];

    const int N = in_sizes[0] / DD;     // 50000
    const int E = in_sizes[3];          // 800000
    const size_t ND = (size_t)N * DD;
    const int SUB = DD * DD;
    const int NB16 = (N + 15) / 16;

    char* base = (char*)d_ws;
    size_t off = 0;
    auto alloc = [&](size_t bytes) -> char* {
        char* p = base + off;
        off = (off + bytes + 63) & ~(size_t)63;
        return p;
    };
    u16*   G    = (u16*)alloc((size_t)N * 384 * 2);
    u16*   xWs  = (u16*)alloc(ND * 2);
    float* At   = (float*)alloc(ND * 4);   // dead after edge_agg -> aliased as e1
    float* Bt   = (float*)alloc(ND * 4);   // dead after edge_agg -> aliased as e2
    float* Ct   = (float*)alloc(ND * 4);
    u16*   e0   = (u16*)alloc(ND * 2);
    u16*   Pn   = (u16*)alloc(ND * 2);
    u16*   Pe   = (u16*)alloc(ND * 2);
    float* z    = (float*)alloc(ND * 4);   // consumed in backend S stage1 -> aliased as e3
    u16*   f1   = (u16*)alloc(ND * 2);
    u16*   f2   = (u16*)alloc(ND * 2);
    u16*   f3   = (u16*)alloc(ND * 2);
    u16*   Wh   = (u16*)alloc((size_t)18 * WT * 2);
    u16*   Wl   = (u16*)alloc((size_t)18 * WT * 2);
    int2*  csr  = (int2*)alloc((size_t)E * 8);
    int*   deg    = (int*)alloc((size_t)(N + 64) * 4);
    int*   rowptr = (int*)alloc((size_t)(N + 1) * 4);
    int*   cursor = (int*)alloc((size_t)N * 4);
    float* s_arr  = (float*)alloc((size_t)N * 4);
    float* bnsums  = (float*)alloc(256 * 4);
    float* bnscale = (float*)alloc(128 * 4);
    float* bnshift = (float*)alloc(128 * 4);

    float* hout = (float*)d_out;
    float* e1 = At;   // safe: At/Bt dead after edge_agg completes (stream order)
    float* e2 = Bt;
    float* e3 = z;    // safe: backend S block reads its z rows (stage1) before writing e3 (stage5)

    WSrc wsrc;
    wsrc.p[0] = W_nb;            wsrc.p[1] = W_nb + SUB;
    wsrc.p[2] = W_el;            wsrc.p[3] = W_el + SUB;
    wsrc.p[4] = W_coord;         wsrc.p[5] = W_sout;
    wsrc.p[6] = W_init;          wsrc.p[7] = W_att;
    wsrc.p[8] = W_coord + SUB;   wsrc.p[9] = W_pair;
    wsrc.p[10] = W_sout + SUB;   wsrc.p[11] = W_nout;
    wsrc.p[12] = W_eout;         wsrc.p[13] = feat_lin;
    wsrc.p[14] = feat_lin + SUB; wsrc.p[15] = feat_lin + 2 * SUB;
    wsrc.p[16] = W_att + SUB;    wsrc.p[17] = W_agg;

    const dim3 blk256(256);
    const dim3 gE((E + 255) / 256);
    const size_t total4 = ND / 4;
    const dim3 gElem((unsigned)((total4 + 255) / 256));

    prep_weights<<<dim3(18 * 8), blk256, 0, stream>>>(wsrc, Wh, Wl);
    front_kernel<<<NB16, blk256, 0, stream>>>(x, Wh, Wl, G, xWs, At, Bt, Ct, e0, N);

    hipMemsetAsync(deg, 0, (size_t)N * 4, stream);
    hist_kernel<<<gE, blk256, 0, stream>>>(ei, deg, E);
    scan_kernel<<<1, 1024, 0, stream>>>(deg, rowptr, cursor, N);
    scatter_kernel<<<gE, blk256, 0, stream>>>(ei, bond, coords, cursor, csr, E);

    edge_agg<<<(N + 3) / 4, blk256, 0, stream>>>(At, Bt, G, rowptr, csr, conv_w, conv_b,
                                                 b_nb, b_el, Pn, Pe, z, s_arr, N);

    backend_kernel<<<dim3(NB16, 3), blk256, 0, stream>>>(Pn, Pe, z, Ct, xWs, e0, s_arr, deg,
                                                         b_nout, b_eout, b_coord, b_pair, b_sout,
                                                         Wh, Wl, f1, f2, f3, e1, e2, e3, N);

    attagg_kernel<<<NB16, blk256, 0, stream>>>(e1, e2, e3, f1, f2, f3, Wh, Wl, hout, N);

    hipMemsetAsync(bnsums, 0, 256 * 4, stream);
    bn_stats<<<512, blk256, 0, stream>>>(hout, bnsums, N);
    bn_finalize<<<1, 128, 0, stream>>>(bnsums, gamma, beta, bnscale, bnshift, 1.0f / (float)N);
    bn_apply<<<gElem, blk256, 0, stream>>>(hout, bnscale, bnshift, total4);
}

// Round 8
// 623.420 us; speedup vs baseline: 1.6940x; 1.0457x over previous
//
#include <hip/hip_runtime.h>
#include <math.h>

#define DD 128
#define LDSS 136            // u16 LDS row stride (128 + 8 pad)
#define PLANE (16 * LDSS)   // u16 elements per 16-row plane
#define WT 16384            // u16 elements per packed 128x128 weight matrix

typedef __attribute__((ext_vector_type(8))) short bf16x8;
typedef __attribute__((ext_vector_type(4))) float f32x4;
typedef unsigned short u16;
typedef unsigned int u32;

__device__ __forceinline__ u16 f2bf(float f) {          // RNE (stored tensors)
    u32 u = __builtin_bit_cast(u32, f);
    u += 0x7fffu + ((u >> 16) & 1u);
    return (u16)(u >> 16);
}
__device__ __forceinline__ float bf2f(u16 h) {
    u32 u = ((u32)h) << 16;
    return __builtin_bit_cast(float, u);
}
__device__ __forceinline__ float mishf(float x) {
    float e = __expf(fminf(x, 15.0f));
    float n = e * (e + 2.0f);
    return x * n * __builtin_amdgcn_rcpf(n + 2.0f);
}
// truncating hi/lo split (3 VALU ops, reconstruction err ~2^-16)
__device__ __forceinline__ void splitv(float v, u16& h, u16& l) {
    u32 u = __builtin_bit_cast(u32, v);
    h = (u16)(u >> 16);
    float r = v - __builtin_bit_cast(float, u & 0xffff0000u);
    l = (u16)(__builtin_bit_cast(u32, r) >> 16);
}

// 2-nt-tile GEMM slice. NM=1: ah*bh ; NM=2: ah*(bh+bl) ; NM=3: + al*bh
template<int NM>
__device__ __forceinline__ void gemm2(const bf16x8* ah, const bf16x8* al,
    const u16* __restrict__ Wh, const u16* __restrict__ Wl, int lane, int ntB, f32x4* acc)
{
#pragma unroll
    for (int kb = 0; kb < 4; kb++)
#pragma unroll
        for (int j = 0; j < 2; j++) {
            size_t boff = (((size_t)kb * 8 + ntB + j) * 64 + lane) * 8;
            bf16x8 bh = *(const bf16x8*)(Wh + boff);
            acc[j] = __builtin_amdgcn_mfma_f32_16x16x32_bf16(ah[kb], bh, acc[j], 0, 0, 0);
            if (NM >= 2) {
                bf16x8 bl = *(const bf16x8*)(Wl + boff);
                acc[j] = __builtin_amdgcn_mfma_f32_16x16x32_bf16(ah[kb], bl, acc[j], 0, 0, 0);
            }
            if (NM == 3)
                acc[j] = __builtin_amdgcn_mfma_f32_16x16x32_bf16(al[kb], bh, acc[j], 0, 0, 0);
        }
}

__device__ __forceinline__ void zero2(f32x4* acc) {
    f32x4 z4 = {0.f, 0.f, 0.f, 0.f};
    acc[0] = z4; acc[1] = z4;
}

__device__ __forceinline__ void frag_hi_global16(const u16* __restrict__ src, int row0,
                                                 int lm, int quad, int M, bf16x8* ah)
{
    int row = row0 + lm; if (row >= M) row = M - 1;
    const u16* p = src + (size_t)row * DD + quad * 8;
#pragma unroll
    for (int kb = 0; kb < 4; kb++) ah[kb] = *(const bf16x8*)(p + kb * 32);
}
__device__ __forceinline__ void frag_split_global16(const float* __restrict__ src, int row0,
                                                    int lm, int quad, int M, bf16x8* ah, bf16x8* al)
{
    int row = row0 + lm; if (row >= M) row = M - 1;
    const float* p = src + (size_t)row * DD + quad * 8;
#pragma unroll
    for (int kb = 0; kb < 4; kb++) {
        float tmp[8];
        *(float4*)tmp       = *(const float4*)(p + kb * 32);
        *(float4*)(tmp + 4) = *(const float4*)(p + kb * 32 + 4);
#pragma unroll
        for (int j = 0; j < 8; j++) { u16 h, l; splitv(tmp[j], h, l); ah[kb][j] = (short)h; al[kb][j] = (short)l; }
    }
}
__device__ __forceinline__ void frag_hi_plane16(const u16* P, int lm, int quad, bf16x8* ah)
{
    const u16* p = P + (size_t)lm * LDSS + quad * 8;
#pragma unroll
    for (int kb = 0; kb < 4; kb++) ah[kb] = *(const bf16x8*)(p + kb * 32);
}
__device__ __forceinline__ void frag_planes16(const u16* PH, const u16* PL, int lm, int quad,
                                              bf16x8* ah, bf16x8* al)
{
    const u16* ph = PH + (size_t)lm * LDSS + quad * 8;
    const u16* pl = PL + (size_t)lm * LDSS + quad * 8;
#pragma unroll
    for (int kb = 0; kb < 4; kb++) {
        ah[kb] = *(const bf16x8*)(ph + kb * 32);
        al[kb] = *(const bf16x8*)(pl + kb * 32);
    }
}

// ============ weight prep ============
struct WSrc { const float* p[18]; };

__global__ __launch_bounds__(256) void prep_weights(WSrc ws, u16* __restrict__ Wh, u16* __restrict__ Wl)
{
    int mat = blockIdx.x >> 3, chunk = blockIdx.x & 7;
    int t = threadIdx.x;
    int tt = chunk * 4 + (t >> 6);
    int lane = t & 63;
    int kb = tt >> 3, nt = tt & 7;
    const float* __restrict__ src = ws.p[mat];
    size_t doff = (size_t)mat * WT + ((size_t)tt * 64 + lane) * 8;
    int srow = kb * 32 + ((lane >> 4) * 8);
    int scol = nt * 16 + (lane & 15);
    u16 th[8], tl[8];
#pragma unroll
    for (int j = 0; j < 8; j++) {
        float v = src[(srow + j) * DD + scol];
        u16 h = f2bf(v);
        th[j] = h;
        tl[j] = f2bf(v - bf2f(h));
    }
    *(bf16x8*)(Wh + doff) = *(bf16x8*)th;
    *(bf16x8*)(Wl + doff) = *(bf16x8*)tl;
}

// drain a 16-row bf16 plane into G segment, 4 rows per wave
__device__ __forceinline__ void drainG(const u16* P, u16* __restrict__ G, int seg,
                                       int row0, int wave, int lane, int M)
{
#pragma unroll
    for (int i = 0; i < 4; i++) {
        int r = wave * 4 + i;
        int grow = row0 + r;
        u32 v = *(const u32*)&P[r * LDSS + lane * 2];
        if (grow < M) *(u32*)(G + (size_t)grow * 384 + seg * 128 + lane * 2) = v;
    }
}

// ============ front: x read once -> G=[As|Bs|xb], xWs, At, Bt, Ct ============
__global__ __launch_bounds__(256, 4) void front_kernel(
    const float* __restrict__ x, const u16* __restrict__ Wh, const u16* __restrict__ Wl,
    u16* __restrict__ G, u16* __restrict__ xWs,
    float* __restrict__ At, float* __restrict__ Bt, float* __restrict__ Ct, int M)
{
    __shared__ u16 sP[2 * PLANE];
    u16* P0 = sP; u16* P1 = sP + PLANE;
    const int t = threadIdx.x, wave = t >> 6, lane = t & 63;
    const int lm = lane & 15, quad = lane >> 4;
    const int ntB = wave * 2;
    const int row0 = blockIdx.x * 16;

    bf16x8 ah[4], al[4];
    {   // every wave loads the same 16 rows (L1 hits); wave 0 writes the xb plane
        int row = row0 + lm; if (row >= M) row = M - 1;
        const float* p = x + (size_t)row * DD + quad * 8;
#pragma unroll
        for (int kb = 0; kb < 4; kb++) {
            float tmp[8];
            *(float4*)tmp       = *(const float4*)(p + kb * 32);
            *(float4*)(tmp + 4) = *(const float4*)(p + kb * 32 + 4);
#pragma unroll
            for (int j = 0; j < 8; j++) {
                u16 h, l; splitv(tmp[j], h, l);
                ah[kb][j] = (short)h; al[kb][j] = (short)l;
                if (wave == 0) P0[lm * LDSS + kb * 32 + quad * 8 + j] = f2bf(tmp[j]);
            }
        }
    }
    __syncthreads();
    drainG(P0, G, 2, row0, wave, lane, M);   // xb
    __syncthreads();
    {   // As = x@W1 -> P1 -> G seg0
        f32x4 acc[2]; zero2(acc);
        gemm2<1>(ah, ah, Wh + 1 * WT, Wh, lane, ntB, acc);
#pragma unroll
        for (int r = 0; r < 4; r++)
#pragma unroll
            for (int j = 0; j < 2; j++)
                P1[(quad * 4 + r) * LDSS + (ntB + j) * 16 + lm] = f2bf(acc[j][r]);
        __syncthreads();
        drainG(P1, G, 0, row0, wave, lane, M);
        __syncthreads();
    }
    {   // Bs = x@W3 -> P0 -> G seg1
        f32x4 acc[2]; zero2(acc);
        gemm2<1>(ah, ah, Wh + 3 * WT, Wh, lane, ntB, acc);
#pragma unroll
        for (int r = 0; r < 4; r++)
#pragma unroll
            for (int j = 0; j < 2; j++)
                P0[(quad * 4 + r) * LDSS + (ntB + j) * 16 + lm] = f2bf(acc[j][r]);
        __syncthreads();
        drainG(P0, G, 1, row0, wave, lane, M);
    }
    {   // xWs = x@W5 -> global bf16
        f32x4 acc[2]; zero2(acc);
        gemm2<1>(ah, ah, Wh + 5 * WT, Wh, lane, ntB, acc);
#pragma unroll
        for (int r = 0; r < 4; r++) {
            int grow = row0 + quad * 4 + r;
            if (grow >= M) continue;
#pragma unroll
            for (int j = 0; j < 2; j++)
                xWs[(size_t)grow * DD + (ntB + j) * 16 + lm] = f2bf(acc[j][r]);
        }
    }
    {   // At, Bt, Ct (split, fp32 out)
        float* outs[3] = {At, Bt, Ct};
        const int mats[3] = {0, 2, 4};
#pragma unroll
        for (int wi = 0; wi < 3; wi++) {
            f32x4 acc[2]; zero2(acc);
            gemm2<3>(ah, al, Wh + (size_t)mats[wi] * WT, Wl + (size_t)mats[wi] * WT, lane, ntB, acc);
            float* out = outs[wi];
#pragma unroll
            for (int r = 0; r < 4; r++) {
                int grow = row0 + quad * 4 + r;
                if (grow >= M) continue;
#pragma unroll
                for (int j = 0; j < 2; j++)
                    out[(size_t)grow * DD + (ntB + j) * 16 + lm] = acc[j][r];
            }
        }
    }
}

// ============ CSR build ============
__global__ __launch_bounds__(256) void hist_kernel(const int* __restrict__ ei, int* __restrict__ deg, int E)
{
    int e = blockIdx.x * 256 + threadIdx.x;
    if (e < E) atomicAdd(&deg[ei[E + e]], 1);
}

__global__ __launch_bounds__(1024) void scan_kernel(const int* __restrict__ deg,
                                                    int* __restrict__ rowptr,
                                                    int* __restrict__ cursor, int N)
{
    __shared__ int sums[1024];
    const int CH = 52;
    int t = threadIdx.x;
    int base = t * CH;
    int local = 0;
#pragma unroll
    for (int i = 0; i < 13; i++) {
        int idx = base + i * 4;
        if (idx + 3 < N) {
            int4 v = *(const int4*)(deg + idx);
            local += v.x + v.y + v.z + v.w;
        } else {
            for (int k = 0; k < 4; k++) if (idx + k < N) local += deg[idx + k];
        }
    }
    sums[t] = local;
    __syncthreads();
    for (int off = 1; off < 1024; off <<= 1) {
        int v = sums[t];
        int u = (t >= off) ? sums[t - off] : 0;
        __syncthreads();
        sums[t] = v + u;
        __syncthreads();
    }
    int run = (t == 0) ? 0 : sums[t - 1];
    for (int i = 0; i < CH; i++) {
        int idx = base + i;
        if (idx < N) {
            rowptr[idx] = run;
            cursor[idx] = run;
            run += deg[idx];
        }
    }
    if (t == 1023) rowptr[N] = sums[1023];
}

__global__ __launch_bounds__(256) void scatter_kernel(
    const int* __restrict__ ei, const int* __restrict__ bond,
    const float* __restrict__ coords, int* __restrict__ cursor,
    int2* __restrict__ csr, int E)
{
    int e = blockIdx.x * 256 + threadIdx.x;
    if (e >= E) return;
    int src = ei[e], dst = ei[E + e];
    int pos = atomicAdd(&cursor[dst], 1);
    float dx = coords[src * 3 + 0] - coords[dst * 3 + 0];
    float dy = coords[src * 3 + 1] - coords[dst * 3 + 1];
    float dz = coords[src * 3 + 2] - coords[dst * 3 + 2];
    float d2 = dx * dx + dy * dy + dz * dz;
    csr[pos] = make_int2(src | (bond[e] << 20), __float_as_int(d2));
}

// ============ per-node edge aggregation ============
__global__ __launch_bounds__(256) void edge_agg(
    const float* __restrict__ At, const float* __restrict__ Bt,
    const u16* __restrict__ G,
    const int* __restrict__ rowptr, const int2* __restrict__ csr,
    const float* __restrict__ conv_w, const float* __restrict__ conv_b,
    const float* __restrict__ b_nb, const float* __restrict__ b_el,
    u16* __restrict__ Pn, u16* __restrict__ Pe, float* __restrict__ z,
    float* __restrict__ s_arr, int N)
{
    int wave = threadIdx.x >> 6;
    int lane = threadIdx.x & 63;
    int node = blockIdx.x * 4 + wave;
    if (node >= N) return;
    int c0 = lane * 2;
    float2 at = *(const float2*)(At + (size_t)node * DD + c0);
    float2 bt = *(const float2*)(Bt + (size_t)node * DD + c0);
    float cb = conv_b[0];
    float cw0 = conv_w[0] + cb, cw1 = conv_w[1] + cb, cw2 = conv_w[2] + cb, cw3 = conv_w[3] + cb;
    float bn0 = b_nb[c0], bn1 = b_nb[c0 + 1];
    float be0 = b_el[c0], be1 = b_el[c0 + 1];
    float accn0 = 0.f, accn1 = 0.f, acce0 = 0.f, acce1 = 0.f, accz0 = 0.f, accz1 = 0.f, ssum = 0.f;
    int beg = rowptr[node], end = rowptr[node + 1];
#pragma unroll 2
    for (int k = beg; k < end; k++) {
        int2 pd = csr[k];
        int src = pd.x & 0xFFFFF;
        int bond = (pd.x >> 20) & 3;
        float w = (bond == 0) ? cw0 : (bond == 1) ? cw1 : (bond == 2) ? cw2 : cw3;
        float d2 = __int_as_float(pd.y);
        const u16* gp = G + (size_t)src * 384;
        u32 ga = *(const u32*)(gp + c0);
        u32 gb = *(const u32*)(gp + 128 + c0);
        u32 gx = *(const u32*)(gp + 256 + c0);
        float a0 = __builtin_bit_cast(float, ga << 16), a1 = __builtin_bit_cast(float, ga & 0xffff0000u);
        float b0 = __builtin_bit_cast(float, gb << 16), b1 = __builtin_bit_cast(float, gb & 0xffff0000u);
        float x0 = __builtin_bit_cast(float, gx << 16), x1 = __builtin_bit_cast(float, gx & 0xffff0000u);
        accn0 += mishf(at.x + a0 + bn0);
        accn1 += mishf(at.y + a1 + bn1);
        acce0 += mishf(w * (bt.x + b0) + be0);
        acce1 += mishf(w * (bt.y + b1) + be1);
        accz0 += d2 * x0;
        accz1 += d2 * x1;
        ssum += d2;
    }
    *(u32*)(Pn + (size_t)node * DD + c0) = (u32)f2bf(accn0) | ((u32)f2bf(accn1) << 16);
    *(u32*)(Pe + (size_t)node * DD + c0) = (u32)f2bf(acce0) | ((u32)f2bf(acce1) << 16);
    *(float2*)(z + (size_t)node * DD + c0) = make_float2(accz0, accz1);
    if (lane == 0) s_arr[node] = ssum;
}

// ============ NE chain (3 stages) — f packed to fp[4], d to dv[8] ============
__device__ __forceinline__ void chainNE_dev(
    const u16* __restrict__ P, const float* __restrict__ bo, int mO, int mF,
    const u16* __restrict__ Wh, const u16* __restrict__ Wl,
    u16* WH0, u16* WH1,
    int row0, int lane, int lm, int quad, int ntB, int M,
    u32* fp, float* dv)
{
    bf16x8 ah[4];
    f32x4 acc[2];
    // stage 1: f = mish(P@W_out + b_out) -> regs + WH0
    frag_hi_global16(P, row0, lm, quad, M, ah);
    zero2(acc);
    gemm2<2>(ah, ah, Wh + (size_t)mO * WT, Wl + (size_t)mO * WT, lane, ntB, acc);
#pragma unroll
    for (int r = 0; r < 4; r++) {
        u32 pk = 0;
#pragma unroll
        for (int j = 0; j < 2; j++) {
            int col = (ntB + j) * 16 + lm;
            u16 hv = f2bf(mishf(acc[j][r] + bo[col]));
            pk |= ((u32)hv) << (16 * j);
            WH0[(quad * 4 + r) * LDSS + col] = hv;
        }
        fp[r] = pk;
    }
    __syncthreads();
    // stage 2: l = mish2(f@FL) -> WH1
    frag_hi_plane16(WH0, lm, quad, ah);
    zero2(acc);
    gemm2<2>(ah, ah, Wh + (size_t)mF * WT, Wl + (size_t)mF * WT, lane, ntB, acc);
#pragma unroll
    for (int r = 0; r < 4; r++)
#pragma unroll
        for (int j = 0; j < 2; j++)
            WH1[(quad * 4 + r) * LDSS + (ntB + j) * 16 + lm] = f2bf(mishf(mishf(acc[j][r])));
    __syncthreads();
    // stage 3: d = l@Wa_b -> regs  (e0 cancels in softmax)
    frag_hi_plane16(WH1, lm, quad, ah);
    zero2(acc);
    gemm2<2>(ah, ah, Wh + 16 * WT, Wl + 16 * WT, lane, ntB, acc);
#pragma unroll
    for (int r = 0; r < 4; r++)
#pragma unroll
        for (int j = 0; j < 2; j++)
            dv[r * 2 + j] = acc[j][r];
}

// ============ mega: all 3 chains + softmax + @W_agg, f/d in registers ============
__global__ __launch_bounds__(256, 4) void mega_kernel(
    const u16* __restrict__ Pn, const u16* __restrict__ Pe, const float* __restrict__ z,
    const float* __restrict__ Ct, const u16* __restrict__ xWs,
    const float* __restrict__ s_arr, const int* __restrict__ deg,
    const float* __restrict__ b_nout, const float* __restrict__ b_eout,
    const float* __restrict__ b_coord, const float* __restrict__ b_pair,
    const float* __restrict__ b_sout,
    const u16* __restrict__ Wh, const u16* __restrict__ Wl,
    float* __restrict__ hout, int M)
{
    __shared__ u16 sP[4 * PLANE];
    u16 *WH0 = sP, *WL0 = sP + PLANE, *WH1 = sP + 2 * PLANE, *WL1 = sP + 3 * PLANE;
    const int t = threadIdx.x, wave = t >> 6, lane = t & 63;
    const int lm = lane & 15, quad = lane >> 4;
    const int ntB = wave * 2;
    const int row0 = blockIdx.x * 16;

    u32 f1p[4], f2p[4], f3p[4];
    float d1v[8], d2v[8];

    // ---- node & edge chains (hi-only planes) ----
    chainNE_dev(Pn, b_nout, 11, 13, Wh, Wl, WH0, WH1, row0, lane, lm, quad, ntB, M, f1p, d1v);
    chainNE_dev(Pe, b_eout, 12, 14, Wh, Wl, WH0, WH1, row0, lane, lm, quad, ntB, M, f2p, d2v);

    // ---- struct chain (hi/lo planes) ----
    bf16x8 ah[4], al[4];
    f32x4 acc[2];
    // S1: Qagg = z@Wc_s + s*Ct + deg*b_coord -> WH0/WL0
    frag_split_global16(z, row0, lm, quad, M, ah, al);
    zero2(acc);
    gemm2<3>(ah, al, Wh + 8 * WT, Wl + 8 * WT, lane, ntB, acc);
#pragma unroll
    for (int r = 0; r < 4; r++) {
        int crow = row0 + quad * 4 + r; if (crow >= M) crow = M - 1;
        float sv = s_arr[crow];
        float dv = (float)deg[crow];
#pragma unroll
        for (int j = 0; j < 2; j++) {
            int col = (ntB + j) * 16 + lm;
            float v = acc[j][r] + sv * Ct[(size_t)crow * DD + col] + dv * b_coord[col];
            int lidx = (quad * 4 + r) * LDSS + col;
            u16 h, l; splitv(v, h, l); WH0[lidx] = h; WL0[lidx] = l;
        }
    }
    __syncthreads();
    // S2: Q = mish(Qagg@W_pair + b_pair) -> WH1/WL1
    frag_planes16(WH0, WL0, lm, quad, ah, al);
    zero2(acc);
    gemm2<3>(ah, al, Wh + 9 * WT, Wl + 9 * WT, lane, ntB, acc);
#pragma unroll
    for (int r = 0; r < 4; r++)
#pragma unroll
        for (int j = 0; j < 2; j++) {
            int col = (ntB + j) * 16 + lm;
            int lidx = (quad * 4 + r) * LDSS + col;
            u16 h, l; splitv(mishf(acc[j][r] + b_pair[col]), h, l); WH1[lidx] = h; WL1[lidx] = l;
        }
    __syncthreads();
    // S3: f_struct = mish(Q@Ws_b + xWs + b_sout) -> f3 regs + WH0/WL0
    frag_planes16(WH1, WL1, lm, quad, ah, al);
    zero2(acc);
    gemm2<3>(ah, al, Wh + 10 * WT, Wl + 10 * WT, lane, ntB, acc);
#pragma unroll
    for (int r = 0; r < 4; r++) {
        int crow = row0 + quad * 4 + r; if (crow >= M) crow = M - 1;
        u32 pk = 0;
#pragma unroll
        for (int j = 0; j < 2; j++) {
            int col = (ntB + j) * 16 + lm;
            float v = mishf(acc[j][r] + bf2f(xWs[(size_t)crow * DD + col]) + b_sout[col]);
            u16 h, l; splitv(v, h, l);
            pk |= ((u32)f2bf(v)) << (16 * j);
            int lidx = (quad * 4 + r) * LDSS + col;
            WH0[lidx] = h; WL0[lidx] = l;
        }
        f3p[r] = pk;
    }
    __syncthreads();
    // S4: l2 = mish2(f_struct@FL2) -> WH1/WL1
    frag_planes16(WH0, WL0, lm, quad, ah, al);
    zero2(acc);
    gemm2<3>(ah, al, Wh + 15 * WT, Wl + 15 * WT, lane, ntB, acc);
#pragma unroll
    for (int r = 0; r < 4; r++)
#pragma unroll
        for (int j = 0; j < 2; j++) {
            int lidx = (quad * 4 + r) * LDSS + (ntB + j) * 16 + lm;
            u16 h, l; splitv(mishf(mishf(acc[j][r])), h, l); WH1[lidx] = h; WL1[lidx] = l;
        }
    __syncthreads();
    // S5: d3 = l2@Wa_b -> acc
    frag_planes16(WH1, WL1, lm, quad, ah, al);
    zero2(acc);
    gemm2<3>(ah, al, Wh + 16 * WT, Wl + 16 * WT, lane, ntB, acc);

    // ---- combine: softmax over paths (e0 cancels) -> att hi/lo into WH0/WL0 ----
#pragma unroll
    for (int r = 0; r < 4; r++)
#pragma unroll
        for (int j = 0; j < 2; j++) {
            int i = r * 2 + j;
            float x1 = d1v[i], x2 = d2v[i], x3 = acc[j][r];
            float m = fmaxf(fmaxf(x1, x2), x3);
            float p1 = __expf(x1 - m), p2 = __expf(x2 - m), p3 = __expf(x3 - m);
            float fv1 = bf2f((u16)(f1p[r] >> (16 * j)));
            float fv2 = bf2f((u16)(f2p[r] >> (16 * j)));
            float fv3 = bf2f((u16)(f3p[r] >> (16 * j)));
            float att = (p1 * fv1 + p2 * fv2 + p3 * fv3) * __builtin_amdgcn_rcpf(p1 + p2 + p3);
            int lidx = (quad * 4 + r) * LDSS + (ntB + j) * 16 + lm;
            u16 h, l; splitv(att, h, l); WH0[lidx] = h; WL0[lidx] = l;
        }
    __syncthreads();
    // ---- h_agg = att@W_agg -> hout fp32 ----
    frag_planes16(WH0, WL0, lm, quad, ah, al);
    zero2(acc);
    gemm2<3>(ah, al, Wh + 17 * WT, Wl + 17 * WT, lane, ntB, acc);
#pragma unroll
    for (int r = 0; r < 4; r++) {
        int grow = row0 + quad * 4 + r;
        if (grow >= M) continue;
#pragma unroll
        for (int j = 0; j < 2; j++)
            hout[(size_t)grow * DD + (ntB + j) * 16 + lm] = acc[j][r];
    }
}

// ============ batchnorm ============
__global__ __launch_bounds__(256) void bn_stats(const float* __restrict__ h, float* __restrict__ sums, int N)
{
    int t = threadIdx.x;
    int col = t & 127;
    float s = 0.f, sq = 0.f;
    for (int r = blockIdx.x * 2 + (t >> 7); r < N; r += gridDim.x * 2) {
        float v = h[(size_t)r * DD + col];
        s += v; sq += v * v;
    }
    __shared__ float sh[256];
    sh[t] = s; __syncthreads();
    float s2 = (t < 128) ? (sh[t] + sh[t + 128]) : 0.f;
    __syncthreads();
    sh[t] = sq; __syncthreads();
    if (t < 128) {
        float q2 = sh[t] + sh[t + 128];
        atomicAdd(&sums[t], s2);
        atomicAdd(&sums[128 + t], q2);
    }
}

__global__ void bn_finalize(const float* __restrict__ sums, const float* __restrict__ gamma,
                            const float* __restrict__ beta, float* __restrict__ scale,
                            float* __restrict__ shift, float n_inv)
{
    int c = threadIdx.x;
    float mean = sums[c] * n_inv;
    float var = sums[128 + c] * n_inv - mean * mean;
    float inv = rsqrtf(var + 1e-5f);
    float sc = gamma[c] * inv;
    scale[c] = sc;
    shift[c] = beta[c] - mean * sc;
}

__global__ __launch_bounds__(256) void bn_apply(float* __restrict__ h, const float* __restrict__ scale,
                                                const float* __restrict__ shift, size_t total4)
{
    size_t idx = (size_t)blockIdx.x * 256 + threadIdx.x;
    if (idx >= total4) return;
    size_t off = idx * 4;
    int c = (int)(off & 127);
    float4 v = *(const float4*)(h + off);
    float4 sc = *(const float4*)(scale + c);
    float4 sh = *(const float4*)(shift + c);
    v.x = mishf(v.x * sc.x + sh.x);
    v.y = mishf(v.y * sc.y + sh.y);
    v.z = mishf(v.z * sc.z + sh.z);
    v.w = mishf(v.w * sc.w + sh.w);
    *(float4*)(h + off) = v;
}

// ============ host ============
extern "C" void kernel_launch(void* const* d_in, const int* in_sizes, int n_in,
                              void* d_out, int out_size, void* d_ws, size_t ws_size,
                              hipStream_t stream)
{
    (void)n_in; (void)out_size; (void)ws_size;
    const float* x       = (const float*)d_in[0];
    const float* coords  = (const float*)d_in[1];
    const int*   ei      = (const int*)d_in[2];
    const int*   bond    = (const int*)d_in[3];
    const float* W_nb    = (const float*)d_in[4];
    const float* b_nb    = (const float*)d_in[5];
    const float* W_nout  = (const float*)d_in[6];
    const float* b_nout  = (const float*)d_in[7];
    const float* conv_w  = (const float*)d_in[8];
    const float* conv_b  = (const float*)d_in[9];
    const float* W_el    = (const float*)d_in[10];
    const float* b_el    = (const float*)d_in[11];
    const float* W_eout  = (const float*)d_in[12];
    const float* b_eout  = (const float*)d_in[13];
    const float* W_coord = (const float*)d_in[14];
    const float* b_coord = (const float*)d_in[15];
    const float* W_pair  = (const float*)d_in[16];
    const float* b_pair  = (const float*)d_in[17];
    const float* W_sout  = (const float*)d_in[18];
    const float* b_sout  = (const float*)d_in[19];
    const float* W_init  = (const float*)d_in[20];
    const float* feat_lin= (const float*)d_in[21];
    const float* W_att   = (const float*)d_in[22];
    const float* W_agg   = (const float*)d_in[23];
    const float* gamma   = (const float*)d_in[24];
    const float* beta    = (const float*)d_in[25];

    const int N = in_sizes[0] / DD;     // 50000
    const int E = in_sizes[3];          // 800000
    const size_t ND = (size_t)N * DD;
    const int SUB = DD * DD;
    const int NB16 = (N + 15) / 16;

    char* base = (char*)d_ws;
    size_t off = 0;
    auto alloc = [&](size_t bytes) -> char* {
        char* p = base + off;
        off = (off + bytes + 63) & ~(size_t)63;
        return p;
    };
    u16*   G    = (u16*)alloc((size_t)N * 384 * 2);
    u16*   xWs  = (u16*)alloc(ND * 2);
    float* At   = (float*)alloc(ND * 4);
    float* Bt   = (float*)alloc(ND * 4);
    float* Ct   = (float*)alloc(ND * 4);
    u16*   Pn   = (u16*)alloc(ND * 2);
    u16*   Pe   = (u16*)alloc(ND * 2);
    float* z    = (float*)alloc(ND * 4);
    u16*   Wh   = (u16*)alloc((size_t)18 * WT * 2);
    u16*   Wl   = (u16*)alloc((size_t)18 * WT * 2);
    int2*  csr  = (int2*)alloc((size_t)E * 8);
    int*   deg    = (int*)alloc((size_t)(N + 64) * 4);
    int*   rowptr = (int*)alloc((size_t)(N + 1) * 4);
    int*   cursor = (int*)alloc((size_t)N * 4);
    float* s_arr  = (float*)alloc((size_t)N * 4);
    float* bnsums  = (float*)alloc(256 * 4);
    float* bnscale = (float*)alloc(128 * 4);
    float* bnshift = (float*)alloc(128 * 4);

    float* hout = (float*)d_out;

    WSrc wsrc;
    wsrc.p[0] = W_nb;            wsrc.p[1] = W_nb + SUB;
    wsrc.p[2] = W_el;            wsrc.p[3] = W_el + SUB;
    wsrc.p[4] = W_coord;         wsrc.p[5] = W_sout;
    wsrc.p[6] = W_init;          wsrc.p[7] = W_att;      // 6,7 unused (e0 cancels) — kept for layout
    wsrc.p[8] = W_coord + SUB;   wsrc.p[9] = W_pair;
    wsrc.p[10] = W_sout + SUB;   wsrc.p[11] = W_nout;
    wsrc.p[12] = W_eout;         wsrc.p[13] = feat_lin;
    wsrc.p[14] = feat_lin + SUB; wsrc.p[15] = feat_lin + 2 * SUB;
    wsrc.p[16] = W_att + SUB;    wsrc.p[17] = W_agg;

    const dim3 blk256(256);
    const dim3 gE((E + 255) / 256);
    const size_t total4 = ND / 4;
    const dim3 gElem((unsigned)((total4 + 255) / 256));

    prep_weights<<<dim3(18 * 8), blk256, 0, stream>>>(wsrc, Wh, Wl);
    front_kernel<<<NB16, blk256, 0, stream>>>(x, Wh, Wl, G, xWs, At, Bt, Ct, N);

    hipMemsetAsync(deg, 0, (size_t)N * 4, stream);
    hist_kernel<<<gE, blk256, 0, stream>>>(ei, deg, E);
    scan_kernel<<<1, 1024, 0, stream>>>(deg, rowptr, cursor, N);
    scatter_kernel<<<gE, blk256, 0, stream>>>(ei, bond, coords, cursor, csr, E);

    edge_agg<<<(N + 3) / 4, blk256, 0, stream>>>(At, Bt, G, rowptr, csr, conv_w, conv_b,
                                                 b_nb, b_el, Pn, Pe, z, s_arr, N);

    mega_kernel<<<NB16, blk256, 0, stream>>>(Pn, Pe, z, Ct, xWs, s_arr, deg,
                                             b_nout, b_eout, b_coord, b_pair, b_sout,
                                             Wh, Wl, hout, N);

    hipMemsetAsync(bnsums, 0, 256 * 4, stream);
    bn_stats<<<512, blk256, 0, stream>>>(hout, bnsums, N);
    bn_finalize<<<1, 128, 0, stream>>>(bnsums, gamma, beta, bnscale, bnshift, 1.0f / (float)N);
    bn_apply<<<gElem, blk256, 0, stream>>>(hout, bnscale, bnshift, total4);
}

// Round 9
// 622.959 us; speedup vs baseline: 1.6953x; 1.0007x over previous
//
#include <hip/hip_runtime.h>
#include <math.h>

#define DD 128
#define LDSS 136            // u16 LDS row stride (128 + 8 pad)
#define PLANE (16 * LDSS)   // u16 elements per 16-row plane
#define WT 16384            // u16 elements per packed 128x128 weight matrix

typedef __attribute__((ext_vector_type(8))) short bf16x8;
typedef __attribute__((ext_vector_type(4))) float f32x4;
typedef unsigned short u16;
typedef unsigned int u32;

__device__ __forceinline__ u16 f2bf(float f) {          // RNE (stored tensors)
    u32 u = __builtin_bit_cast(u32, f);
    u += 0x7fffu + ((u >> 16) & 1u);
    return (u16)(u >> 16);
}
__device__ __forceinline__ float bf2f(u16 h) {
    u32 u = ((u32)h) << 16;
    return __builtin_bit_cast(float, u);
}
__device__ __forceinline__ float mishf(float x) {
    float e = __expf(fminf(x, 15.0f));
    float n = e * (e + 2.0f);
    return x * n * __builtin_amdgcn_rcpf(n + 2.0f);
}
// truncating hi/lo split (3 VALU ops, reconstruction err ~2^-16)
__device__ __forceinline__ void splitv(float v, u16& h, u16& l) {
    u32 u = __builtin_bit_cast(u32, v);
    h = (u16)(u >> 16);
    float r = v - __builtin_bit_cast(float, u & 0xffff0000u);
    l = (u16)(__builtin_bit_cast(u32, r) >> 16);
}

// 2-nt-tile GEMM slice. NM=1: ah*bh ; NM=2: ah*(bh+bl) ; NM=3: + al*bh
template<int NM>
__device__ __forceinline__ void gemm2(const bf16x8* ah, const bf16x8* al,
    const u16* __restrict__ Wh, const u16* __restrict__ Wl, int lane, int ntB, f32x4* acc)
{
#pragma unroll
    for (int kb = 0; kb < 4; kb++)
#pragma unroll
        for (int j = 0; j < 2; j++) {
            size_t boff = (((size_t)kb * 8 + ntB + j) * 64 + lane) * 8;
            bf16x8 bh = *(const bf16x8*)(Wh + boff);
            acc[j] = __builtin_amdgcn_mfma_f32_16x16x32_bf16(ah[kb], bh, acc[j], 0, 0, 0);
            if (NM >= 2) {
                bf16x8 bl = *(const bf16x8*)(Wl + boff);
                acc[j] = __builtin_amdgcn_mfma_f32_16x16x32_bf16(ah[kb], bl, acc[j], 0, 0, 0);
            }
            if (NM == 3)
                acc[j] = __builtin_amdgcn_mfma_f32_16x16x32_bf16(al[kb], bh, acc[j], 0, 0, 0);
        }
}

// dual-A NM=2 GEMM pair (two independent A streams, shared or distinct B)
__device__ __forceinline__ void gemm2_dual(const bf16x8* a1, const bf16x8* a2,
    const u16* __restrict__ W1h, const u16* __restrict__ W1l,
    const u16* __restrict__ W2h, const u16* __restrict__ W2l,
    int lane, int ntB, f32x4* acc1, f32x4* acc2)
{
#pragma unroll
    for (int kb = 0; kb < 4; kb++)
#pragma unroll
        for (int j = 0; j < 2; j++) {
            size_t boff = (((size_t)kb * 8 + ntB + j) * 64 + lane) * 8;
            bf16x8 b1h = *(const bf16x8*)(W1h + boff);
            bf16x8 b1l = *(const bf16x8*)(W1l + boff);
            acc1[j] = __builtin_amdgcn_mfma_f32_16x16x32_bf16(a1[kb], b1h, acc1[j], 0, 0, 0);
            acc1[j] = __builtin_amdgcn_mfma_f32_16x16x32_bf16(a1[kb], b1l, acc1[j], 0, 0, 0);
            bf16x8 b2h = (W2h == W1h) ? b1h : *(const bf16x8*)(W2h + boff);
            bf16x8 b2l = (W2l == W1l) ? b1l : *(const bf16x8*)(W2l + boff);
            acc2[j] = __builtin_amdgcn_mfma_f32_16x16x32_bf16(a2[kb], b2h, acc2[j], 0, 0, 0);
            acc2[j] = __builtin_amdgcn_mfma_f32_16x16x32_bf16(a2[kb], b2l, acc2[j], 0, 0, 0);
        }
}

__device__ __forceinline__ void zero2(f32x4* acc) {
    f32x4 z4 = {0.f, 0.f, 0.f, 0.f};
    acc[0] = z4; acc[1] = z4;
}

__device__ __forceinline__ void frag_hi_global16(const u16* __restrict__ src, int row0,
                                                 int lm, int quad, int M, bf16x8* ah)
{
    int row = row0 + lm; if (row >= M) row = M - 1;
    const u16* p = src + (size_t)row * DD + quad * 8;
#pragma unroll
    for (int kb = 0; kb < 4; kb++) ah[kb] = *(const bf16x8*)(p + kb * 32);
}
__device__ __forceinline__ void frag_split_global16(const float* __restrict__ src, int row0,
                                                    int lm, int quad, int M, bf16x8* ah, bf16x8* al)
{
    int row = row0 + lm; if (row >= M) row = M - 1;
    const float* p = src + (size_t)row * DD + quad * 8;
#pragma unroll
    for (int kb = 0; kb < 4; kb++) {
        float tmp[8];
        *(float4*)tmp       = *(const float4*)(p + kb * 32);
        *(float4*)(tmp + 4) = *(const float4*)(p + kb * 32 + 4);
#pragma unroll
        for (int j = 0; j < 8; j++) { u16 h, l; splitv(tmp[j], h, l); ah[kb][j] = (short)h; al[kb][j] = (short)l; }
    }
}
__device__ __forceinline__ void frag_hi_plane16(const u16* P, int lm, int quad, bf16x8* ah)
{
    const u16* p = P + (size_t)lm * LDSS + quad * 8;
#pragma unroll
    for (int kb = 0; kb < 4; kb++) ah[kb] = *(const bf16x8*)(p + kb * 32);
}
__device__ __forceinline__ void frag_planes16(const u16* PH, const u16* PL, int lm, int quad,
                                              bf16x8* ah, bf16x8* al)
{
    const u16* ph = PH + (size_t)lm * LDSS + quad * 8;
    const u16* pl = PL + (size_t)lm * LDSS + quad * 8;
#pragma unroll
    for (int kb = 0; kb < 4; kb++) {
        ah[kb] = *(const bf16x8*)(ph + kb * 32);
        al[kb] = *(const bf16x8*)(pl + kb * 32);
    }
}

// ============ weight prep ============
struct WSrc { const float* p[18]; };

__global__ __launch_bounds__(256) void prep_weights(WSrc ws, u16* __restrict__ Wh, u16* __restrict__ Wl)
{
    int mat = blockIdx.x >> 3, chunk = blockIdx.x & 7;
    int t = threadIdx.x;
    int tt = chunk * 4 + (t >> 6);
    int lane = t & 63;
    int kb = tt >> 3, nt = tt & 7;
    const float* __restrict__ src = ws.p[mat];
    size_t doff = (size_t)mat * WT + ((size_t)tt * 64 + lane) * 8;
    int srow = kb * 32 + ((lane >> 4) * 8);
    int scol = nt * 16 + (lane & 15);
    u16 th[8], tl[8];
#pragma unroll
    for (int j = 0; j < 8; j++) {
        float v = src[(srow + j) * DD + scol];
        u16 h = f2bf(v);
        th[j] = h;
        tl[j] = f2bf(v - bf2f(h));
    }
    *(bf16x8*)(Wh + doff) = *(bf16x8*)th;
    *(bf16x8*)(Wl + doff) = *(bf16x8*)tl;
}

// ============ front + hist packed in one launch ============
__global__ __launch_bounds__(256, 4) void fronthist_kernel(
    const float* __restrict__ x, const u16* __restrict__ Wh, const u16* __restrict__ Wl,
    u16* __restrict__ G, u16* __restrict__ xWs,
    float* __restrict__ At, float* __restrict__ Bt, float* __restrict__ Ct,
    const int* __restrict__ ei, int* __restrict__ deg, int E, int M, int NBF)
{
    __shared__ u16 sP[3 * PLANE];
    const int t = threadIdx.x;
    if ((int)blockIdx.x >= NBF) {           // ---- histogram part ----
        int e = ((int)blockIdx.x - NBF) * 256 + t;
        if (e < E) atomicAdd(&deg[ei[E + e]], 1);
        return;
    }
    u16 *P0 = sP, *P1 = sP + PLANE, *P2 = sP + 2 * PLANE;
    const int wave = t >> 6, lane = t & 63;
    const int lm = lane & 15, quad = lane >> 4;
    const int ntB = wave * 2;
    const int row0 = blockIdx.x * 16;

    bf16x8 ah[4], al[4];
    {   // every wave loads the same 16 rows (L1 hits); wave 0 writes the xb plane
        int row = row0 + lm; if (row >= M) row = M - 1;
        const float* p = x + (size_t)row * DD + quad * 8;
#pragma unroll
        for (int kb = 0; kb < 4; kb++) {
            float tmp[8];
            *(float4*)tmp       = *(const float4*)(p + kb * 32);
            *(float4*)(tmp + 4) = *(const float4*)(p + kb * 32 + 4);
#pragma unroll
            for (int j = 0; j < 8; j++) {
                u16 h, l; splitv(tmp[j], h, l);
                ah[kb][j] = (short)h; al[kb][j] = (short)l;
                if (wave == 0) P0[lm * LDSS + kb * 32 + quad * 8 + j] = f2bf(tmp[j]);
            }
        }
    }
    {   // As = x@W1 -> P1
        f32x4 acc[2]; zero2(acc);
        gemm2<1>(ah, ah, Wh + 1 * WT, Wh, lane, ntB, acc);
#pragma unroll
        for (int r = 0; r < 4; r++)
#pragma unroll
            for (int j = 0; j < 2; j++)
                P1[(quad * 4 + r) * LDSS + (ntB + j) * 16 + lm] = f2bf(acc[j][r]);
    }
    {   // Bs = x@W3 -> P2
        f32x4 acc[2]; zero2(acc);
        gemm2<1>(ah, ah, Wh + 3 * WT, Wh, lane, ntB, acc);
#pragma unroll
        for (int r = 0; r < 4; r++)
#pragma unroll
            for (int j = 0; j < 2; j++)
                P2[(quad * 4 + r) * LDSS + (ntB + j) * 16 + lm] = f2bf(acc[j][r]);
    }
    __syncthreads();   // single barrier: planes complete, drain all three
#pragma unroll
    for (int i = 0; i < 4; i++) {
        int r = wave * 4 + i;
        int grow = row0 + r;
        if (grow >= M) continue;
        u16* gp = G + (size_t)grow * 384;
        *(u32*)(gp +       lane * 2) = *(const u32*)&P1[r * LDSS + lane * 2];   // As seg0
        *(u32*)(gp + 128 + lane * 2) = *(const u32*)&P2[r * LDSS + lane * 2];   // Bs seg1
        *(u32*)(gp + 256 + lane * 2) = *(const u32*)&P0[r * LDSS + lane * 2];   // xb seg2
    }
    {   // xWs = x@W5 -> global bf16
        f32x4 acc[2]; zero2(acc);
        gemm2<1>(ah, ah, Wh + 5 * WT, Wh, lane, ntB, acc);
#pragma unroll
        for (int r = 0; r < 4; r++) {
            int grow = row0 + quad * 4 + r;
            if (grow >= M) continue;
#pragma unroll
            for (int j = 0; j < 2; j++)
                xWs[(size_t)grow * DD + (ntB + j) * 16 + lm] = f2bf(acc[j][r]);
        }
    }
    {   // At, Bt, Ct (split, fp32 out) — independent, no barriers
        float* outs[3] = {At, Bt, Ct};
        const int mats[3] = {0, 2, 4};
#pragma unroll
        for (int wi = 0; wi < 3; wi++) {
            f32x4 acc[2]; zero2(acc);
            gemm2<3>(ah, al, Wh + (size_t)mats[wi] * WT, Wl + (size_t)mats[wi] * WT, lane, ntB, acc);
            float* out = outs[wi];
#pragma unroll
            for (int r = 0; r < 4; r++) {
                int grow = row0 + quad * 4 + r;
                if (grow >= M) continue;
#pragma unroll
                for (int j = 0; j < 2; j++)
                    out[(size_t)grow * DD + (ntB + j) * 16 + lm] = acc[j][r];
            }
        }
    }
}

// ============ CSR scan + scatter ============
__global__ __launch_bounds__(1024) void scan_kernel(const int* __restrict__ deg,
                                                    int* __restrict__ rowptr,
                                                    int* __restrict__ cursor, int N)
{
    __shared__ int sums[1024];
    const int CH = 52;
    int t = threadIdx.x;
    int base = t * CH;
    int local = 0;
#pragma unroll
    for (int i = 0; i < 13; i++) {
        int idx = base + i * 4;
        if (idx + 3 < N) {
            int4 v = *(const int4*)(deg + idx);
            local += v.x + v.y + v.z + v.w;
        } else {
            for (int k = 0; k < 4; k++) if (idx + k < N) local += deg[idx + k];
        }
    }
    sums[t] = local;
    __syncthreads();
    for (int off = 1; off < 1024; off <<= 1) {
        int v = sums[t];
        int u = (t >= off) ? sums[t - off] : 0;
        __syncthreads();
        sums[t] = v + u;
        __syncthreads();
    }
    int run = (t == 0) ? 0 : sums[t - 1];
    for (int i = 0; i < CH; i++) {
        int idx = base + i;
        if (idx < N) {
            rowptr[idx] = run;
            cursor[idx] = run;
            run += deg[idx];
        }
    }
    if (t == 1023) rowptr[N] = sums[1023];
}

__global__ __launch_bounds__(256) void scatter_kernel(
    const int* __restrict__ ei, const int* __restrict__ bond,
    const float* __restrict__ coords, int* __restrict__ cursor,
    int2* __restrict__ csr, int E)
{
    int e = blockIdx.x * 256 + threadIdx.x;
    if (e >= E) return;
    int src = ei[e], dst = ei[E + e];
    int pos = atomicAdd(&cursor[dst], 1);
    float dx = coords[src * 3 + 0] - coords[dst * 3 + 0];
    float dy = coords[src * 3 + 1] - coords[dst * 3 + 1];
    float dz = coords[src * 3 + 2] - coords[dst * 3 + 2];
    float d2 = dx * dx + dy * dy + dz * dz;
    csr[pos] = make_int2(src | (bond[e] << 20), __float_as_int(d2));
}

// ============ per-node edge aggregation ============
__global__ __launch_bounds__(256) void edge_agg(
    const float* __restrict__ At, const float* __restrict__ Bt,
    const u16* __restrict__ G,
    const int* __restrict__ rowptr, const int2* __restrict__ csr,
    const float* __restrict__ conv_w, const float* __restrict__ conv_b,
    const float* __restrict__ b_nb, const float* __restrict__ b_el,
    u16* __restrict__ Pn, u16* __restrict__ Pe, float* __restrict__ z,
    float* __restrict__ s_arr, int N)
{
    int wave = threadIdx.x >> 6;
    int lane = threadIdx.x & 63;
    int node = blockIdx.x * 4 + wave;
    if (node >= N) return;
    int c0 = lane * 2;
    float2 at = *(const float2*)(At + (size_t)node * DD + c0);
    float2 bt = *(const float2*)(Bt + (size_t)node * DD + c0);
    float cb = conv_b[0];
    float cw0 = conv_w[0] + cb, cw1 = conv_w[1] + cb, cw2 = conv_w[2] + cb, cw3 = conv_w[3] + cb;
    float bn0 = b_nb[c0], bn1 = b_nb[c0 + 1];
    float be0 = b_el[c0], be1 = b_el[c0 + 1];
    float accn0 = 0.f, accn1 = 0.f, acce0 = 0.f, acce1 = 0.f, accz0 = 0.f, accz1 = 0.f, ssum = 0.f;
    int beg = rowptr[node], end = rowptr[node + 1];
#pragma unroll 2
    for (int k = beg; k < end; k++) {
        int2 pd = csr[k];
        int src = pd.x & 0xFFFFF;
        int bond = (pd.x >> 20) & 3;
        float w = (bond == 0) ? cw0 : (bond == 1) ? cw1 : (bond == 2) ? cw2 : cw3;
        float d2 = __int_as_float(pd.y);
        const u16* gp = G + (size_t)src * 384;
        u32 ga = *(const u32*)(gp + c0);
        u32 gb = *(const u32*)(gp + 128 + c0);
        u32 gx = *(const u32*)(gp + 256 + c0);
        float a0 = __builtin_bit_cast(float, ga << 16), a1 = __builtin_bit_cast(float, ga & 0xffff0000u);
        float b0 = __builtin_bit_cast(float, gb << 16), b1 = __builtin_bit_cast(float, gb & 0xffff0000u);
        float x0 = __builtin_bit_cast(float, gx << 16), x1 = __builtin_bit_cast(float, gx & 0xffff0000u);
        accn0 += mishf(at.x + a0 + bn0);
        accn1 += mishf(at.y + a1 + bn1);
        acce0 += mishf(w * (bt.x + b0) + be0);
        acce1 += mishf(w * (bt.y + b1) + be1);
        accz0 += d2 * x0;
        accz1 += d2 * x1;
        ssum += d2;
    }
    *(u32*)(Pn + (size_t)node * DD + c0) = (u32)f2bf(accn0) | ((u32)f2bf(accn1) << 16);
    *(u32*)(Pe + (size_t)node * DD + c0) = (u32)f2bf(acce0) | ((u32)f2bf(acce1) << 16);
    *(float2*)(z + (size_t)node * DD + c0) = make_float2(accz0, accz1);
    if (lane == 0) s_arr[node] = ssum;
}

// ============ mega: all 3 chains + softmax + @W_agg + BN partial sums ============
__global__ __launch_bounds__(256, 4) void mega_kernel(
    const u16* __restrict__ Pn, const u16* __restrict__ Pe, const float* __restrict__ z,
    const float* __restrict__ Ct, const u16* __restrict__ xWs,
    const float* __restrict__ s_arr, const int* __restrict__ deg,
    const float* __restrict__ b_nout, const float* __restrict__ b_eout,
    const float* __restrict__ b_coord, const float* __restrict__ b_pair,
    const float* __restrict__ b_sout,
    const u16* __restrict__ Wh, const u16* __restrict__ Wl,
    float* __restrict__ hout, float* __restrict__ bnsums, int M)
{
    __shared__ u16 sP[4 * PLANE];
    u16 *PA = sP, *PB = sP + PLANE, *PC = sP + 2 * PLANE, *PD = sP + 3 * PLANE;
    const int t = threadIdx.x, wave = t >> 6, lane = t & 63;
    const int lm = lane & 15, quad = lane >> 4;
    const int ntB = wave * 2;
    const int row0 = blockIdx.x * 16;

    u32 f1p[4], f2p[4], f3p[4];
    float d1v[8], d2v[8];

    // ======== node & edge chains INTERLEAVED (2 independent GEMM streams) ========
    {
        bf16x8 an[4], ae[4];
        f32x4 accn[2], acce[2];
        // stage 1: f_n, f_e
        frag_hi_global16(Pn, row0, lm, quad, M, an);
        frag_hi_global16(Pe, row0, lm, quad, M, ae);
        zero2(accn); zero2(acce);
        gemm2_dual(an, ae, Wh + 11 * WT, Wl + 11 * WT, Wh + 12 * WT, Wl + 12 * WT, lane, ntB, accn, acce);
#pragma unroll
        for (int r = 0; r < 4; r++) {
            u32 pkn = 0, pke = 0;
#pragma unroll
            for (int j = 0; j < 2; j++) {
                int col = (ntB + j) * 16 + lm;
                int lidx = (quad * 4 + r) * LDSS + col;
                u16 hn = f2bf(mishf(accn[j][r] + b_nout[col]));
                u16 he = f2bf(mishf(acce[j][r] + b_eout[col]));
                pkn |= ((u32)hn) << (16 * j);
                pke |= ((u32)he) << (16 * j);
                PA[lidx] = hn; PB[lidx] = he;
            }
            f1p[r] = pkn; f2p[r] = pke;
        }
        __syncthreads();
        // stage 2: l_n, l_e
        frag_hi_plane16(PA, lm, quad, an);
        frag_hi_plane16(PB, lm, quad, ae);
        zero2(accn); zero2(acce);
        gemm2_dual(an, ae, Wh + 13 * WT, Wl + 13 * WT, Wh + 14 * WT, Wl + 14 * WT, lane, ntB, accn, acce);
#pragma unroll
        for (int r = 0; r < 4; r++)
#pragma unroll
            for (int j = 0; j < 2; j++) {
                int lidx = (quad * 4 + r) * LDSS + (ntB + j) * 16 + lm;
                PC[lidx] = f2bf(mishf(mishf(accn[j][r])));
                PD[lidx] = f2bf(mishf(mishf(acce[j][r])));
            }
        __syncthreads();
        // stage 3: d_n, d_e (shared B = Wa_b; e0 cancels in softmax)
        frag_hi_plane16(PC, lm, quad, an);
        frag_hi_plane16(PD, lm, quad, ae);
        zero2(accn); zero2(acce);
        gemm2_dual(an, ae, Wh + 16 * WT, Wl + 16 * WT, Wh + 16 * WT, Wl + 16 * WT, lane, ntB, accn, acce);
#pragma unroll
        for (int r = 0; r < 4; r++)
#pragma unroll
            for (int j = 0; j < 2; j++) {
                d1v[r * 2 + j] = accn[j][r];
                d2v[r * 2 + j] = acce[j][r];
            }
    }

    // ======== struct chain (hi/lo split planes) ========
    bf16x8 ah[4], al[4];
    f32x4 acc[2];
    // S1: Qagg = z@Wc_s + s*Ct + deg*b_coord -> PA/PB
    frag_split_global16(z, row0, lm, quad, M, ah, al);
    zero2(acc);
    gemm2<3>(ah, al, Wh + 8 * WT, Wl + 8 * WT, lane, ntB, acc);
#pragma unroll
    for (int r = 0; r < 4; r++) {
        int crow = row0 + quad * 4 + r; if (crow >= M) crow = M - 1;
        float sv = s_arr[crow];
        float dv = (float)deg[crow];
#pragma unroll
        for (int j = 0; j < 2; j++) {
            int col = (ntB + j) * 16 + lm;
            float v = acc[j][r] + sv * Ct[(size_t)crow * DD + col] + dv * b_coord[col];
            int lidx = (quad * 4 + r) * LDSS + col;
            u16 h, l; splitv(v, h, l); PA[lidx] = h; PB[lidx] = l;
        }
    }
    __syncthreads();
    // S2: Q = mish(Qagg@W_pair + b_pair) -> PC/PD
    frag_planes16(PA, PB, lm, quad, ah, al);
    zero2(acc);
    gemm2<3>(ah, al, Wh + 9 * WT, Wl + 9 * WT, lane, ntB, acc);
#pragma unroll
    for (int r = 0; r < 4; r++)
#pragma unroll
        for (int j = 0; j < 2; j++) {
            int col = (ntB + j) * 16 + lm;
            int lidx = (quad * 4 + r) * LDSS + col;
            u16 h, l; splitv(mishf(acc[j][r] + b_pair[col]), h, l); PC[lidx] = h; PD[lidx] = l;
        }
    __syncthreads();
    // S3: f_struct = mish(Q@Ws_b + xWs + b_sout) -> f3 regs + PA/PB
    frag_planes16(PC, PD, lm, quad, ah, al);
    zero2(acc);
    gemm2<3>(ah, al, Wh + 10 * WT, Wl + 10 * WT, lane, ntB, acc);
#pragma unroll
    for (int r = 0; r < 4; r++) {
        int crow = row0 + quad * 4 + r; if (crow >= M) crow = M - 1;
        u32 pk = 0;
#pragma unroll
        for (int j = 0; j < 2; j++) {
            int col = (ntB + j) * 16 + lm;
            float v = mishf(acc[j][r] + bf2f(xWs[(size_t)crow * DD + col]) + b_sout[col]);
            u16 h, l; splitv(v, h, l);
            pk |= ((u32)f2bf(v)) << (16 * j);
            int lidx = (quad * 4 + r) * LDSS + col;
            PA[lidx] = h; PB[lidx] = l;
        }
        f3p[r] = pk;
    }
    __syncthreads();
    // S4: l2 = mish2(f_struct@FL2) -> PC/PD
    frag_planes16(PA, PB, lm, quad, ah, al);
    zero2(acc);
    gemm2<3>(ah, al, Wh + 15 * WT, Wl + 15 * WT, lane, ntB, acc);
#pragma unroll
    for (int r = 0; r < 4; r++)
#pragma unroll
        for (int j = 0; j < 2; j++) {
            int lidx = (quad * 4 + r) * LDSS + (ntB + j) * 16 + lm;
            u16 h, l; splitv(mishf(mishf(acc[j][r])), h, l); PC[lidx] = h; PD[lidx] = l;
        }
    __syncthreads();
    // S5: d3 = l2@Wa_b -> acc
    frag_planes16(PC, PD, lm, quad, ah, al);
    zero2(acc);
    gemm2<3>(ah, al, Wh + 16 * WT, Wl + 16 * WT, lane, ntB, acc);

    // ---- combine: softmax over paths (e0 cancels) -> att hi/lo into PA/PB ----
#pragma unroll
    for (int r = 0; r < 4; r++)
#pragma unroll
        for (int j = 0; j < 2; j++) {
            int i = r * 2 + j;
            float x1 = d1v[i], x2 = d2v[i], x3 = acc[j][r];
            float m = fmaxf(fmaxf(x1, x2), x3);
            float p1 = __expf(x1 - m), p2 = __expf(x2 - m), p3 = __expf(x3 - m);
            float fv1 = bf2f((u16)(f1p[r] >> (16 * j)));
            float fv2 = bf2f((u16)(f2p[r] >> (16 * j)));
            float fv3 = bf2f((u16)(f3p[r] >> (16 * j)));
            float att = (p1 * fv1 + p2 * fv2 + p3 * fv3) * __builtin_amdgcn_rcpf(p1 + p2 + p3);
            int lidx = (quad * 4 + r) * LDSS + (ntB + j) * 16 + lm;
            u16 h, l; splitv(att, h, l); PA[lidx] = h; PB[lidx] = l;
        }
    __syncthreads();
    // ---- h_agg = att@W_agg -> hout fp32 + BN partial sums ----
    frag_planes16(PA, PB, lm, quad, ah, al);
    zero2(acc);
    gemm2<3>(ah, al, Wh + 17 * WT, Wl + 17 * WT, lane, ntB, acc);
    float s[2] = {0.f, 0.f}, q[2] = {0.f, 0.f};
#pragma unroll
    for (int r = 0; r < 4; r++) {
        int grow = row0 + quad * 4 + r;
        if (grow >= M) continue;
#pragma unroll
        for (int j = 0; j < 2; j++) {
            float v = acc[j][r];
            hout[(size_t)grow * DD + (ntB + j) * 16 + lm] = v;
            s[j] += v; q[j] += v * v;
        }
    }
    // per-block column reduction in LDS (planes dead), then global atomics
    __syncthreads();
    float* red = (float*)sP;                 // 256 floats
    if (t < 128) { red[t] = 0.f; red[128 + t] = 0.f; }
    __syncthreads();
#pragma unroll
    for (int j = 0; j < 2; j++) {
        int col = (ntB + j) * 16 + lm;
        atomicAdd(&red[col], s[j]);
        atomicAdd(&red[128 + col], q[j]);
    }
    __syncthreads();
    if (t < 128) {
        atomicAdd(&bnsums[t], red[t]);
        atomicAdd(&bnsums[128 + t], red[128 + t]);
    }
}

// ============ batchnorm finalize + apply ============
__global__ void bn_finalize(const float* __restrict__ sums, const float* __restrict__ gamma,
                            const float* __restrict__ beta, float* __restrict__ scale,
                            float* __restrict__ shift, float n_inv)
{
    int c = threadIdx.x;
    float mean = sums[c] * n_inv;
    float var = sums[128 + c] * n_inv - mean * mean;
    float inv = rsqrtf(var + 1e-5f);
    float sc = gamma[c] * inv;
    scale[c] = sc;
    shift[c] = beta[c] - mean * sc;
}

__global__ __launch_bounds__(256) void bn_apply(float* __restrict__ h, const float* __restrict__ scale,
                                                const float* __restrict__ shift, size_t total4)
{
    size_t idx = (size_t)blockIdx.x * 256 + threadIdx.x;
    if (idx >= total4) return;
    size_t off = idx * 4;
    int c = (int)(off & 127);
    float4 v = *(const float4*)(h + off);
    float4 sc = *(const float4*)(scale + c);
    float4 sh = *(const float4*)(shift + c);
    v.x = mishf(v.x * sc.x + sh.x);
    v.y = mishf(v.y * sc.y + sh.y);
    v.z = mishf(v.z * sc.z + sh.z);
    v.w = mishf(v.w * sc.w + sh.w);
    *(float4*)(h + off) = v;
}

// ============ host ============
extern "C" void kernel_launch(void* const* d_in, const int* in_sizes, int n_in,
                              void* d_out, int out_size, void* d_ws, size_t ws_size,
                              hipStream_t stream)
{
    (void)n_in; (void)out_size; (void)ws_size;
    const float* x       = (const float*)d_in[0];
    const float* coords  = (const float*)d_in[1];
    const int*   ei      = (const int*)d_in[2];
    const int*   bond    = (const int*)d_in[3];
    const float* W_nb    = (const float*)d_in[4];
    const float* b_nb    = (const float*)d_in[5];
    const float* W_nout  = (const float*)d_in[6];
    const float* b_nout  = (const float*)d_in[7];
    const float* conv_w  = (const float*)d_in[8];
    const float* conv_b  = (const float*)d_in[9];
    const float* W_el    = (const float*)d_in[10];
    const float* b_el    = (const float*)d_in[11];
    const float* W_eout  = (const float*)d_in[12];
    const float* b_eout  = (const float*)d_in[13];
    const float* W_coord = (const float*)d_in[14];
    const float* b_coord = (const float*)d_in[15];
    const float* W_pair  = (const float*)d_in[16];
    const float* b_pair  = (const float*)d_in[17];
    const float* W_sout  = (const float*)d_in[18];
    const float* b_sout  = (const float*)d_in[19];
    const float* W_init  = (const float*)d_in[20];
    const float* feat_lin= (const float*)d_in[21];
    const float* W_att   = (const float*)d_in[22];
    const float* W_agg   = (const float*)d_in[23];
    const float* gamma   = (const float*)d_in[24];
    const float* beta    = (const float*)d_in[25];

    const int N = in_sizes[0] / DD;     // 50000
    const int E = in_sizes[3];          // 800000
    const size_t ND = (size_t)N * DD;
    const int SUB = DD * DD;
    const int NB16 = (N + 15) / 16;
    const int EB   = (E + 255) / 256;

    char* base = (char*)d_ws;
    size_t off = 0;
    auto alloc = [&](size_t bytes) -> char* {
        char* p = base + off;
        off = (off + bytes + 63) & ~(size_t)63;
        return p;
    };
    u16*   G    = (u16*)alloc((size_t)N * 384 * 2);
    u16*   xWs  = (u16*)alloc(ND * 2);
    float* At   = (float*)alloc(ND * 4);
    float* Bt   = (float*)alloc(ND * 4);
    float* Ct   = (float*)alloc(ND * 4);
    u16*   Pn   = (u16*)alloc(ND * 2);
    u16*   Pe   = (u16*)alloc(ND * 2);
    float* z    = (float*)alloc(ND * 4);
    u16*   Wh   = (u16*)alloc((size_t)18 * WT * 2);
    u16*   Wl   = (u16*)alloc((size_t)18 * WT * 2);
    int2*  csr  = (int2*)alloc((size_t)E * 8);
    int*   deg    = (int*)alloc((size_t)(N + 64) * 4);
    int*   rowptr = (int*)alloc((size_t)(N + 1) * 4);
    int*   cursor = (int*)alloc((size_t)N * 4);
    float* s_arr  = (float*)alloc((size_t)N * 4);
    float* bnsums  = (float*)alloc(256 * 4);
    float* bnscale = (float*)alloc(128 * 4);
    float* bnshift = (float*)alloc(128 * 4);

    float* hout = (float*)d_out;

    WSrc wsrc;
    wsrc.p[0] = W_nb;            wsrc.p[1] = W_nb + SUB;
    wsrc.p[2] = W_el;            wsrc.p[3] = W_el + SUB;
    wsrc.p[4] = W_coord;         wsrc.p[5] = W_sout;
    wsrc.p[6] = W_init;          wsrc.p[7] = W_att;      // 6,7 unused (e0 cancels) — kept for layout
    wsrc.p[8] = W_coord + SUB;   wsrc.p[9] = W_pair;
    wsrc.p[10] = W_sout + SUB;   wsrc.p[11] = W_nout;
    wsrc.p[12] = W_eout;         wsrc.p[13] = feat_lin;
    wsrc.p[14] = feat_lin + SUB; wsrc.p[15] = feat_lin + 2 * SUB;
    wsrc.p[16] = W_att + SUB;    wsrc.p[17] = W_agg;

    const dim3 blk256(256);
    const size_t total4 = ND / 4;
    const dim3 gElem((unsigned)((total4 + 255) / 256));

    hipMemsetAsync(deg, 0, (size_t)N * 4, stream);
    hipMemsetAsync(bnsums, 0, 256 * 4, stream);

    prep_weights<<<dim3(18 * 8), blk256, 0, stream>>>(wsrc, Wh, Wl);
    fronthist_kernel<<<dim3(NB16 + EB), blk256, 0, stream>>>(x, Wh, Wl, G, xWs, At, Bt, Ct,
                                                             ei, deg, E, N, NB16);
    scan_kernel<<<1, 1024, 0, stream>>>(deg, rowptr, cursor, N);
    scatter_kernel<<<dim3(EB), blk256, 0, stream>>>(ei, bond, coords, cursor, csr, E);

    edge_agg<<<(N + 3) / 4, blk256, 0, stream>>>(At, Bt, G, rowptr, csr, conv_w, conv_b,
                                                 b_nb, b_el, Pn, Pe, z, s_arr, N);

    mega_kernel<<<NB16, blk256, 0, stream>>>(Pn, Pe, z, Ct, xWs, s_arr, deg,
                                             b_nout, b_eout, b_coord, b_pair, b_sout,
                                             Wh, Wl, hout, bnsums, N);

    bn_finalize<<<1, 128, 0, stream>>>(bnsums, gamma, beta, bnscale, bnshift, 1.0f / (float)N);
    bn_apply<<<gElem, blk256, 0, stream>>>(hout, bnscale, bnshift, total4);
}